// Round 7
// baseline (643.825 us; speedup 1.0000x reference)
//
#include <hip/hip_runtime.h>
#include <math.h>

#define N_NODES 50000
#define N_EDGES 800000
#define NGRAPH  64
#define SCAN_BLOCKS ((N_NODES + 255) / 256)   // 196

typedef __bf16 bf16x8 __attribute__((ext_vector_type(8)));
typedef float  f32x4  __attribute__((ext_vector_type(4)));
typedef unsigned short us8 __attribute__((ext_vector_type(8)));

__device__ __forceinline__ unsigned short f2bf(float f) {
    unsigned u = __float_as_uint(f);
    u += 0x7fff + ((u >> 16) & 1);          // round-to-nearest-even
    return (unsigned short)(u >> 16);
}
__device__ __forceinline__ float bf2f(unsigned short u) {
    return __uint_as_float((unsigned)u << 16);
}

// ---------------------------------------------------------------------------
// CSR build
// ---------------------------------------------------------------------------
__global__ void degree_kernel(const int* __restrict__ ei, int* __restrict__ counts) {
    int e = blockIdx.x * 256 + threadIdx.x;
    if (e < N_EDGES) atomicAdd(&counts[ei[N_EDGES + e]], 1);
}

__global__ __launch_bounds__(256) void block_sum_kernel(const int* __restrict__ counts,
                                                        int* __restrict__ bsum) {
    int i = blockIdx.x * 256 + threadIdx.x;
    int v = (i < N_NODES) ? counts[i] : 0;
    #pragma unroll
    for (int o = 32; o >= 1; o >>= 1) v += __shfl_xor(v, o);
    __shared__ int ws[4];
    if ((threadIdx.x & 63) == 0) ws[threadIdx.x >> 6] = v;
    __syncthreads();
    if (threadIdx.x == 0) bsum[blockIdx.x] = ws[0] + ws[1] + ws[2] + ws[3];
}

__global__ __launch_bounds__(256) void scan_bsum_kernel(const int* __restrict__ bsum,
                                                        int* __restrict__ boff) {
    int t = threadIdx.x;
    int v = (t < SCAN_BLOCKS) ? bsum[t] : 0;
    int lane = t & 63, wid = t >> 6;
    int incl = v;
    #pragma unroll
    for (int o = 1; o < 64; o <<= 1) {
        int tv = __shfl_up(incl, o);
        if (lane >= o) incl += tv;
    }
    __shared__ int wsum[4];
    if (lane == 63) wsum[wid] = incl;
    __syncthreads();
    int add = 0;
    for (int w = 0; w < wid; w++) add += wsum[w];
    if (t < SCAN_BLOCKS) boff[t] = add + incl - v;   // exclusive
}

__global__ __launch_bounds__(256) void block_scan_kernel(const int* __restrict__ counts,
                                                         const int* __restrict__ boff,
                                                         int* __restrict__ offs,
                                                         int* __restrict__ cursor) {
    int i = blockIdx.x * 256 + threadIdx.x;
    int v = (i < N_NODES) ? counts[i] : 0;
    int lane = threadIdx.x & 63, wid = threadIdx.x >> 6;
    int incl = v;
    #pragma unroll
    for (int o = 1; o < 64; o <<= 1) {
        int tv = __shfl_up(incl, o);
        if (lane >= o) incl += tv;
    }
    __shared__ int wsum[4];
    if (lane == 63) wsum[wid] = incl;
    __syncthreads();
    int add = boff[blockIdx.x];
    for (int w = 0; w < wid; w++) add += wsum[w];
    if (i < N_NODES) {
        offs[i + 1] = add + incl;
        cursor[i]   = add + incl - v;
    }
    if (i == 0) offs[0] = 0;
}

__global__ void scatter_kernel(const int* __restrict__ ei, int* __restrict__ cursor,
                               int* __restrict__ csr) {
    int e = blockIdx.x * 256 + threadIdx.x;
    if (e < N_EDGES) {
        int d = ei[N_EDGES + e];
        int pos = atomicAdd(&cursor[d], 1);
        csr[pos] = ei[e];  // src
    }
}

// ---------------------------------------------------------------------------
// Skip-path fusion (fp32): Wc[l] = Ws[l] @ Wt[l], bc[l] = bs[l] @ Wt[l] + bt[l]
// ---------------------------------------------------------------------------
__global__ void wc_kernel(const float* __restrict__ Ws, const float* __restrict__ Wt,
                          float* __restrict__ Wc) {
    int idx = blockIdx.x * 256 + threadIdx.x;       // 2*128*128 = 32768
    int l = idx >> 14, ij = idx & 16383, i = ij >> 7, j = ij & 127;
    const float* a = Ws + (size_t)l * 32768;
    const float* b = Wt + (size_t)l * 32768;
    float s = 0.f;
    for (int k = 0; k < 256; k++) s = fmaf(a[i * 256 + k], b[k * 128 + j], s);
    Wc[idx] = s;
}

__global__ void bc_kernel(const float* __restrict__ bs, const float* __restrict__ Wt,
                          const float* __restrict__ bt, float* __restrict__ bc) {
    int idx = threadIdx.x;                           // 2 layers x 128
    int l = idx >> 7, j = idx & 127;
    const float* b = Wt + (size_t)l * 32768;
    float s = bt[l * 128 + j];
    for (int k = 0; k < 256; k++) s = fmaf(bs[l * 256 + k], b[k * 128 + j], s);
    bc[idx] = s;
}

// ---------------------------------------------------------------------------
// Weight packing into MFMA B-fragment layout (bf16, ks-major)
// ---------------------------------------------------------------------------
__global__ void pack_qkv_kernel(const float* __restrict__ Wq, const float* __restrict__ Wk,
                                const float* __restrict__ Wv, unsigned short* __restrict__ out) {
    int idx = blockIdx.x * 256 + threadIdx.x;        // 2*3*32768 = 196608
    if (idx >= 196608) return;
    int j = idx & 7, lane = (idx >> 3) & 63, ct = (idx >> 9) & 15, ks = (idx >> 13) & 3;
    int m3 = idx >> 15;                              // 0..5
    int l = m3 / 3, m = m3 % 3;
    int k = ks * 32 + ((lane >> 4) * 8) + j;
    int n = ct * 16 + (lane & 15);
    const float* W = (m == 0) ? Wq : (m == 1) ? Wk : Wv;
    out[idx] = f2bf(W[(size_t)l * 32768 + k * 256 + n]);
}

// fused [Wt;Wc] (K=384): KS=12 (ks 0..7 from Wt, 8..11 from Wc), CT=8
__global__ void pack_fused_kernel(const float* __restrict__ Wt, const float* __restrict__ Wc,
                                  unsigned short* __restrict__ out) {
    int idx = blockIdx.x * 256 + threadIdx.x;        // 2*49152 = 98304
    if (idx >= 98304) return;
    int l = idx / 49152, r = idx % 49152;
    int j = r & 7, lane = (r >> 3) & 63;
    int rest = r >> 9;
    int ct = rest & 7, ks = rest >> 3;               // ks 0..11
    int k = ks * 32 + ((lane >> 4) * 8) + j;
    int n = ct * 16 + (lane & 15);
    float v = (k < 256) ? Wt[(size_t)l * 32768 + k * 128 + n]
                        : Wc[(size_t)l * 16384 + (k - 256) * 128 + n];
    out[idx] = f2bf(v);
}

// fp32 -> bf16 elementwise (x input), 4 elems/thread
__global__ void f2bf_kernel(const float* __restrict__ in, unsigned short* __restrict__ out, int n4) {
    int i = blockIdx.x * 256 + threadIdx.x;
    if (i >= n4) return;
    float4 v = ((const float4*)in)[i];
    ushort4 o;
    o.x = f2bf(v.x); o.y = f2bf(v.y); o.z = f2bf(v.z); o.w = f2bf(v.w);
    ((ushort4*)out)[i] = o;
}

// ---------------------------------------------------------------------------
// MFMA q/k/v projection -> q bf16 [N,256]; k,v fine-interleaved bf16 kv rows:
// row = 64 chunks of 8 shorts, chunk l = [k[4l..4l+3] | v[4l..4l+3]]
// so attn lane l reads the whole edge (k+v slice) in ONE 16B load.
// ---------------------------------------------------------------------------
__global__ __launch_bounds__(256) void proj_mfma_kernel(
    const unsigned short* __restrict__ xb, const unsigned short* __restrict__ Wp,
    const float* __restrict__ b0, const float* __restrict__ b1, const float* __restrict__ b2,
    unsigned short* __restrict__ oq, unsigned short* __restrict__ kv) {
    int w = threadIdx.x >> 6, lane = threadIdx.x & 63;
    int quad = lane >> 4, lr = lane & 15;
    int rbase = blockIdx.x * 128 + w * 32;

    bf16x8 a[2][4];
    #pragma unroll
    for (int s = 0; s < 2; s++) {
        int r = rbase + s * 16 + lr;
        if (r > N_NODES - 1) r = N_NODES - 1;
        const unsigned short* xr = xb + (size_t)r * 128 + quad * 8;
        #pragma unroll
        for (int ks = 0; ks < 4; ks++) a[s][ks] = *(const bf16x8*)(xr + ks * 32);
    }

    const float* bias[3] = {b0, b1, b2};
    for (int mm = 0; mm < 3; mm++) {
        const unsigned short* wp = Wp + mm * 32768;
        for (int ct = 0; ct < 16; ct++) {
            f32x4 c0 = {0.f, 0.f, 0.f, 0.f}, c1 = {0.f, 0.f, 0.f, 0.f};
            #pragma unroll
            for (int ks = 0; ks < 4; ks++) {
                bf16x8 b = *(const bf16x8*)(wp + (size_t)((ks * 16 + ct) * 64 + lane) * 8);
                c0 = __builtin_amdgcn_mfma_f32_16x16x32_bf16(a[0][ks], b, c0, 0, 0, 0);
                c1 = __builtin_amdgcn_mfma_f32_16x16x32_bf16(a[1][ks], b, c1, 0, 0, 0);
            }
            int col = ct * 16 + lr;
            float bb = bias[mm][col];
            // kv chunk offset for this col: (col>>2)*8 + (col&3), +4 for v
            int kvo = ((col >> 2) << 3) + (col & 3) + ((mm == 2) ? 4 : 0);
            #pragma unroll
            for (int r = 0; r < 4; r++) {
                int row0 = rbase + quad * 4 + r;
                int row1 = rbase + 16 + quad * 4 + r;
                float v0 = c0[r] + bb, v1 = c1[r] + bb;
                if (mm == 0) {
                    if (row0 < N_NODES) oq[(size_t)row0 * 256 + col] = f2bf(v0);
                    if (row1 < N_NODES) oq[(size_t)row1 * 256 + col] = f2bf(v1);
                } else {
                    if (row0 < N_NODES) kv[(size_t)row0 * 512 + kvo] = f2bf(v0);
                    if (row1 < N_NODES) kv[(size_t)row1 * 512 + kvo] = f2bf(v1);
                }
            }
        }
    }
}

// ---------------------------------------------------------------------------
// MFMA output linear: x_next = relu([h|x] @ [Wt;Wc] + bc); writes bf16 only
// ---------------------------------------------------------------------------
__global__ __launch_bounds__(256) void out_mfma_kernel(
    const unsigned short* __restrict__ hb, const unsigned short* __restrict__ xb,
    const unsigned short* __restrict__ Wfp, const float* __restrict__ bc,
    unsigned short* __restrict__ xbout) {
    int w = threadIdx.x >> 6, lane = threadIdx.x & 63;
    int quad = lane >> 4, lr = lane & 15;
    int rbase = blockIdx.x * 128 + w * 32;
    int r0 = rbase + lr;      if (r0 > N_NODES - 1) r0 = N_NODES - 1;
    int r1 = rbase + 16 + lr; if (r1 > N_NODES - 1) r1 = N_NODES - 1;

    f32x4 acc[8][2];
    #pragma unroll
    for (int ct = 0; ct < 8; ct++) {
        acc[ct][0] = (f32x4){0.f, 0.f, 0.f, 0.f};
        acc[ct][1] = (f32x4){0.f, 0.f, 0.f, 0.f};
    }

    #pragma unroll 4
    for (int ks = 0; ks < 12; ks++) {
        bf16x8 a0, a1;
        if (ks < 8) {
            a0 = *(const bf16x8*)(hb + (size_t)r0 * 256 + ks * 32 + quad * 8);
            a1 = *(const bf16x8*)(hb + (size_t)r1 * 256 + ks * 32 + quad * 8);
        } else {
            a0 = *(const bf16x8*)(xb + (size_t)r0 * 128 + (ks - 8) * 32 + quad * 8);
            a1 = *(const bf16x8*)(xb + (size_t)r1 * 128 + (ks - 8) * 32 + quad * 8);
        }
        #pragma unroll
        for (int ct = 0; ct < 8; ct++) {
            bf16x8 b = *(const bf16x8*)(Wfp + (size_t)((ks * 8 + ct) * 64 + lane) * 8);
            acc[ct][0] = __builtin_amdgcn_mfma_f32_16x16x32_bf16(a0, b, acc[ct][0], 0, 0, 0);
            acc[ct][1] = __builtin_amdgcn_mfma_f32_16x16x32_bf16(a1, b, acc[ct][1], 0, 0, 0);
        }
    }

    #pragma unroll
    for (int ct = 0; ct < 8; ct++) {
        int col = ct * 16 + lr;
        float bb = bc[col];
        #pragma unroll
        for (int r = 0; r < 4; r++) {
            int row0 = rbase + quad * 4 + r;
            if (row0 < N_NODES)
                xbout[(size_t)row0 * 128 + col] = f2bf(fmaxf(acc[ct][0][r] + bb, 0.f));
            int row1 = rbase + 16 + quad * 4 + r;
            if (row1 < N_NODES)
                xbout[(size_t)row1 * 128 + col] = f2bf(fmaxf(acc[ct][1][r] + bb, 0.f));
        }
    }
}

// ---------------------------------------------------------------------------
// Attention, single pass, no max-subtraction (|logit| <~ 3 << 88, exp-safe;
// softmax shift-invariant). One wave per dst node. Lane l covers row elems
// [4l,4l+4) of both k and v via ONE 16B load from the interleaved kv row.
// Lanes 0..31 = head0, 32..63 = head1; intra-32 butterfly only.
// ---------------------------------------------------------------------------
__global__ __launch_bounds__(64) void attn_kernel(
    const unsigned short* __restrict__ q, const unsigned short* __restrict__ kv,
    const int* __restrict__ offs, const int* __restrict__ csr,
    unsigned short* __restrict__ hout) {
    const float SCALE = 0.08838834764831845f;  // 1/sqrt(128)
    int n = blockIdx.x, lane = threadIdx.x;
    ushort4 qu = ((const ushort4*)(q + (size_t)n * 256))[lane];
    float4 q4 = make_float4(bf2f(qu.x), bf2f(qu.y), bf2f(qu.z), bf2f(qu.w));
    int beg = offs[n], end = offs[n + 1];

    float4 acc = make_float4(0.f, 0.f, 0.f, 0.f);
    float d = 0.f;

    int j = beg;
    for (; j + 4 <= end; j += 4) {
        int s0 = csr[j], s1 = csr[j + 1], s2 = csr[j + 2], s3 = csr[j + 3];
        us8 c0 = ((const us8*)(kv + (size_t)s0 * 512))[lane];
        us8 c1 = ((const us8*)(kv + (size_t)s1 * 512))[lane];
        us8 c2 = ((const us8*)(kv + (size_t)s2 * 512))[lane];
        us8 c3 = ((const us8*)(kv + (size_t)s3 * 512))[lane];
        float p0 = q4.x * bf2f(c0[0]) + q4.y * bf2f(c0[1]) + q4.z * bf2f(c0[2]) + q4.w * bf2f(c0[3]);
        float p1 = q4.x * bf2f(c1[0]) + q4.y * bf2f(c1[1]) + q4.z * bf2f(c1[2]) + q4.w * bf2f(c1[3]);
        float p2 = q4.x * bf2f(c2[0]) + q4.y * bf2f(c2[1]) + q4.z * bf2f(c2[2]) + q4.w * bf2f(c2[3]);
        float p3 = q4.x * bf2f(c3[0]) + q4.y * bf2f(c3[1]) + q4.z * bf2f(c3[2]) + q4.w * bf2f(c3[3]);
        #pragma unroll
        for (int o = 16; o >= 1; o >>= 1) {
            p0 += __shfl_xor(p0, o);
            p1 += __shfl_xor(p1, o);
            p2 += __shfl_xor(p2, o);
            p3 += __shfl_xor(p3, o);
        }
        float e0 = __expf(p0 * SCALE), e1 = __expf(p1 * SCALE);
        float e2 = __expf(p2 * SCALE), e3 = __expf(p3 * SCALE);
        d += (e0 + e1) + (e2 + e3);
        acc.x = fmaf(e0, bf2f(c0[4]), fmaf(e1, bf2f(c1[4]), fmaf(e2, bf2f(c2[4]), fmaf(e3, bf2f(c3[4]), acc.x))));
        acc.y = fmaf(e0, bf2f(c0[5]), fmaf(e1, bf2f(c1[5]), fmaf(e2, bf2f(c2[5]), fmaf(e3, bf2f(c3[5]), acc.y))));
        acc.z = fmaf(e0, bf2f(c0[6]), fmaf(e1, bf2f(c1[6]), fmaf(e2, bf2f(c2[6]), fmaf(e3, bf2f(c3[6]), acc.z))));
        acc.w = fmaf(e0, bf2f(c0[7]), fmaf(e1, bf2f(c1[7]), fmaf(e2, bf2f(c2[7]), fmaf(e3, bf2f(c3[7]), acc.w))));
    }
    for (; j < end; j++) {
        int s = csr[j];
        us8 c = ((const us8*)(kv + (size_t)s * 512))[lane];
        float p = q4.x * bf2f(c[0]) + q4.y * bf2f(c[1]) + q4.z * bf2f(c[2]) + q4.w * bf2f(c[3]);
        #pragma unroll
        for (int o = 16; o >= 1; o >>= 1) p += __shfl_xor(p, o);
        float e = __expf(p * SCALE);
        d += e;
        acc.x = fmaf(e, bf2f(c[4]), acc.x);
        acc.y = fmaf(e, bf2f(c[5]), acc.y);
        acc.z = fmaf(e, bf2f(c[6]), acc.z);
        acc.w = fmaf(e, bf2f(c[7]), acc.w);
    }

    float inv = 1.f / (d + 1e-16f);
    ushort4 hv;
    hv.x = f2bf(acc.x * inv);
    hv.y = f2bf(acc.y * inv);
    hv.z = f2bf(acc.z * inv);
    hv.w = f2bf(acc.w * inv);
    ((ushort4*)(hout + (size_t)n * 256))[lane] = hv;
}

// ---------------------------------------------------------------------------
// Per-graph node counts via binary search over the SORTED graph_indices.
// ---------------------------------------------------------------------------
__global__ __launch_bounds__(64) void graph_count_kernel(const int* __restrict__ gi,
                                                         int* __restrict__ pcnt) {
    int g = threadIdx.x;   // 0..63
    auto lb = [&](int target) {
        int lo = 0, hi = N_NODES;
        while (lo < hi) {
            int mid = (lo + hi) >> 1;
            if (gi[mid] < target) lo = mid + 1;
            else hi = mid;
        }
        return lo;
    };
    int a = lb(g), b = lb(g + 1);
    pcnt[g] = b - a;
}

// ---------------------------------------------------------------------------
// Pooling from bf16 x. gi sorted -> per-run local accumulate, one atomic per
// (col, run). relu output >= 0 => uint atomicMax order-correct, 0 is identity.
// ---------------------------------------------------------------------------
__global__ __launch_bounds__(256) void pool_accum_kernel(
    const unsigned short* __restrict__ xb, const int* __restrict__ gi,
    float* __restrict__ psum, unsigned* __restrict__ pmax) {
    int n0 = blockIdx.x * 32;
    int col = threadIdx.x & 127, half = threadIdx.x >> 7;
    float sum = 0.f, mx = 0.f;
    int first = n0 + half;
    if (first >= N_NODES) return;
    int cur_g = gi[first];
    for (int r = half; r < 32; r += 2) {
        int n = n0 + r;
        if (n >= N_NODES) break;
        int g = gi[n];
        if (g != cur_g) {
            atomicAdd(&psum[cur_g * 128 + col], sum);
            atomicMax(&pmax[cur_g * 128 + col], __float_as_uint(mx));
            sum = 0.f; mx = 0.f; cur_g = g;
        }
        float v = bf2f(xb[(size_t)n * 128 + col]);
        sum += v;
        mx = fmaxf(mx, v);
    }
    atomicAdd(&psum[cur_g * 128 + col], sum);
    atomicMax(&pmax[cur_g * 128 + col], __float_as_uint(mx));
}

__global__ void pool_final_kernel(const float* __restrict__ psum, const unsigned* __restrict__ pmax,
                                  const int* __restrict__ pcnt, float* __restrict__ out) {
    int idx = blockIdx.x * 256 + threadIdx.x;
    if (idx >= NGRAPH * 384) return;
    int g = idx / 384, c = idx % 384;
    float r;
    if (c < 128)       r = __uint_as_float(pmax[g * 128 + c]);
    else if (c < 256)  r = psum[g * 128 + (c - 128)] / fmaxf((float)pcnt[g], 1.f);
    else               r = psum[g * 128 + (c - 256)];
    out[idx] = r;
}

// ---------------------------------------------------------------------------
extern "C" void kernel_launch(void* const* d_in, const int* in_sizes, int n_in,
                              void* d_out, int out_size, void* d_ws, size_t ws_size,
                              hipStream_t stream) {
    const float* x   = (const float*)d_in[0];
    const int*   ei  = (const int*)d_in[1];
    const int*   gi  = (const int*)d_in[2];
    const float* Wq  = (const float*)d_in[3];
    const float* bq  = (const float*)d_in[4];
    const float* Wk  = (const float*)d_in[5];
    const float* bk  = (const float*)d_in[6];
    const float* Wv  = (const float*)d_in[7];
    const float* bv  = (const float*)d_in[8];
    const float* Wsk = (const float*)d_in[9];
    const float* bsk = (const float*)d_in[10];
    const float* Wt  = (const float*)d_in[11];
    const float* bt  = (const float*)d_in[12];
    float* out = (float*)d_out;

    char* p = (char*)d_ws;
    auto take = [&](size_t bytes) -> char* {
        char* r = p;
        p += (bytes + 255) & ~(size_t)255;
        return r;
    };
    unsigned short* qbuf   = (unsigned short*)take((size_t)N_NODES * 256 * 2);  // q bf16
    unsigned short* kvbuf  = (unsigned short*)take((size_t)N_NODES * 512 * 2);  // interleaved k|v
    unsigned short* xb     = (unsigned short*)take((size_t)N_NODES * 128 * 2);  // layer0 A / final x
    unsigned short* xb2    = (unsigned short*)take((size_t)N_NODES * 128 * 2);  // layer1 A
    unsigned short* hb     = (unsigned short*)take((size_t)N_NODES * 256 * 2);  // attn out bf16
    unsigned short* Wqkvp  = (unsigned short*)take((size_t)196608 * 2);         // packed qkv
    unsigned short* Wfp    = (unsigned short*)take((size_t)98304 * 2);          // packed [Wt;Wc]
    float*          Wc     = (float*)take(2 * 128 * 128 * 4);
    float*          bc     = (float*)take(2 * 128 * 4);
    int*            counts = (int*)take((size_t)N_NODES * 4);
    int*            offs   = (int*)take((size_t)(N_NODES + 1) * 4);
    int*            cursor = (int*)take((size_t)N_NODES * 4);
    int*            csr    = (int*)take((size_t)N_EDGES * 4);
    int*            bsum   = (int*)take((size_t)SCAN_BLOCKS * 4);
    int*            boff   = (int*)take((size_t)SCAN_BLOCKS * 4);
    float*          psum   = (float*)take(NGRAPH * 128 * 4);
    unsigned*       pmax   = (unsigned*)take(NGRAPH * 128 * 4);
    int*            pcnt   = (int*)take(NGRAPH * 4);

    const int EB = (N_EDGES + 255) / 256;          // 3125
    const int GB = (N_NODES + 127) / 128;          // 391  (MFMA GEMM blocks)
    const int PB = (N_NODES + 31) / 32;            // 1563 (pooling blocks)

    // ---- CSR build ----
    hipMemsetAsync(counts, 0, (size_t)N_NODES * 4, stream);
    degree_kernel<<<EB, 256, 0, stream>>>(ei, counts);
    block_sum_kernel<<<SCAN_BLOCKS, 256, 0, stream>>>(counts, bsum);
    scan_bsum_kernel<<<1, 256, 0, stream>>>(bsum, boff);
    block_scan_kernel<<<SCAN_BLOCKS, 256, 0, stream>>>(counts, boff, offs, cursor);
    scatter_kernel<<<EB, 256, 0, stream>>>(ei, cursor, csr);

    // ---- weight prep ----
    wc_kernel<<<128, 256, 0, stream>>>(Wsk, Wt, Wc);
    bc_kernel<<<1, 256, 0, stream>>>(bsk, Wt, bt, bc);
    pack_qkv_kernel<<<768, 256, 0, stream>>>(Wq, Wk, Wv, Wqkvp);
    pack_fused_kernel<<<384, 256, 0, stream>>>(Wt, Wc, Wfp);
    f2bf_kernel<<<(N_NODES * 32 + 255) / 256, 256, 0, stream>>>(x, xb, N_NODES * 32);

    // ---- layer 0 ----
    proj_mfma_kernel<<<GB, 256, 0, stream>>>(xb, Wqkvp, bq, bk, bv, qbuf, kvbuf);
    attn_kernel<<<N_NODES, 64, 0, stream>>>(qbuf, kvbuf, offs, csr, hb);
    out_mfma_kernel<<<GB, 256, 0, stream>>>(hb, xb, Wfp, bc, xb2);

    // ---- layer 1 ----
    proj_mfma_kernel<<<GB, 256, 0, stream>>>(xb2, Wqkvp + 98304, bq + 256, bk + 256, bv + 256,
                                             qbuf, kvbuf);
    attn_kernel<<<N_NODES, 64, 0, stream>>>(qbuf, kvbuf, offs, csr, hb);
    out_mfma_kernel<<<GB, 256, 0, stream>>>(hb, xb2, Wfp + 49152, bc + 128, xb);

    // ---- pooling (reads bf16 x, fp32 accumulate; counts via binary search) ----
    hipMemsetAsync(psum, 0, NGRAPH * 128 * 4, stream);
    hipMemsetAsync(pmax, 0, NGRAPH * 128 * 4, stream);
    graph_count_kernel<<<1, 64, 0, stream>>>(gi, pcnt);
    pool_accum_kernel<<<PB, 256, 0, stream>>>(xb, gi, psum, pmax);
    pool_final_kernel<<<(NGRAPH * 384 + 255) / 256, 256, 0, stream>>>(psum, pmax, pcnt, out);
}

// Round 8
// 632.526 us; speedup vs baseline: 1.0179x; 1.0179x over previous
//
#include <hip/hip_runtime.h>
#include <math.h>

#define N_NODES 50000
#define N_EDGES 800000
#define NGRAPH  64
#define SCAN_BLOCKS ((N_NODES + 255) / 256)   // 196

typedef __bf16 bf16x8 __attribute__((ext_vector_type(8)));
typedef float  f32x4  __attribute__((ext_vector_type(4)));
typedef unsigned short us8 __attribute__((ext_vector_type(8)));

__device__ __forceinline__ unsigned short f2bf(float f) {
    unsigned u = __float_as_uint(f);
    u += 0x7fff + ((u >> 16) & 1);          // round-to-nearest-even
    return (unsigned short)(u >> 16);
}
__device__ __forceinline__ float bf2f(unsigned short u) {
    return __uint_as_float((unsigned)u << 16);
}

// ---------------------------------------------------------------------------
// CSR build
// ---------------------------------------------------------------------------
__global__ void degree_kernel(const int* __restrict__ ei, int* __restrict__ counts) {
    int e = blockIdx.x * 256 + threadIdx.x;
    if (e < N_EDGES) atomicAdd(&counts[ei[N_EDGES + e]], 1);
}

__global__ __launch_bounds__(256) void block_sum_kernel(const int* __restrict__ counts,
                                                        int* __restrict__ bsum) {
    int i = blockIdx.x * 256 + threadIdx.x;
    int v = (i < N_NODES) ? counts[i] : 0;
    #pragma unroll
    for (int o = 32; o >= 1; o >>= 1) v += __shfl_xor(v, o);
    __shared__ int ws[4];
    if ((threadIdx.x & 63) == 0) ws[threadIdx.x >> 6] = v;
    __syncthreads();
    if (threadIdx.x == 0) bsum[blockIdx.x] = ws[0] + ws[1] + ws[2] + ws[3];
}

__global__ __launch_bounds__(256) void scan_bsum_kernel(const int* __restrict__ bsum,
                                                        int* __restrict__ boff) {
    int t = threadIdx.x;
    int v = (t < SCAN_BLOCKS) ? bsum[t] : 0;
    int lane = t & 63, wid = t >> 6;
    int incl = v;
    #pragma unroll
    for (int o = 1; o < 64; o <<= 1) {
        int tv = __shfl_up(incl, o);
        if (lane >= o) incl += tv;
    }
    __shared__ int wsum[4];
    if (lane == 63) wsum[wid] = incl;
    __syncthreads();
    int add = 0;
    for (int w = 0; w < wid; w++) add += wsum[w];
    if (t < SCAN_BLOCKS) boff[t] = add + incl - v;   // exclusive
}

__global__ __launch_bounds__(256) void block_scan_kernel(const int* __restrict__ counts,
                                                         const int* __restrict__ boff,
                                                         int* __restrict__ offs,
                                                         int* __restrict__ cursor) {
    int i = blockIdx.x * 256 + threadIdx.x;
    int v = (i < N_NODES) ? counts[i] : 0;
    int lane = threadIdx.x & 63, wid = threadIdx.x >> 6;
    int incl = v;
    #pragma unroll
    for (int o = 1; o < 64; o <<= 1) {
        int tv = __shfl_up(incl, o);
        if (lane >= o) incl += tv;
    }
    __shared__ int wsum[4];
    if (lane == 63) wsum[wid] = incl;
    __syncthreads();
    int add = boff[blockIdx.x];
    for (int w = 0; w < wid; w++) add += wsum[w];
    if (i < N_NODES) {
        offs[i + 1] = add + incl;
        cursor[i]   = add + incl - v;
    }
    if (i == 0) offs[0] = 0;
}

__global__ void scatter_kernel(const int* __restrict__ ei, int* __restrict__ cursor,
                               int* __restrict__ csr) {
    int e = blockIdx.x * 256 + threadIdx.x;
    if (e < N_EDGES) {
        int d = ei[N_EDGES + e];
        int pos = atomicAdd(&cursor[d], 1);
        csr[pos] = ei[e];  // src
    }
}

// ---------------------------------------------------------------------------
// Skip-path fusion (fp32): Wc[l] = Ws[l] @ Wt[l], bc[l] = bs[l] @ Wt[l] + bt[l]
// ---------------------------------------------------------------------------
__global__ void wc_kernel(const float* __restrict__ Ws, const float* __restrict__ Wt,
                          float* __restrict__ Wc) {
    int idx = blockIdx.x * 256 + threadIdx.x;       // 2*128*128 = 32768
    int l = idx >> 14, ij = idx & 16383, i = ij >> 7, j = ij & 127;
    const float* a = Ws + (size_t)l * 32768;
    const float* b = Wt + (size_t)l * 32768;
    float s = 0.f;
    for (int k = 0; k < 256; k++) s = fmaf(a[i * 256 + k], b[k * 128 + j], s);
    Wc[idx] = s;
}

__global__ void bc_kernel(const float* __restrict__ bs, const float* __restrict__ Wt,
                          const float* __restrict__ bt, float* __restrict__ bc) {
    int idx = threadIdx.x;                           // 2 layers x 128
    int l = idx >> 7, j = idx & 127;
    const float* b = Wt + (size_t)l * 32768;
    float s = bt[l * 128 + j];
    for (int k = 0; k < 256; k++) s = fmaf(bs[l * 256 + k], b[k * 128 + j], s);
    bc[idx] = s;
}

// ---------------------------------------------------------------------------
// Weight packing into MFMA fragment layout (bf16, ks-major). A- and B-frag
// layouts are symmetric (lane&15 -> matrix dim, quad*8+j -> k), so this same
// packing serves as the A operand in the swapped (A=W, B=x) GEMMs.
// ---------------------------------------------------------------------------
__global__ void pack_qkv_kernel(const float* __restrict__ Wq, const float* __restrict__ Wk,
                                const float* __restrict__ Wv, unsigned short* __restrict__ out) {
    int idx = blockIdx.x * 256 + threadIdx.x;        // 2*3*32768 = 196608
    if (idx >= 196608) return;
    int j = idx & 7, lane = (idx >> 3) & 63, ct = (idx >> 9) & 15, ks = (idx >> 13) & 3;
    int m3 = idx >> 15;                              // 0..5
    int l = m3 / 3, m = m3 % 3;
    int k = ks * 32 + ((lane >> 4) * 8) + j;
    int n = ct * 16 + (lane & 15);
    const float* W = (m == 0) ? Wq : (m == 1) ? Wk : Wv;
    out[idx] = f2bf(W[(size_t)l * 32768 + k * 256 + n]);
}

// fused [Wt;Wc] (K=384): KS=12 (ks 0..7 from Wt, 8..11 from Wc), CT=8
__global__ void pack_fused_kernel(const float* __restrict__ Wt, const float* __restrict__ Wc,
                                  unsigned short* __restrict__ out) {
    int idx = blockIdx.x * 256 + threadIdx.x;        // 2*49152 = 98304
    if (idx >= 98304) return;
    int l = idx / 49152, r = idx % 49152;
    int j = r & 7, lane = (r >> 3) & 63;
    int rest = r >> 9;
    int ct = rest & 7, ks = rest >> 3;               // ks 0..11
    int k = ks * 32 + ((lane >> 4) * 8) + j;
    int n = ct * 16 + (lane & 15);
    float v = (k < 256) ? Wt[(size_t)l * 32768 + k * 128 + n]
                        : Wc[(size_t)l * 16384 + (k - 256) * 128 + n];
    out[idx] = f2bf(v);
}

// fp32 -> bf16 elementwise (x input), 4 elems/thread
__global__ void f2bf_kernel(const float* __restrict__ in, unsigned short* __restrict__ out, int n4) {
    int i = blockIdx.x * 256 + threadIdx.x;
    if (i >= n4) return;
    float4 v = ((const float4*)in)[i];
    ushort4 o;
    o.x = f2bf(v.x); o.y = f2bf(v.y); o.z = f2bf(v.z); o.w = f2bf(v.w);
    ((ushort4*)out)[i] = o;
}

// ---------------------------------------------------------------------------
// MFMA q/k/v projection, swapped operands: A = W (packed frags), B = x rows.
// C layout: lane&15 = node, quad*4+r = 4 CONSECUTIVE out-channels -> each
// store is one ushort4 (8B/lane). q bf16 [N,256]; kv fine-interleaved rows:
// chunk c (8 shorts) = [k[4c..4c+3] | v[4c..4c+3]].
// ---------------------------------------------------------------------------
__global__ __launch_bounds__(256) void proj_mfma_kernel(
    const unsigned short* __restrict__ xb, const unsigned short* __restrict__ Wp,
    const float* __restrict__ b0, const float* __restrict__ b1, const float* __restrict__ b2,
    unsigned short* __restrict__ oq, unsigned short* __restrict__ kv) {
    int w = threadIdx.x >> 6, lane = threadIdx.x & 63;
    int quad = lane >> 4, lr = lane & 15;
    int rbase = blockIdx.x * 128 + w * 32;
    int n0 = rbase + lr, n1 = rbase + 16 + lr;
    int n0c = min(n0, N_NODES - 1), n1c = min(n1, N_NODES - 1);

    bf16x8 a0[4], a1[4];                 // B-operand fragments (x rows)
    #pragma unroll
    for (int ks = 0; ks < 4; ks++) {
        a0[ks] = *(const bf16x8*)(xb + (size_t)n0c * 128 + ks * 32 + quad * 8);
        a1[ks] = *(const bf16x8*)(xb + (size_t)n1c * 128 + ks * 32 + quad * 8);
    }

    const float* bias[3] = {b0, b1, b2};
    for (int mm = 0; mm < 3; mm++) {
        const unsigned short* wp = Wp + mm * 32768;
        for (int ct = 0; ct < 16; ct++) {
            f32x4 c0 = {0.f, 0.f, 0.f, 0.f}, c1 = {0.f, 0.f, 0.f, 0.f};
            #pragma unroll
            for (int ks = 0; ks < 4; ks++) {
                bf16x8 wf = *(const bf16x8*)(wp + (size_t)((ks * 16 + ct) * 64 + lane) * 8);
                c0 = __builtin_amdgcn_mfma_f32_16x16x32_bf16(wf, a0[ks], c0, 0, 0, 0);
                c1 = __builtin_amdgcn_mfma_f32_16x16x32_bf16(wf, a1[ks], c1, 0, 0, 0);
            }
            int ob = ct * 16 + quad * 4;                 // out-ch base (mult of 4)
            float4 bb = *(const float4*)&bias[mm][ob];
            ushort4 s0, s1;
            s0.x = f2bf(c0[0] + bb.x); s0.y = f2bf(c0[1] + bb.y);
            s0.z = f2bf(c0[2] + bb.z); s0.w = f2bf(c0[3] + bb.w);
            s1.x = f2bf(c1[0] + bb.x); s1.y = f2bf(c1[1] + bb.y);
            s1.z = f2bf(c1[2] + bb.z); s1.w = f2bf(c1[3] + bb.w);
            if (mm == 0) {
                if (n0 < N_NODES) *(ushort4*)(oq + (size_t)n0 * 256 + ob) = s0;
                if (n1 < N_NODES) *(ushort4*)(oq + (size_t)n1 * 256 + ob) = s1;
            } else {
                int kvo = (ob >> 2) * 8 + ((mm == 2) ? 4 : 0);
                if (n0 < N_NODES) *(ushort4*)(kv + (size_t)n0 * 512 + kvo) = s0;
                if (n1 < N_NODES) *(ushort4*)(kv + (size_t)n1 * 512 + kvo) = s1;
            }
        }
    }
}

// ---------------------------------------------------------------------------
// MFMA output linear, swapped operands: x_next = relu([h|x] @ [Wt;Wc] + bc).
// ushort4 stores (4 consecutive out-cols per lane).
// ---------------------------------------------------------------------------
__global__ __launch_bounds__(256) void out_mfma_kernel(
    const unsigned short* __restrict__ hb, const unsigned short* __restrict__ xb,
    const unsigned short* __restrict__ Wfp, const float* __restrict__ bc,
    unsigned short* __restrict__ xbout) {
    int w = threadIdx.x >> 6, lane = threadIdx.x & 63;
    int quad = lane >> 4, lr = lane & 15;
    int rbase = blockIdx.x * 128 + w * 32;
    int n0 = rbase + lr, n1 = rbase + 16 + lr;
    int n0c = min(n0, N_NODES - 1), n1c = min(n1, N_NODES - 1);

    f32x4 acc[8][2];
    #pragma unroll
    for (int ct = 0; ct < 8; ct++) {
        acc[ct][0] = (f32x4){0.f, 0.f, 0.f, 0.f};
        acc[ct][1] = (f32x4){0.f, 0.f, 0.f, 0.f};
    }

    #pragma unroll 4
    for (int ks = 0; ks < 12; ks++) {
        bf16x8 a0, a1;
        if (ks < 8) {
            a0 = *(const bf16x8*)(hb + (size_t)n0c * 256 + ks * 32 + quad * 8);
            a1 = *(const bf16x8*)(hb + (size_t)n1c * 256 + ks * 32 + quad * 8);
        } else {
            a0 = *(const bf16x8*)(xb + (size_t)n0c * 128 + (ks - 8) * 32 + quad * 8);
            a1 = *(const bf16x8*)(xb + (size_t)n1c * 128 + (ks - 8) * 32 + quad * 8);
        }
        #pragma unroll
        for (int ct = 0; ct < 8; ct++) {
            bf16x8 wf = *(const bf16x8*)(Wfp + (size_t)((ks * 8 + ct) * 64 + lane) * 8);
            acc[ct][0] = __builtin_amdgcn_mfma_f32_16x16x32_bf16(wf, a0, acc[ct][0], 0, 0, 0);
            acc[ct][1] = __builtin_amdgcn_mfma_f32_16x16x32_bf16(wf, a1, acc[ct][1], 0, 0, 0);
        }
    }

    #pragma unroll
    for (int ct = 0; ct < 8; ct++) {
        int ob = ct * 16 + quad * 4;
        float4 bb = *(const float4*)&bc[ob];
        ushort4 s0, s1;
        s0.x = f2bf(fmaxf(acc[ct][0][0] + bb.x, 0.f));
        s0.y = f2bf(fmaxf(acc[ct][0][1] + bb.y, 0.f));
        s0.z = f2bf(fmaxf(acc[ct][0][2] + bb.z, 0.f));
        s0.w = f2bf(fmaxf(acc[ct][0][3] + bb.w, 0.f));
        s1.x = f2bf(fmaxf(acc[ct][1][0] + bb.x, 0.f));
        s1.y = f2bf(fmaxf(acc[ct][1][1] + bb.y, 0.f));
        s1.z = f2bf(fmaxf(acc[ct][1][2] + bb.z, 0.f));
        s1.w = f2bf(fmaxf(acc[ct][1][3] + bb.w, 0.f));
        if (n0 < N_NODES) *(ushort4*)(xbout + (size_t)n0 * 128 + ob) = s0;
        if (n1 < N_NODES) *(ushort4*)(xbout + (size_t)n1 * 128 + ob) = s1;
    }
}

// ---------------------------------------------------------------------------
// Attention (unchanged — at the scattered-read ceiling ~3.5 TB/s).
// Single pass, no max-subtraction; one wave per dst node; lane l reads the
// whole edge slice (k+v) in ONE 16B load from the interleaved kv row.
// ---------------------------------------------------------------------------
__global__ __launch_bounds__(64) void attn_kernel(
    const unsigned short* __restrict__ q, const unsigned short* __restrict__ kv,
    const int* __restrict__ offs, const int* __restrict__ csr,
    unsigned short* __restrict__ hout) {
    const float SCALE = 0.08838834764831845f;  // 1/sqrt(128)
    int n = blockIdx.x, lane = threadIdx.x;
    ushort4 qu = ((const ushort4*)(q + (size_t)n * 256))[lane];
    float4 q4 = make_float4(bf2f(qu.x), bf2f(qu.y), bf2f(qu.z), bf2f(qu.w));
    int beg = offs[n], end = offs[n + 1];

    float4 acc = make_float4(0.f, 0.f, 0.f, 0.f);
    float d = 0.f;

    int j = beg;
    for (; j + 4 <= end; j += 4) {
        int s0 = csr[j], s1 = csr[j + 1], s2 = csr[j + 2], s3 = csr[j + 3];
        us8 c0 = ((const us8*)(kv + (size_t)s0 * 512))[lane];
        us8 c1 = ((const us8*)(kv + (size_t)s1 * 512))[lane];
        us8 c2 = ((const us8*)(kv + (size_t)s2 * 512))[lane];
        us8 c3 = ((const us8*)(kv + (size_t)s3 * 512))[lane];
        float p0 = q4.x * bf2f(c0[0]) + q4.y * bf2f(c0[1]) + q4.z * bf2f(c0[2]) + q4.w * bf2f(c0[3]);
        float p1 = q4.x * bf2f(c1[0]) + q4.y * bf2f(c1[1]) + q4.z * bf2f(c1[2]) + q4.w * bf2f(c1[3]);
        float p2 = q4.x * bf2f(c2[0]) + q4.y * bf2f(c2[1]) + q4.z * bf2f(c2[2]) + q4.w * bf2f(c2[3]);
        float p3 = q4.x * bf2f(c3[0]) + q4.y * bf2f(c3[1]) + q4.z * bf2f(c3[2]) + q4.w * bf2f(c3[3]);
        #pragma unroll
        for (int o = 16; o >= 1; o >>= 1) {
            p0 += __shfl_xor(p0, o);
            p1 += __shfl_xor(p1, o);
            p2 += __shfl_xor(p2, o);
            p3 += __shfl_xor(p3, o);
        }
        float e0 = __expf(p0 * SCALE), e1 = __expf(p1 * SCALE);
        float e2 = __expf(p2 * SCALE), e3 = __expf(p3 * SCALE);
        d += (e0 + e1) + (e2 + e3);
        acc.x = fmaf(e0, bf2f(c0[4]), fmaf(e1, bf2f(c1[4]), fmaf(e2, bf2f(c2[4]), fmaf(e3, bf2f(c3[4]), acc.x))));
        acc.y = fmaf(e0, bf2f(c0[5]), fmaf(e1, bf2f(c1[5]), fmaf(e2, bf2f(c2[5]), fmaf(e3, bf2f(c3[5]), acc.y))));
        acc.z = fmaf(e0, bf2f(c0[6]), fmaf(e1, bf2f(c1[6]), fmaf(e2, bf2f(c2[6]), fmaf(e3, bf2f(c3[6]), acc.z))));
        acc.w = fmaf(e0, bf2f(c0[7]), fmaf(e1, bf2f(c1[7]), fmaf(e2, bf2f(c2[7]), fmaf(e3, bf2f(c3[7]), acc.w))));
    }
    for (; j < end; j++) {
        int s = csr[j];
        us8 c = ((const us8*)(kv + (size_t)s * 512))[lane];
        float p = q4.x * bf2f(c[0]) + q4.y * bf2f(c[1]) + q4.z * bf2f(c[2]) + q4.w * bf2f(c[3]);
        #pragma unroll
        for (int o = 16; o >= 1; o >>= 1) p += __shfl_xor(p, o);
        float e = __expf(p * SCALE);
        d += e;
        acc.x = fmaf(e, bf2f(c[4]), acc.x);
        acc.y = fmaf(e, bf2f(c[5]), acc.y);
        acc.z = fmaf(e, bf2f(c[6]), acc.z);
        acc.w = fmaf(e, bf2f(c[7]), acc.w);
    }

    float inv = 1.f / (d + 1e-16f);
    ushort4 hv;
    hv.x = f2bf(acc.x * inv);
    hv.y = f2bf(acc.y * inv);
    hv.z = f2bf(acc.z * inv);
    hv.w = f2bf(acc.w * inv);
    ((ushort4*)(hout + (size_t)n * 256))[lane] = hv;
}

// ---------------------------------------------------------------------------
// Per-graph node counts via binary search over the SORTED graph_indices.
// ---------------------------------------------------------------------------
__global__ __launch_bounds__(64) void graph_count_kernel(const int* __restrict__ gi,
                                                         int* __restrict__ pcnt) {
    int g = threadIdx.x;   // 0..63
    auto lb = [&](int target) {
        int lo = 0, hi = N_NODES;
        while (lo < hi) {
            int mid = (lo + hi) >> 1;
            if (gi[mid] < target) lo = mid + 1;
            else hi = mid;
        }
        return lo;
    };
    int a = lb(g), b = lb(g + 1);
    pcnt[g] = b - a;
}

// ---------------------------------------------------------------------------
// Pooling from bf16 x, ushort4-vectorized. Block covers 128 nodes; thread
// (col-group, phase) walks nodes stride-8, accumulating per-graph runs
// locally (gi sorted), flushing 4 cols per run boundary.
// ---------------------------------------------------------------------------
__global__ __launch_bounds__(256) void pool_accum_kernel(
    const unsigned short* __restrict__ xb, const int* __restrict__ gi,
    float* __restrict__ psum, unsigned* __restrict__ pmax) {
    int n0 = blockIdx.x * 128;
    int c4 = (threadIdx.x & 31) * 4;        // 4 consecutive cols
    int phase = threadIdx.x >> 5;           // 0..7
    int first = n0 + phase;
    if (first >= N_NODES) return;
    float s0 = 0.f, s1 = 0.f, s2 = 0.f, s3 = 0.f;
    float m0 = 0.f, m1 = 0.f, m2 = 0.f, m3 = 0.f;
    int cur_g = gi[first];
    for (int r = phase; r < 128; r += 8) {
        int n = n0 + r;
        if (n >= N_NODES) break;
        int g = gi[n];
        if (g != cur_g) {
            float* ps = &psum[cur_g * 128 + c4];
            unsigned* pm = &pmax[cur_g * 128 + c4];
            atomicAdd(ps + 0, s0); atomicAdd(ps + 1, s1);
            atomicAdd(ps + 2, s2); atomicAdd(ps + 3, s3);
            atomicMax(pm + 0, __float_as_uint(m0)); atomicMax(pm + 1, __float_as_uint(m1));
            atomicMax(pm + 2, __float_as_uint(m2)); atomicMax(pm + 3, __float_as_uint(m3));
            s0 = s1 = s2 = s3 = 0.f;
            m0 = m1 = m2 = m3 = 0.f;
            cur_g = g;
        }
        ushort4 u = *(const ushort4*)(xb + (size_t)n * 128 + c4);
        float v0 = bf2f(u.x), v1 = bf2f(u.y), v2 = bf2f(u.z), v3 = bf2f(u.w);
        s0 += v0; s1 += v1; s2 += v2; s3 += v3;
        m0 = fmaxf(m0, v0); m1 = fmaxf(m1, v1);
        m2 = fmaxf(m2, v2); m3 = fmaxf(m3, v3);
    }
    float* ps = &psum[cur_g * 128 + c4];
    unsigned* pm = &pmax[cur_g * 128 + c4];
    atomicAdd(ps + 0, s0); atomicAdd(ps + 1, s1);
    atomicAdd(ps + 2, s2); atomicAdd(ps + 3, s3);
    atomicMax(pm + 0, __float_as_uint(m0)); atomicMax(pm + 1, __float_as_uint(m1));
    atomicMax(pm + 2, __float_as_uint(m2)); atomicMax(pm + 3, __float_as_uint(m3));
}

__global__ void pool_final_kernel(const float* __restrict__ psum, const unsigned* __restrict__ pmax,
                                  const int* __restrict__ pcnt, float* __restrict__ out) {
    int idx = blockIdx.x * 256 + threadIdx.x;
    if (idx >= NGRAPH * 384) return;
    int g = idx / 384, c = idx % 384;
    float r;
    if (c < 128)       r = __uint_as_float(pmax[g * 128 + c]);
    else if (c < 256)  r = psum[g * 128 + (c - 128)] / fmaxf((float)pcnt[g], 1.f);
    else               r = psum[g * 128 + (c - 256)];
    out[idx] = r;
}

// ---------------------------------------------------------------------------
extern "C" void kernel_launch(void* const* d_in, const int* in_sizes, int n_in,
                              void* d_out, int out_size, void* d_ws, size_t ws_size,
                              hipStream_t stream) {
    const float* x   = (const float*)d_in[0];
    const int*   ei  = (const int*)d_in[1];
    const int*   gi  = (const int*)d_in[2];
    const float* Wq  = (const float*)d_in[3];
    const float* bq  = (const float*)d_in[4];
    const float* Wk  = (const float*)d_in[5];
    const float* bk  = (const float*)d_in[6];
    const float* Wv  = (const float*)d_in[7];
    const float* bv  = (const float*)d_in[8];
    const float* Wsk = (const float*)d_in[9];
    const float* bsk = (const float*)d_in[10];
    const float* Wt  = (const float*)d_in[11];
    const float* bt  = (const float*)d_in[12];
    float* out = (float*)d_out;

    char* p = (char*)d_ws;
    auto take = [&](size_t bytes) -> char* {
        char* r = p;
        p += (bytes + 255) & ~(size_t)255;
        return r;
    };
    unsigned short* qbuf   = (unsigned short*)take((size_t)N_NODES * 256 * 2);  // q bf16
    unsigned short* kvbuf  = (unsigned short*)take((size_t)N_NODES * 512 * 2);  // interleaved k|v
    unsigned short* xb     = (unsigned short*)take((size_t)N_NODES * 128 * 2);  // layer0 A / final x
    unsigned short* xb2    = (unsigned short*)take((size_t)N_NODES * 128 * 2);  // layer1 A
    unsigned short* hb     = (unsigned short*)take((size_t)N_NODES * 256 * 2);  // attn out bf16
    unsigned short* Wqkvp  = (unsigned short*)take((size_t)196608 * 2);         // packed qkv
    unsigned short* Wfp    = (unsigned short*)take((size_t)98304 * 2);          // packed [Wt;Wc]
    float*          Wc     = (float*)take(2 * 128 * 128 * 4);
    float*          bc     = (float*)take(2 * 128 * 4);
    int*            counts = (int*)take((size_t)N_NODES * 4);
    int*            offs   = (int*)take((size_t)(N_NODES + 1) * 4);
    int*            cursor = (int*)take((size_t)N_NODES * 4);
    int*            csr    = (int*)take((size_t)N_EDGES * 4);
    int*            bsum   = (int*)take((size_t)SCAN_BLOCKS * 4);
    int*            boff   = (int*)take((size_t)SCAN_BLOCKS * 4);
    float*          psum   = (float*)take(NGRAPH * 128 * 4);
    unsigned*       pmax   = (unsigned*)take(NGRAPH * 128 * 4);
    int*            pcnt   = (int*)take(NGRAPH * 4);

    const int EB = (N_EDGES + 255) / 256;          // 3125
    const int GB = (N_NODES + 127) / 128;          // 391  (MFMA GEMM blocks)
    const int PB = (N_NODES + 127) / 128;          // 391  (pooling blocks)

    // ---- CSR build ----
    hipMemsetAsync(counts, 0, (size_t)N_NODES * 4, stream);
    degree_kernel<<<EB, 256, 0, stream>>>(ei, counts);
    block_sum_kernel<<<SCAN_BLOCKS, 256, 0, stream>>>(counts, bsum);
    scan_bsum_kernel<<<1, 256, 0, stream>>>(bsum, boff);
    block_scan_kernel<<<SCAN_BLOCKS, 256, 0, stream>>>(counts, boff, offs, cursor);
    scatter_kernel<<<EB, 256, 0, stream>>>(ei, cursor, csr);

    // ---- weight prep ----
    wc_kernel<<<128, 256, 0, stream>>>(Wsk, Wt, Wc);
    bc_kernel<<<1, 256, 0, stream>>>(bsk, Wt, bt, bc);
    pack_qkv_kernel<<<768, 256, 0, stream>>>(Wq, Wk, Wv, Wqkvp);
    pack_fused_kernel<<<384, 256, 0, stream>>>(Wt, Wc, Wfp);
    f2bf_kernel<<<(N_NODES * 32 + 255) / 256, 256, 0, stream>>>(x, xb, N_NODES * 32);

    // ---- layer 0 ----
    proj_mfma_kernel<<<GB, 256, 0, stream>>>(xb, Wqkvp, bq, bk, bv, qbuf, kvbuf);
    attn_kernel<<<N_NODES, 64, 0, stream>>>(qbuf, kvbuf, offs, csr, hb);
    out_mfma_kernel<<<GB, 256, 0, stream>>>(hb, xb, Wfp, bc, xb2);

    // ---- layer 1 ----
    proj_mfma_kernel<<<GB, 256, 0, stream>>>(xb2, Wqkvp + 98304, bq + 256, bk + 256, bv + 256,
                                             qbuf, kvbuf);
    attn_kernel<<<N_NODES, 64, 0, stream>>>(qbuf, kvbuf, offs, csr, hb);
    out_mfma_kernel<<<GB, 256, 0, stream>>>(hb, xb2, Wfp + 49152, bc + 128, xb);

    // ---- pooling (bf16 reads, fp32 accumulate; counts via binary search) ----
    hipMemsetAsync(psum, 0, NGRAPH * 128 * 4, stream);
    hipMemsetAsync(pmax, 0, NGRAPH * 128 * 4, stream);
    graph_count_kernel<<<1, 64, 0, stream>>>(gi, pcnt);
    pool_accum_kernel<<<PB, 256, 0, stream>>>(xb, gi, psum, pmax);
    pool_final_kernel<<<(NGRAPH * 384 + 255) / 256, 256, 0, stream>>>(psum, pmax, pcnt, out);
}

// Round 9
// 602.662 us; speedup vs baseline: 1.0683x; 1.0496x over previous
//
#include <hip/hip_runtime.h>
#include <math.h>

#define N_NODES 50000
#define N_EDGES 800000
#define NGRAPH  64
#define SCAN_BLOCKS ((N_NODES + 255) / 256)   // 196
#define LROW 136   // LDS x-tile row stride (shorts): 272B -> bank step 4, 2-way max

typedef __bf16 bf16x8 __attribute__((ext_vector_type(8)));
typedef float  f32x4  __attribute__((ext_vector_type(4)));
typedef unsigned short us8 __attribute__((ext_vector_type(8)));

__device__ __forceinline__ unsigned short f2bf(float f) {
    unsigned u = __float_as_uint(f);
    u += 0x7fff + ((u >> 16) & 1);          // round-to-nearest-even
    return (unsigned short)(u >> 16);
}
__device__ __forceinline__ float bf2f(unsigned short u) {
    return __uint_as_float((unsigned)u << 16);
}

// ---------------------------------------------------------------------------
// CSR build
// ---------------------------------------------------------------------------
__global__ void degree_kernel(const int* __restrict__ ei, int* __restrict__ counts) {
    int e = blockIdx.x * 256 + threadIdx.x;
    if (e < N_EDGES) atomicAdd(&counts[ei[N_EDGES + e]], 1);
}

__global__ __launch_bounds__(256) void block_sum_kernel(const int* __restrict__ counts,
                                                        int* __restrict__ bsum) {
    int i = blockIdx.x * 256 + threadIdx.x;
    int v = (i < N_NODES) ? counts[i] : 0;
    #pragma unroll
    for (int o = 32; o >= 1; o >>= 1) v += __shfl_xor(v, o);
    __shared__ int ws[4];
    if ((threadIdx.x & 63) == 0) ws[threadIdx.x >> 6] = v;
    __syncthreads();
    if (threadIdx.x == 0) bsum[blockIdx.x] = ws[0] + ws[1] + ws[2] + ws[3];
}

__global__ __launch_bounds__(256) void scan_bsum_kernel(const int* __restrict__ bsum,
                                                        int* __restrict__ boff) {
    int t = threadIdx.x;
    int v = (t < SCAN_BLOCKS) ? bsum[t] : 0;
    int lane = t & 63, wid = t >> 6;
    int incl = v;
    #pragma unroll
    for (int o = 1; o < 64; o <<= 1) {
        int tv = __shfl_up(incl, o);
        if (lane >= o) incl += tv;
    }
    __shared__ int wsum[4];
    if (lane == 63) wsum[wid] = incl;
    __syncthreads();
    int add = 0;
    for (int w = 0; w < wid; w++) add += wsum[w];
    if (t < SCAN_BLOCKS) boff[t] = add + incl - v;   // exclusive
}

__global__ __launch_bounds__(256) void block_scan_kernel(const int* __restrict__ counts,
                                                         const int* __restrict__ boff,
                                                         int* __restrict__ offs,
                                                         int* __restrict__ cursor) {
    int i = blockIdx.x * 256 + threadIdx.x;
    int v = (i < N_NODES) ? counts[i] : 0;
    int lane = threadIdx.x & 63, wid = threadIdx.x >> 6;
    int incl = v;
    #pragma unroll
    for (int o = 1; o < 64; o <<= 1) {
        int tv = __shfl_up(incl, o);
        if (lane >= o) incl += tv;
    }
    __shared__ int wsum[4];
    if (lane == 63) wsum[wid] = incl;
    __syncthreads();
    int add = boff[blockIdx.x];
    for (int w = 0; w < wid; w++) add += wsum[w];
    if (i < N_NODES) {
        offs[i + 1] = add + incl;
        cursor[i]   = add + incl - v;
    }
    if (i == 0) offs[0] = 0;
}

__global__ void scatter_kernel(const int* __restrict__ ei, int* __restrict__ cursor,
                               int* __restrict__ csr) {
    int e = blockIdx.x * 256 + threadIdx.x;
    if (e < N_EDGES) {
        int d = ei[N_EDGES + e];
        int pos = atomicAdd(&cursor[d], 1);
        csr[pos] = ei[e];  // src
    }
}

// ---------------------------------------------------------------------------
// Skip-path fusion (fp32): Wc[l] = Ws[l] @ Wt[l], bc[l] = bs[l] @ Wt[l] + bt[l]
// ---------------------------------------------------------------------------
__global__ void wc_kernel(const float* __restrict__ Ws, const float* __restrict__ Wt,
                          float* __restrict__ Wc) {
    int idx = blockIdx.x * 256 + threadIdx.x;       // 2*128*128 = 32768
    int l = idx >> 14, ij = idx & 16383, i = ij >> 7, j = ij & 127;
    const float* a = Ws + (size_t)l * 32768;
    const float* b = Wt + (size_t)l * 32768;
    float s = 0.f;
    for (int k = 0; k < 256; k++) s = fmaf(a[i * 256 + k], b[k * 128 + j], s);
    Wc[idx] = s;
}

__global__ void bc_kernel(const float* __restrict__ bs, const float* __restrict__ Wt,
                          const float* __restrict__ bt, float* __restrict__ bc) {
    int idx = threadIdx.x;                           // 2 layers x 128
    int l = idx >> 7, j = idx & 127;
    const float* b = Wt + (size_t)l * 32768;
    float s = bt[l * 128 + j];
    for (int k = 0; k < 256; k++) s = fmaf(bs[l * 256 + k], b[k * 128 + j], s);
    bc[idx] = s;
}

// ---------------------------------------------------------------------------
// Weight packing into MFMA fragment layout (bf16, ks-major). Serves as the
// A operand in the swapped (A=W, B=x) GEMMs.
// ---------------------------------------------------------------------------
__global__ void pack_qkv_kernel(const float* __restrict__ Wq, const float* __restrict__ Wk,
                                const float* __restrict__ Wv, unsigned short* __restrict__ out) {
    int idx = blockIdx.x * 256 + threadIdx.x;        // 2*3*32768 = 196608
    if (idx >= 196608) return;
    int j = idx & 7, lane = (idx >> 3) & 63, ct = (idx >> 9) & 15, ks = (idx >> 13) & 3;
    int m3 = idx >> 15;                              // 0..5
    int l = m3 / 3, m = m3 % 3;
    int k = ks * 32 + ((lane >> 4) * 8) + j;
    int n = ct * 16 + (lane & 15);
    const float* W = (m == 0) ? Wq : (m == 1) ? Wk : Wv;
    out[idx] = f2bf(W[(size_t)l * 32768 + k * 256 + n]);
}

// fused [Wt;Wc] (K=384): KS=12 (ks 0..7 from Wt, 8..11 from Wc), CT=8
__global__ void pack_fused_kernel(const float* __restrict__ Wt, const float* __restrict__ Wc,
                                  unsigned short* __restrict__ out) {
    int idx = blockIdx.x * 256 + threadIdx.x;        // 2*49152 = 98304
    if (idx >= 98304) return;
    int l = idx / 49152, r = idx % 49152;
    int j = r & 7, lane = (r >> 3) & 63;
    int rest = r >> 9;
    int ct = rest & 7, ks = rest >> 3;               // ks 0..11
    int k = ks * 32 + ((lane >> 4) * 8) + j;
    int n = ct * 16 + (lane & 15);
    float v = (k < 256) ? Wt[(size_t)l * 32768 + k * 128 + n]
                        : Wc[(size_t)l * 16384 + (k - 256) * 128 + n];
    out[idx] = f2bf(v);
}

// ---------------------------------------------------------------------------
// Shared proj stage: qkv projection for a 32-node wave tile whose bf16 x rows
// sit in LDS (row stride LROW). Writes q bf16 [N,256] and fine-interleaved kv
// rows (chunk c = [k[4c..4c+3] | v[4c..4c+3]]).
// ---------------------------------------------------------------------------
__device__ __forceinline__ void proj_from_lds(
    const unsigned short* T, const unsigned short* __restrict__ Wp,
    const float* __restrict__ b0, const float* __restrict__ b1, const float* __restrict__ b2,
    unsigned short* __restrict__ oq, unsigned short* __restrict__ kv,
    int rbase, int quad, int lr, int lane) {
    int n0 = rbase + lr, n1 = rbase + 16 + lr;
    bf16x8 a0[4], a1[4];
    #pragma unroll
    for (int ks = 0; ks < 4; ks++) {
        a0[ks] = *(const bf16x8*)(T + lr * LROW + ks * 32 + quad * 8);
        a1[ks] = *(const bf16x8*)(T + (16 + lr) * LROW + ks * 32 + quad * 8);
    }
    const float* bias[3] = {b0, b1, b2};
    for (int mm = 0; mm < 3; mm++) {
        const unsigned short* wp = Wp + mm * 32768;
        for (int ct = 0; ct < 16; ct++) {
            f32x4 c0 = {0.f, 0.f, 0.f, 0.f}, c1 = {0.f, 0.f, 0.f, 0.f};
            #pragma unroll
            for (int ks = 0; ks < 4; ks++) {
                bf16x8 wf = *(const bf16x8*)(wp + (size_t)((ks * 16 + ct) * 64 + lane) * 8);
                c0 = __builtin_amdgcn_mfma_f32_16x16x32_bf16(wf, a0[ks], c0, 0, 0, 0);
                c1 = __builtin_amdgcn_mfma_f32_16x16x32_bf16(wf, a1[ks], c1, 0, 0, 0);
            }
            int ob = ct * 16 + quad * 4;
            float4 bb = *(const float4*)&bias[mm][ob];
            ushort4 s0, s1;
            s0.x = f2bf(c0[0] + bb.x); s0.y = f2bf(c0[1] + bb.y);
            s0.z = f2bf(c0[2] + bb.z); s0.w = f2bf(c0[3] + bb.w);
            s1.x = f2bf(c1[0] + bb.x); s1.y = f2bf(c1[1] + bb.y);
            s1.z = f2bf(c1[2] + bb.z); s1.w = f2bf(c1[3] + bb.w);
            if (mm == 0) {
                if (n0 < N_NODES) *(ushort4*)(oq + (size_t)n0 * 256 + ob) = s0;
                if (n1 < N_NODES) *(ushort4*)(oq + (size_t)n1 * 256 + ob) = s1;
            } else {
                int kvo = (ob >> 2) * 8 + ((mm == 2) ? 4 : 0);
                if (n0 < N_NODES) *(ushort4*)(kv + (size_t)n0 * 512 + kvo) = s0;
                if (n1 < N_NODES) *(ushort4*)(kv + (size_t)n1 * 512 + kvo) = s1;
            }
        }
    }
}

// ---------------------------------------------------------------------------
// Layer-0 front: convert fp32 x -> bf16 xb (global, needed for skip path and
// as record) AND stage the tile in LDS, then run the qkv projection.
// ---------------------------------------------------------------------------
__global__ __launch_bounds__(256) void fproj_kernel(
    const float* __restrict__ xf, unsigned short* __restrict__ xb,
    const unsigned short* __restrict__ Wp,
    const float* __restrict__ b0, const float* __restrict__ b1, const float* __restrict__ b2,
    unsigned short* __restrict__ oq, unsigned short* __restrict__ kv) {
    __shared__ unsigned short tile[4][32 * LROW];
    int w = threadIdx.x >> 6, lane = threadIdx.x & 63;
    int quad = lane >> 4, lr = lane & 15;
    int rbase = blockIdx.x * 128 + w * 32;
    unsigned short* T = tile[w];

    #pragma unroll
    for (int s = 0; s < 2; s++) {
        int row = rbase + s * 16 + lr;
        if (row < N_NODES) {
            const float4* src = (const float4*)(xf + (size_t)row * 128 + quad * 32);
            ushort4* gdst = (ushort4*)(xb + (size_t)row * 128 + quad * 32);
            ushort4* ldst = (ushort4*)(T + (s * 16 + lr) * LROW + quad * 32);
            #pragma unroll
            for (int i = 0; i < 8; i++) {
                float4 v = src[i];
                ushort4 o;
                o.x = f2bf(v.x); o.y = f2bf(v.y); o.z = f2bf(v.z); o.w = f2bf(v.w);
                gdst[i] = o;
                ldst[i] = o;
            }
        }
    }
    __syncthreads();
    proj_from_lds(T, Wp, b0, b1, b2, oq, kv, rbase, quad, lr, lane);
}

// ---------------------------------------------------------------------------
// Fused output linear (+ next layer's qkv projection when do_proj):
// x_next = relu([h|x] @ [Wt;Wc] + bc) -> global bf16 + LDS tile -> proj.
// ---------------------------------------------------------------------------
__global__ __launch_bounds__(256) void outproj_kernel(
    const unsigned short* __restrict__ hb, const unsigned short* __restrict__ xbin,
    const unsigned short* __restrict__ Wfp, const float* __restrict__ bc,
    unsigned short* __restrict__ xbout,
    const unsigned short* __restrict__ Wp,
    const float* __restrict__ b0, const float* __restrict__ b1, const float* __restrict__ b2,
    unsigned short* __restrict__ oq, unsigned short* __restrict__ kv, int do_proj) {
    __shared__ unsigned short tile[4][32 * LROW];
    int w = threadIdx.x >> 6, lane = threadIdx.x & 63;
    int quad = lane >> 4, lr = lane & 15;
    int rbase = blockIdx.x * 128 + w * 32;
    int n0 = rbase + lr, n1 = rbase + 16 + lr;
    int n0c = min(n0, N_NODES - 1), n1c = min(n1, N_NODES - 1);
    unsigned short* T = tile[w];

    f32x4 acc[8][2];
    #pragma unroll
    for (int ct = 0; ct < 8; ct++) {
        acc[ct][0] = (f32x4){0.f, 0.f, 0.f, 0.f};
        acc[ct][1] = (f32x4){0.f, 0.f, 0.f, 0.f};
    }

    #pragma unroll 4
    for (int ks = 0; ks < 12; ks++) {
        bf16x8 a0, a1;
        if (ks < 8) {
            a0 = *(const bf16x8*)(hb + (size_t)n0c * 256 + ks * 32 + quad * 8);
            a1 = *(const bf16x8*)(hb + (size_t)n1c * 256 + ks * 32 + quad * 8);
        } else {
            a0 = *(const bf16x8*)(xbin + (size_t)n0c * 128 + (ks - 8) * 32 + quad * 8);
            a1 = *(const bf16x8*)(xbin + (size_t)n1c * 128 + (ks - 8) * 32 + quad * 8);
        }
        #pragma unroll
        for (int ct = 0; ct < 8; ct++) {
            bf16x8 wf = *(const bf16x8*)(Wfp + (size_t)((ks * 8 + ct) * 64 + lane) * 8);
            acc[ct][0] = __builtin_amdgcn_mfma_f32_16x16x32_bf16(wf, a0, acc[ct][0], 0, 0, 0);
            acc[ct][1] = __builtin_amdgcn_mfma_f32_16x16x32_bf16(wf, a1, acc[ct][1], 0, 0, 0);
        }
    }

    #pragma unroll
    for (int ct = 0; ct < 8; ct++) {
        int ob = ct * 16 + quad * 4;
        float4 bb = *(const float4*)&bc[ob];
        ushort4 s0, s1;
        s0.x = f2bf(fmaxf(acc[ct][0][0] + bb.x, 0.f));
        s0.y = f2bf(fmaxf(acc[ct][0][1] + bb.y, 0.f));
        s0.z = f2bf(fmaxf(acc[ct][0][2] + bb.z, 0.f));
        s0.w = f2bf(fmaxf(acc[ct][0][3] + bb.w, 0.f));
        s1.x = f2bf(fmaxf(acc[ct][1][0] + bb.x, 0.f));
        s1.y = f2bf(fmaxf(acc[ct][1][1] + bb.y, 0.f));
        s1.z = f2bf(fmaxf(acc[ct][1][2] + bb.z, 0.f));
        s1.w = f2bf(fmaxf(acc[ct][1][3] + bb.w, 0.f));
        if (n0 < N_NODES) *(ushort4*)(xbout + (size_t)n0 * 128 + ob) = s0;
        if (n1 < N_NODES) *(ushort4*)(xbout + (size_t)n1 * 128 + ob) = s1;
        *(ushort4*)(T + lr * LROW + ob) = s0;
        *(ushort4*)(T + (16 + lr) * LROW + ob) = s1;
    }

    if (do_proj) {
        __syncthreads();
        proj_from_lds(T, Wp, b0, b1, b2, oq, kv, rbase, quad, lr, lane);
    }
}

// ---------------------------------------------------------------------------
// Attention: 256-thread blocks, one dst node per wave (4/block), unroll 8
// (8 kv-row loads in flight). Single pass, no max-subtraction (|logit|<~3,
// exp-safe; softmax shift-invariant). Lane l reads the edge's k+v slice in
// ONE 16B load from the interleaved kv row. Lanes 0..31 head0, 32..63 head1.
// ---------------------------------------------------------------------------
__global__ __launch_bounds__(256) void attn_kernel(
    const unsigned short* __restrict__ q, const unsigned short* __restrict__ kv,
    const int* __restrict__ offs, const int* __restrict__ csr,
    unsigned short* __restrict__ hout) {
    const float SCALE = 0.08838834764831845f;  // 1/sqrt(128)
    int w = threadIdx.x >> 6, lane = threadIdx.x & 63;
    int n = blockIdx.x * 4 + w;                // 12500*4 = 50000 exactly
    ushort4 qu = ((const ushort4*)(q + (size_t)n * 256))[lane];
    float4 q4 = make_float4(bf2f(qu.x), bf2f(qu.y), bf2f(qu.z), bf2f(qu.w));
    int beg = offs[n], end = offs[n + 1];

    float4 acc = make_float4(0.f, 0.f, 0.f, 0.f);
    float d = 0.f;

    int j = beg;
    for (; j + 8 <= end; j += 8) {
        us8 c[8];
        #pragma unroll
        for (int u = 0; u < 8; u++) {
            int s = csr[j + u];
            c[u] = ((const us8*)(kv + (size_t)s * 512))[lane];
        }
        float p[8];
        #pragma unroll
        for (int u = 0; u < 8; u++)
            p[u] = q4.x * bf2f(c[u][0]) + q4.y * bf2f(c[u][1]) +
                   q4.z * bf2f(c[u][2]) + q4.w * bf2f(c[u][3]);
        #pragma unroll
        for (int o = 16; o >= 1; o >>= 1) {
            #pragma unroll
            for (int u = 0; u < 8; u++) p[u] += __shfl_xor(p[u], o);
        }
        #pragma unroll
        for (int u = 0; u < 8; u++) {
            float e = __expf(p[u] * SCALE);
            d += e;
            acc.x = fmaf(e, bf2f(c[u][4]), acc.x);
            acc.y = fmaf(e, bf2f(c[u][5]), acc.y);
            acc.z = fmaf(e, bf2f(c[u][6]), acc.z);
            acc.w = fmaf(e, bf2f(c[u][7]), acc.w);
        }
    }
    for (; j < end; j++) {
        int s = csr[j];
        us8 c = ((const us8*)(kv + (size_t)s * 512))[lane];
        float p = q4.x * bf2f(c[0]) + q4.y * bf2f(c[1]) + q4.z * bf2f(c[2]) + q4.w * bf2f(c[3]);
        #pragma unroll
        for (int o = 16; o >= 1; o >>= 1) p += __shfl_xor(p, o);
        float e = __expf(p * SCALE);
        d += e;
        acc.x = fmaf(e, bf2f(c[4]), acc.x);
        acc.y = fmaf(e, bf2f(c[5]), acc.y);
        acc.z = fmaf(e, bf2f(c[6]), acc.z);
        acc.w = fmaf(e, bf2f(c[7]), acc.w);
    }

    float inv = 1.f / (d + 1e-16f);
    ushort4 hv;
    hv.x = f2bf(acc.x * inv);
    hv.y = f2bf(acc.y * inv);
    hv.z = f2bf(acc.z * inv);
    hv.w = f2bf(acc.w * inv);
    ((ushort4*)(hout + (size_t)n * 256))[lane] = hv;
}

// ---------------------------------------------------------------------------
// Pool init: zero psum/pmax (replaces 2 memsets) + per-graph counts via
// binary search over the SORTED graph_indices.
// ---------------------------------------------------------------------------
__global__ __launch_bounds__(256) void pool_init_kernel(const int* __restrict__ gi,
                                                        int* __restrict__ pcnt,
                                                        float* __restrict__ psum,
                                                        unsigned* __restrict__ pmax) {
    int t = threadIdx.x;
    float4* ps = (float4*)psum;    // 2048 float4
    uint4*  pm = (uint4*)pmax;
    for (int i = t; i < 2048; i += 256) {
        ps[i] = make_float4(0.f, 0.f, 0.f, 0.f);
        uint4 z; z.x = z.y = z.z = z.w = 0u;
        pm[i] = z;
    }
    if (t < NGRAPH) {
        auto lb = [&](int target) {
            int lo = 0, hi = N_NODES;
            while (lo < hi) {
                int mid = (lo + hi) >> 1;
                if (gi[mid] < target) lo = mid + 1;
                else hi = mid;
            }
            return lo;
        };
        int a = lb(t), b = lb(t + 1);
        pcnt[t] = b - a;
    }
}

// ---------------------------------------------------------------------------
// Pooling from bf16 x, ushort4-vectorized, run-compressed (gi sorted).
// relu output >= 0 => uint atomicMax order-correct, 0 is the identity.
// ---------------------------------------------------------------------------
__global__ __launch_bounds__(256) void pool_accum_kernel(
    const unsigned short* __restrict__ xb, const int* __restrict__ gi,
    float* __restrict__ psum, unsigned* __restrict__ pmax) {
    int n0 = blockIdx.x * 128;
    int c4 = (threadIdx.x & 31) * 4;        // 4 consecutive cols
    int phase = threadIdx.x >> 5;           // 0..7
    int first = n0 + phase;
    if (first >= N_NODES) return;
    float s0 = 0.f, s1 = 0.f, s2 = 0.f, s3 = 0.f;
    float m0 = 0.f, m1 = 0.f, m2 = 0.f, m3 = 0.f;
    int cur_g = gi[first];
    for (int r = phase; r < 128; r += 8) {
        int n = n0 + r;
        if (n >= N_NODES) break;
        int g = gi[n];
        if (g != cur_g) {
            float* ps = &psum[cur_g * 128 + c4];
            unsigned* pm = &pmax[cur_g * 128 + c4];
            atomicAdd(ps + 0, s0); atomicAdd(ps + 1, s1);
            atomicAdd(ps + 2, s2); atomicAdd(ps + 3, s3);
            atomicMax(pm + 0, __float_as_uint(m0)); atomicMax(pm + 1, __float_as_uint(m1));
            atomicMax(pm + 2, __float_as_uint(m2)); atomicMax(pm + 3, __float_as_uint(m3));
            s0 = s1 = s2 = s3 = 0.f;
            m0 = m1 = m2 = m3 = 0.f;
            cur_g = g;
        }
        ushort4 u = *(const ushort4*)(xb + (size_t)n * 128 + c4);
        float v0 = bf2f(u.x), v1 = bf2f(u.y), v2 = bf2f(u.z), v3 = bf2f(u.w);
        s0 += v0; s1 += v1; s2 += v2; s3 += v3;
        m0 = fmaxf(m0, v0); m1 = fmaxf(m1, v1);
        m2 = fmaxf(m2, v2); m3 = fmaxf(m3, v3);
    }
    float* ps = &psum[cur_g * 128 + c4];
    unsigned* pm = &pmax[cur_g * 128 + c4];
    atomicAdd(ps + 0, s0); atomicAdd(ps + 1, s1);
    atomicAdd(ps + 2, s2); atomicAdd(ps + 3, s3);
    atomicMax(pm + 0, __float_as_uint(m0)); atomicMax(pm + 1, __float_as_uint(m1));
    atomicMax(pm + 2, __float_as_uint(m2)); atomicMax(pm + 3, __float_as_uint(m3));
}

__global__ void pool_final_kernel(const float* __restrict__ psum, const unsigned* __restrict__ pmax,
                                  const int* __restrict__ pcnt, float* __restrict__ out) {
    int idx = blockIdx.x * 256 + threadIdx.x;
    if (idx >= NGRAPH * 384) return;
    int g = idx / 384, c = idx % 384;
    float r;
    if (c < 128)       r = __uint_as_float(pmax[g * 128 + c]);
    else if (c < 256)  r = psum[g * 128 + (c - 128)] / fmaxf((float)pcnt[g], 1.f);
    else               r = psum[g * 128 + (c - 256)];
    out[idx] = r;
}

// ---------------------------------------------------------------------------
extern "C" void kernel_launch(void* const* d_in, const int* in_sizes, int n_in,
                              void* d_out, int out_size, void* d_ws, size_t ws_size,
                              hipStream_t stream) {
    const float* x   = (const float*)d_in[0];
    const int*   ei  = (const int*)d_in[1];
    const int*   gi  = (const int*)d_in[2];
    const float* Wq  = (const float*)d_in[3];
    const float* bq  = (const float*)d_in[4];
    const float* Wk  = (const float*)d_in[5];
    const float* bk  = (const float*)d_in[6];
    const float* Wv  = (const float*)d_in[7];
    const float* bv  = (const float*)d_in[8];
    const float* Wsk = (const float*)d_in[9];
    const float* bsk = (const float*)d_in[10];
    const float* Wt  = (const float*)d_in[11];
    const float* bt  = (const float*)d_in[12];
    float* out = (float*)d_out;

    char* p = (char*)d_ws;
    auto take = [&](size_t bytes) -> char* {
        char* r = p;
        p += (bytes + 255) & ~(size_t)255;
        return r;
    };
    unsigned short* qbuf   = (unsigned short*)take((size_t)N_NODES * 256 * 2);  // q bf16
    unsigned short* kvbuf  = (unsigned short*)take((size_t)N_NODES * 512 * 2);  // interleaved k|v
    unsigned short* xb     = (unsigned short*)take((size_t)N_NODES * 128 * 2);  // x0 bf16 / final x
    unsigned short* xb2    = (unsigned short*)take((size_t)N_NODES * 128 * 2);  // x1 bf16
    unsigned short* hb     = (unsigned short*)take((size_t)N_NODES * 256 * 2);  // attn out bf16
    unsigned short* Wqkvp  = (unsigned short*)take((size_t)196608 * 2);         // packed qkv
    unsigned short* Wfp    = (unsigned short*)take((size_t)98304 * 2);          // packed [Wt;Wc]
    float*          Wc     = (float*)take(2 * 128 * 128 * 4);
    float*          bc     = (float*)take(2 * 128 * 4);
    int*            counts = (int*)take((size_t)N_NODES * 4);
    int*            offs   = (int*)take((size_t)(N_NODES + 1) * 4);
    int*            cursor = (int*)take((size_t)N_NODES * 4);
    int*            csr    = (int*)take((size_t)N_EDGES * 4);
    int*            bsum   = (int*)take((size_t)SCAN_BLOCKS * 4);
    int*            boff   = (int*)take((size_t)SCAN_BLOCKS * 4);
    float*          psum   = (float*)take(NGRAPH * 128 * 4);
    unsigned*       pmax   = (unsigned*)take(NGRAPH * 128 * 4);
    int*            pcnt   = (int*)take(NGRAPH * 4);

    const int EB = (N_EDGES + 255) / 256;          // 3125
    const int GB = (N_NODES + 127) / 128;          // 391  (MFMA GEMM / pooling blocks)
    const int AB = (N_NODES + 3) / 4;              // 12500 (attn blocks, 4 dst/block)

    // ---- CSR build ----
    hipMemsetAsync(counts, 0, (size_t)N_NODES * 4, stream);
    degree_kernel<<<EB, 256, 0, stream>>>(ei, counts);
    block_sum_kernel<<<SCAN_BLOCKS, 256, 0, stream>>>(counts, bsum);
    scan_bsum_kernel<<<1, 256, 0, stream>>>(bsum, boff);
    block_scan_kernel<<<SCAN_BLOCKS, 256, 0, stream>>>(counts, boff, offs, cursor);
    scatter_kernel<<<EB, 256, 0, stream>>>(ei, cursor, csr);

    // ---- weight prep ----
    wc_kernel<<<128, 256, 0, stream>>>(Wsk, Wt, Wc);
    bc_kernel<<<1, 256, 0, stream>>>(bsk, Wt, bt, bc);
    pack_qkv_kernel<<<768, 256, 0, stream>>>(Wq, Wk, Wv, Wqkvp);
    pack_fused_kernel<<<384, 256, 0, stream>>>(Wt, Wc, Wfp);

    // ---- layer 0 ----
    fproj_kernel<<<GB, 256, 0, stream>>>(x, xb, Wqkvp, bq, bk, bv, qbuf, kvbuf);
    attn_kernel<<<AB, 256, 0, stream>>>(qbuf, kvbuf, offs, csr, hb);
    // out(L0) fused with proj(L1)
    outproj_kernel<<<GB, 256, 0, stream>>>(hb, xb, Wfp, bc, xb2,
                                           Wqkvp + 98304, bq + 256, bk + 256, bv + 256,
                                           qbuf, kvbuf, 1);
    // ---- layer 1 ----
    attn_kernel<<<AB, 256, 0, stream>>>(qbuf, kvbuf, offs, csr, hb);
    outproj_kernel<<<GB, 256, 0, stream>>>(hb, xb2, Wfp + 49152, bc + 128, xb,
                                           Wqkvp, bq, bk, bv, qbuf, kvbuf, 0);

    // ---- pooling ----
    pool_init_kernel<<<1, 256, 0, stream>>>(gi, pcnt, psum, pmax);
    pool_accum_kernel<<<GB, 256, 0, stream>>>(xb, gi, psum, pmax);
    pool_final_kernel<<<(NGRAPH * 384 + 255) / 256, 256, 0, stream>>>(psum, pmax, pcnt, out);
}

// Round 10
// 556.683 us; speedup vs baseline: 1.1565x; 1.0826x over previous
//
#include <hip/hip_runtime.h>
#include <math.h>

#define N_NODES 50000
#define N_EDGES 800000
#define NGRAPH  64
#define SCAN_BLOCKS ((N_NODES + 255) / 256)   // 196
#define LROW 136   // LDS x-tile row stride (shorts): 272B -> bank step 4, 2-way max

typedef __bf16 bf16x8 __attribute__((ext_vector_type(8)));
typedef float  f32x4  __attribute__((ext_vector_type(4)));
typedef float  f32x2  __attribute__((ext_vector_type(2)));

__device__ __forceinline__ unsigned short f2bf(float f) {
    unsigned u = __float_as_uint(f);
    u += 0x7fff + ((u >> 16) & 1);          // round-to-nearest-even
    return (unsigned short)(u >> 16);
}
__device__ __forceinline__ float bf2f(unsigned short u) {
    return __uint_as_float((unsigned)u << 16);
}

// ---------------------------------------------------------------------------
// CSR build
// ---------------------------------------------------------------------------
__global__ void degree_kernel(const int* __restrict__ ei, int* __restrict__ counts) {
    int e = blockIdx.x * 256 + threadIdx.x;
    if (e < N_EDGES) atomicAdd(&counts[ei[N_EDGES + e]], 1);
}

__global__ __launch_bounds__(256) void block_sum_kernel(const int* __restrict__ counts,
                                                        int* __restrict__ bsum) {
    int i = blockIdx.x * 256 + threadIdx.x;
    int v = (i < N_NODES) ? counts[i] : 0;
    #pragma unroll
    for (int o = 32; o >= 1; o >>= 1) v += __shfl_xor(v, o);
    __shared__ int ws[4];
    if ((threadIdx.x & 63) == 0) ws[threadIdx.x >> 6] = v;
    __syncthreads();
    if (threadIdx.x == 0) bsum[blockIdx.x] = ws[0] + ws[1] + ws[2] + ws[3];
}

__global__ __launch_bounds__(256) void scan_bsum_kernel(const int* __restrict__ bsum,
                                                        int* __restrict__ boff) {
    int t = threadIdx.x;
    int v = (t < SCAN_BLOCKS) ? bsum[t] : 0;
    int lane = t & 63, wid = t >> 6;
    int incl = v;
    #pragma unroll
    for (int o = 1; o < 64; o <<= 1) {
        int tv = __shfl_up(incl, o);
        if (lane >= o) incl += tv;
    }
    __shared__ int wsum[4];
    if (lane == 63) wsum[wid] = incl;
    __syncthreads();
    int add = 0;
    for (int w = 0; w < wid; w++) add += wsum[w];
    if (t < SCAN_BLOCKS) boff[t] = add + incl - v;   // exclusive
}

__global__ __launch_bounds__(256) void block_scan_kernel(const int* __restrict__ counts,
                                                         const int* __restrict__ boff,
                                                         int* __restrict__ offs,
                                                         int* __restrict__ cursor) {
    int i = blockIdx.x * 256 + threadIdx.x;
    int v = (i < N_NODES) ? counts[i] : 0;
    int lane = threadIdx.x & 63, wid = threadIdx.x >> 6;
    int incl = v;
    #pragma unroll
    for (int o = 1; o < 64; o <<= 1) {
        int tv = __shfl_up(incl, o);
        if (lane >= o) incl += tv;
    }
    __shared__ int wsum[4];
    if (lane == 63) wsum[wid] = incl;
    __syncthreads();
    int add = boff[blockIdx.x];
    for (int w = 0; w < wid; w++) add += wsum[w];
    if (i < N_NODES) {
        offs[i + 1] = add + incl;
        cursor[i]   = add + incl - v;
    }
    if (i == 0) offs[0] = 0;
}

__global__ void scatter_kernel(const int* __restrict__ ei, int* __restrict__ cursor,
                               int* __restrict__ csr) {
    int e = blockIdx.x * 256 + threadIdx.x;
    if (e < N_EDGES) {
        int d = ei[N_EDGES + e];
        int pos = atomicAdd(&cursor[d], 1);
        csr[pos] = ei[e];  // src
    }
}

// ---------------------------------------------------------------------------
// Skip-path fusion (fp32): Wc[l] = Ws[l] @ Wt[l], bc[l] = bs[l] @ Wt[l] + bt[l]
// ---------------------------------------------------------------------------
__global__ void wc_kernel(const float* __restrict__ Ws, const float* __restrict__ Wt,
                          float* __restrict__ Wc) {
    int idx = blockIdx.x * 256 + threadIdx.x;       // 2*128*128 = 32768
    int l = idx >> 14, ij = idx & 16383, i = ij >> 7, j = ij & 127;
    const float* a = Ws + (size_t)l * 32768;
    const float* b = Wt + (size_t)l * 32768;
    float s = 0.f;
    for (int k = 0; k < 256; k++) s = fmaf(a[i * 256 + k], b[k * 128 + j], s);
    Wc[idx] = s;
}

__global__ void bc_kernel(const float* __restrict__ bs, const float* __restrict__ Wt,
                          const float* __restrict__ bt, float* __restrict__ bc) {
    int idx = threadIdx.x;                           // 2 layers x 128
    int l = idx >> 7, j = idx & 127;
    const float* b = Wt + (size_t)l * 32768;
    float s = bt[l * 128 + j];
    for (int k = 0; k < 256; k++) s = fmaf(bs[l * 256 + k], b[k * 128 + j], s);
    bc[idx] = s;
}

// ---------------------------------------------------------------------------
// Weight packing into MFMA fragment layout (bf16, ks-major). Serves as the
// A operand in the swapped (A=W, B=x) GEMMs.
// ---------------------------------------------------------------------------
__global__ void pack_qkv_kernel(const float* __restrict__ Wq, const float* __restrict__ Wk,
                                const float* __restrict__ Wv, unsigned short* __restrict__ out) {
    int idx = blockIdx.x * 256 + threadIdx.x;        // 2*3*32768 = 196608
    if (idx >= 196608) return;
    int j = idx & 7, lane = (idx >> 3) & 63, ct = (idx >> 9) & 15, ks = (idx >> 13) & 3;
    int m3 = idx >> 15;                              // 0..5
    int l = m3 / 3, m = m3 % 3;
    int k = ks * 32 + ((lane >> 4) * 8) + j;
    int n = ct * 16 + (lane & 15);
    const float* W = (m == 0) ? Wq : (m == 1) ? Wk : Wv;
    out[idx] = f2bf(W[(size_t)l * 32768 + k * 256 + n]);
}

// fused [Wt;Wc] (K=384): KS=12 (ks 0..7 from Wt, 8..11 from Wc), CT=8
__global__ void pack_fused_kernel(const float* __restrict__ Wt, const float* __restrict__ Wc,
                                  unsigned short* __restrict__ out) {
    int idx = blockIdx.x * 256 + threadIdx.x;        // 2*49152 = 98304
    if (idx >= 98304) return;
    int l = idx / 49152, r = idx % 49152;
    int j = r & 7, lane = (r >> 3) & 63;
    int rest = r >> 9;
    int ct = rest & 7, ks = rest >> 3;               // ks 0..11
    int k = ks * 32 + ((lane >> 4) * 8) + j;
    int n = ct * 16 + (lane & 15);
    float v = (k < 256) ? Wt[(size_t)l * 32768 + k * 128 + n]
                        : Wc[(size_t)l * 16384 + (k - 256) * 128 + n];
    out[idx] = f2bf(v);
}

// ---------------------------------------------------------------------------
// Shared proj stage: qkv projection for a 32-node wave tile whose bf16 x rows
// sit in LDS. q -> bf16 [N,256]; k -> fp8 e4m3 [N,256] (uint-packed, 4/lane);
// v -> bf16 [N,256].
// ---------------------------------------------------------------------------
__device__ __forceinline__ void proj_from_lds(
    const unsigned short* T, const unsigned short* __restrict__ Wp,
    const float* __restrict__ b0, const float* __restrict__ b1, const float* __restrict__ b2,
    unsigned short* __restrict__ oq, unsigned* __restrict__ k8,
    unsigned short* __restrict__ vb,
    int rbase, int quad, int lr, int lane) {
    int n0 = rbase + lr, n1 = rbase + 16 + lr;
    bf16x8 a0[4], a1[4];
    #pragma unroll
    for (int ks = 0; ks < 4; ks++) {
        a0[ks] = *(const bf16x8*)(T + lr * LROW + ks * 32 + quad * 8);
        a1[ks] = *(const bf16x8*)(T + (16 + lr) * LROW + ks * 32 + quad * 8);
    }
    const float* bias[3] = {b0, b1, b2};
    for (int mm = 0; mm < 3; mm++) {
        const unsigned short* wp = Wp + mm * 32768;
        for (int ct = 0; ct < 16; ct++) {
            f32x4 c0 = {0.f, 0.f, 0.f, 0.f}, c1 = {0.f, 0.f, 0.f, 0.f};
            #pragma unroll
            for (int ks = 0; ks < 4; ks++) {
                bf16x8 wf = *(const bf16x8*)(wp + (size_t)((ks * 16 + ct) * 64 + lane) * 8);
                c0 = __builtin_amdgcn_mfma_f32_16x16x32_bf16(wf, a0[ks], c0, 0, 0, 0);
                c1 = __builtin_amdgcn_mfma_f32_16x16x32_bf16(wf, a1[ks], c1, 0, 0, 0);
            }
            int ob = ct * 16 + quad * 4;
            float4 bb = *(const float4*)&bias[mm][ob];
            float v00 = c0[0] + bb.x, v01 = c0[1] + bb.y, v02 = c0[2] + bb.z, v03 = c0[3] + bb.w;
            float v10 = c1[0] + bb.x, v11 = c1[1] + bb.y, v12 = c1[2] + bb.z, v13 = c1[3] + bb.w;
            if (mm == 1) {
                // k -> fp8 e4m3 (HW pack, RNE)
                int u0 = __builtin_amdgcn_cvt_pk_fp8_f32(v00, v01, 0, false);
                u0 = __builtin_amdgcn_cvt_pk_fp8_f32(v02, v03, u0, true);
                int u1 = __builtin_amdgcn_cvt_pk_fp8_f32(v10, v11, 0, false);
                u1 = __builtin_amdgcn_cvt_pk_fp8_f32(v12, v13, u1, true);
                if (n0 < N_NODES) k8[(size_t)n0 * 64 + (ob >> 2)] = (unsigned)u0;
                if (n1 < N_NODES) k8[(size_t)n1 * 64 + (ob >> 2)] = (unsigned)u1;
            } else {
                ushort4 s0, s1;
                s0.x = f2bf(v00); s0.y = f2bf(v01); s0.z = f2bf(v02); s0.w = f2bf(v03);
                s1.x = f2bf(v10); s1.y = f2bf(v11); s1.z = f2bf(v12); s1.w = f2bf(v13);
                unsigned short* dst = (mm == 0) ? oq : vb;
                if (n0 < N_NODES) *(ushort4*)(dst + (size_t)n0 * 256 + ob) = s0;
                if (n1 < N_NODES) *(ushort4*)(dst + (size_t)n1 * 256 + ob) = s1;
            }
        }
    }
}

// ---------------------------------------------------------------------------
// Layer-0 front: fp32 x -> bf16 xb (global) + LDS tile, then qkv projection.
// ---------------------------------------------------------------------------
__global__ __launch_bounds__(256) void fproj_kernel(
    const float* __restrict__ xf, unsigned short* __restrict__ xb,
    const unsigned short* __restrict__ Wp,
    const float* __restrict__ b0, const float* __restrict__ b1, const float* __restrict__ b2,
    unsigned short* __restrict__ oq, unsigned* __restrict__ k8,
    unsigned short* __restrict__ vb) {
    __shared__ unsigned short tile[4][32 * LROW];
    int w = threadIdx.x >> 6, lane = threadIdx.x & 63;
    int quad = lane >> 4, lr = lane & 15;
    int rbase = blockIdx.x * 128 + w * 32;
    unsigned short* T = tile[w];

    #pragma unroll
    for (int s = 0; s < 2; s++) {
        int row = rbase + s * 16 + lr;
        if (row < N_NODES) {
            const float4* src = (const float4*)(xf + (size_t)row * 128 + quad * 32);
            ushort4* gdst = (ushort4*)(xb + (size_t)row * 128 + quad * 32);
            ushort4* ldst = (ushort4*)(T + (s * 16 + lr) * LROW + quad * 32);
            #pragma unroll
            for (int i = 0; i < 8; i++) {
                float4 v = src[i];
                ushort4 o;
                o.x = f2bf(v.x); o.y = f2bf(v.y); o.z = f2bf(v.z); o.w = f2bf(v.w);
                gdst[i] = o;
                ldst[i] = o;
            }
        }
    }
    __syncthreads();
    proj_from_lds(T, Wp, b0, b1, b2, oq, k8, vb, rbase, quad, lr, lane);
}

// ---------------------------------------------------------------------------
// Fused output linear (+ next layer's qkv projection when do_proj):
// x_next = relu([h|x] @ [Wt;Wc] + bc) -> global bf16 + LDS tile -> proj.
// ---------------------------------------------------------------------------
__global__ __launch_bounds__(256) void outproj_kernel(
    const unsigned short* __restrict__ hb, const unsigned short* __restrict__ xbin,
    const unsigned short* __restrict__ Wfp, const float* __restrict__ bc,
    unsigned short* __restrict__ xbout,
    const unsigned short* __restrict__ Wp,
    const float* __restrict__ b0, const float* __restrict__ b1, const float* __restrict__ b2,
    unsigned short* __restrict__ oq, unsigned* __restrict__ k8,
    unsigned short* __restrict__ vb, int do_proj) {
    __shared__ unsigned short tile[4][32 * LROW];
    int w = threadIdx.x >> 6, lane = threadIdx.x & 63;
    int quad = lane >> 4, lr = lane & 15;
    int rbase = blockIdx.x * 128 + w * 32;
    int n0 = rbase + lr, n1 = rbase + 16 + lr;
    int n0c = min(n0, N_NODES - 1), n1c = min(n1, N_NODES - 1);
    unsigned short* T = tile[w];

    f32x4 acc[8][2];
    #pragma unroll
    for (int ct = 0; ct < 8; ct++) {
        acc[ct][0] = (f32x4){0.f, 0.f, 0.f, 0.f};
        acc[ct][1] = (f32x4){0.f, 0.f, 0.f, 0.f};
    }

    #pragma unroll 4
    for (int ks = 0; ks < 12; ks++) {
        bf16x8 a0, a1;
        if (ks < 8) {
            a0 = *(const bf16x8*)(hb + (size_t)n0c * 256 + ks * 32 + quad * 8);
            a1 = *(const bf16x8*)(hb + (size_t)n1c * 256 + ks * 32 + quad * 8);
        } else {
            a0 = *(const bf16x8*)(xbin + (size_t)n0c * 128 + (ks - 8) * 32 + quad * 8);
            a1 = *(const bf16x8*)(xbin + (size_t)n1c * 128 + (ks - 8) * 32 + quad * 8);
        }
        #pragma unroll
        for (int ct = 0; ct < 8; ct++) {
            bf16x8 wf = *(const bf16x8*)(Wfp + (size_t)((ks * 8 + ct) * 64 + lane) * 8);
            acc[ct][0] = __builtin_amdgcn_mfma_f32_16x16x32_bf16(wf, a0, acc[ct][0], 0, 0, 0);
            acc[ct][1] = __builtin_amdgcn_mfma_f32_16x16x32_bf16(wf, a1, acc[ct][1], 0, 0, 0);
        }
    }

    #pragma unroll
    for (int ct = 0; ct < 8; ct++) {
        int ob = ct * 16 + quad * 4;
        float4 bb = *(const float4*)&bc[ob];
        ushort4 s0, s1;
        s0.x = f2bf(fmaxf(acc[ct][0][0] + bb.x, 0.f));
        s0.y = f2bf(fmaxf(acc[ct][0][1] + bb.y, 0.f));
        s0.z = f2bf(fmaxf(acc[ct][0][2] + bb.z, 0.f));
        s0.w = f2bf(fmaxf(acc[ct][0][3] + bb.w, 0.f));
        s1.x = f2bf(fmaxf(acc[ct][1][0] + bb.x, 0.f));
        s1.y = f2bf(fmaxf(acc[ct][1][1] + bb.y, 0.f));
        s1.z = f2bf(fmaxf(acc[ct][1][2] + bb.z, 0.f));
        s1.w = f2bf(fmaxf(acc[ct][1][3] + bb.w, 0.f));
        if (n0 < N_NODES) *(ushort4*)(xbout + (size_t)n0 * 128 + ob) = s0;
        if (n1 < N_NODES) *(ushort4*)(xbout + (size_t)n1 * 128 + ob) = s1;
        *(ushort4*)(T + lr * LROW + ob) = s0;
        *(ushort4*)(T + (16 + lr) * LROW + ob) = s1;
    }

    if (do_proj) {
        __syncthreads();
        proj_from_lds(T, Wp, b0, b1, b2, oq, k8, vb, rbase, quad, lr, lane);
    }
}

// ---------------------------------------------------------------------------
// Attention: 256-thread blocks, one dst/wave, unroll 8. Single pass, no
// max-subtraction (|logit|<~3, exp-safe; softmax shift-invariant).
// k is fp8 e4m3 (lane: one 4B uint = 4 values, HW unpack); v bf16 (8B/lane).
// Lanes 0..31 head0, 32..63 head1; intra-32 butterfly.
// ---------------------------------------------------------------------------
__global__ __launch_bounds__(256) void attn_kernel(
    const unsigned short* __restrict__ q, const unsigned* __restrict__ k8,
    const unsigned short* __restrict__ vb,
    const int* __restrict__ offs, const int* __restrict__ csr,
    unsigned short* __restrict__ hout) {
    const float SCALE = 0.08838834764831845f;  // 1/sqrt(128)
    int w = threadIdx.x >> 6, lane = threadIdx.x & 63;
    int n = blockIdx.x * 4 + w;                // 12500*4 = 50000 exactly
    ushort4 qu = ((const ushort4*)(q + (size_t)n * 256))[lane];
    float4 q4 = make_float4(bf2f(qu.x), bf2f(qu.y), bf2f(qu.z), bf2f(qu.w));
    int beg = offs[n], end = offs[n + 1];

    float4 acc = make_float4(0.f, 0.f, 0.f, 0.f);
    float d = 0.f;

    int j = beg;
    for (; j + 8 <= end; j += 8) {
        unsigned ku[8];
        ushort4 vu[8];
        #pragma unroll
        for (int u = 0; u < 8; u++) {
            int s = csr[j + u];
            ku[u] = k8[(size_t)s * 64 + lane];
            vu[u] = ((const ushort4*)(vb + (size_t)s * 256))[lane];
        }
        float p[8];
        #pragma unroll
        for (int u = 0; u < 8; u++) {
            f32x2 lo = __builtin_amdgcn_cvt_pk_f32_fp8((int)ku[u], false);
            f32x2 hi = __builtin_amdgcn_cvt_pk_f32_fp8((int)ku[u], true);
            p[u] = q4.x * lo.x + q4.y * lo.y + q4.z * hi.x + q4.w * hi.y;
        }
        #pragma unroll
        for (int o = 16; o >= 1; o >>= 1) {
            #pragma unroll
            for (int u = 0; u < 8; u++) p[u] += __shfl_xor(p[u], o);
        }
        #pragma unroll
        for (int u = 0; u < 8; u++) {
            float e = __expf(p[u] * SCALE);
            d += e;
            acc.x = fmaf(e, bf2f(vu[u].x), acc.x);
            acc.y = fmaf(e, bf2f(vu[u].y), acc.y);
            acc.z = fmaf(e, bf2f(vu[u].z), acc.z);
            acc.w = fmaf(e, bf2f(vu[u].w), acc.w);
        }
    }
    for (; j < end; j++) {
        int s = csr[j];
        unsigned ku = k8[(size_t)s * 64 + lane];
        ushort4 vu = ((const ushort4*)(vb + (size_t)s * 256))[lane];
        f32x2 lo = __builtin_amdgcn_cvt_pk_f32_fp8((int)ku, false);
        f32x2 hi = __builtin_amdgcn_cvt_pk_f32_fp8((int)ku, true);
        float p = q4.x * lo.x + q4.y * lo.y + q4.z * hi.x + q4.w * hi.y;
        #pragma unroll
        for (int o = 16; o >= 1; o >>= 1) p += __shfl_xor(p, o);
        float e = __expf(p * SCALE);
        d += e;
        acc.x = fmaf(e, bf2f(vu.x), acc.x);
        acc.y = fmaf(e, bf2f(vu.y), acc.y);
        acc.z = fmaf(e, bf2f(vu.z), acc.z);
        acc.w = fmaf(e, bf2f(vu.w), acc.w);
    }

    float inv = 1.f / (d + 1e-16f);
    ushort4 hv;
    hv.x = f2bf(acc.x * inv);
    hv.y = f2bf(acc.y * inv);
    hv.z = f2bf(acc.z * inv);
    hv.w = f2bf(acc.w * inv);
    ((ushort4*)(hout + (size_t)n * 256))[lane] = hv;
}

// ---------------------------------------------------------------------------
// Pool init: zero psum/pmax + per-graph counts via binary search (gi sorted).
// ---------------------------------------------------------------------------
__global__ __launch_bounds__(256) void pool_init_kernel(const int* __restrict__ gi,
                                                        int* __restrict__ pcnt,
                                                        float* __restrict__ psum,
                                                        unsigned* __restrict__ pmax) {
    int t = threadIdx.x;
    float4* ps = (float4*)psum;    // 2048 float4
    uint4*  pm = (uint4*)pmax;
    for (int i = t; i < 2048; i += 256) {
        ps[i] = make_float4(0.f, 0.f, 0.f, 0.f);
        uint4 z; z.x = z.y = z.z = z.w = 0u;
        pm[i] = z;
    }
    if (t < NGRAPH) {
        auto lb = [&](int target) {
            int lo = 0, hi = N_NODES;
            while (lo < hi) {
                int mid = (lo + hi) >> 1;
                if (gi[mid] < target) lo = mid + 1;
                else hi = mid;
            }
            return lo;
        };
        int a = lb(t), b = lb(t + 1);
        pcnt[t] = b - a;
    }
}

// ---------------------------------------------------------------------------
// Pooling from bf16 x, ushort4-vectorized, run-compressed (gi sorted).
// relu output >= 0 => uint atomicMax order-correct, 0 is the identity.
// ---------------------------------------------------------------------------
__global__ __launch_bounds__(256) void pool_accum_kernel(
    const unsigned short* __restrict__ xb, const int* __restrict__ gi,
    float* __restrict__ psum, unsigned* __restrict__ pmax) {
    int n0 = blockIdx.x * 128;
    int c4 = (threadIdx.x & 31) * 4;        // 4 consecutive cols
    int phase = threadIdx.x >> 5;           // 0..7
    int first = n0 + phase;
    if (first >= N_NODES) return;
    float s0 = 0.f, s1 = 0.f, s2 = 0.f, s3 = 0.f;
    float m0 = 0.f, m1 = 0.f, m2 = 0.f, m3 = 0.f;
    int cur_g = gi[first];
    for (int r = phase; r < 128; r += 8) {
        int n = n0 + r;
        if (n >= N_NODES) break;
        int g = gi[n];
        if (g != cur_g) {
            float* ps = &psum[cur_g * 128 + c4];
            unsigned* pm = &pmax[cur_g * 128 + c4];
            atomicAdd(ps + 0, s0); atomicAdd(ps + 1, s1);
            atomicAdd(ps + 2, s2); atomicAdd(ps + 3, s3);
            atomicMax(pm + 0, __float_as_uint(m0)); atomicMax(pm + 1, __float_as_uint(m1));
            atomicMax(pm + 2, __float_as_uint(m2)); atomicMax(pm + 3, __float_as_uint(m3));
            s0 = s1 = s2 = s3 = 0.f;
            m0 = m1 = m2 = m3 = 0.f;
            cur_g = g;
        }
        ushort4 u = *(const ushort4*)(xb + (size_t)n * 128 + c4);
        float v0 = bf2f(u.x), v1 = bf2f(u.y), v2 = bf2f(u.z), v3 = bf2f(u.w);
        s0 += v0; s1 += v1; s2 += v2; s3 += v3;
        m0 = fmaxf(m0, v0); m1 = fmaxf(m1, v1);
        m2 = fmaxf(m2, v2); m3 = fmaxf(m3, v3);
    }
    float* ps = &psum[cur_g * 128 + c4];
    unsigned* pm = &pmax[cur_g * 128 + c4];
    atomicAdd(ps + 0, s0); atomicAdd(ps + 1, s1);
    atomicAdd(ps + 2, s2); atomicAdd(ps + 3, s3);
    atomicMax(pm + 0, __float_as_uint(m0)); atomicMax(pm + 1, __float_as_uint(m1));
    atomicMax(pm + 2, __float_as_uint(m2)); atomicMax(pm + 3, __float_as_uint(m3));
}

__global__ void pool_final_kernel(const float* __restrict__ psum, const unsigned* __restrict__ pmax,
                                  const int* __restrict__ pcnt, float* __restrict__ out) {
    int idx = blockIdx.x * 256 + threadIdx.x;
    if (idx >= NGRAPH * 384) return;
    int g = idx / 384, c = idx % 384;
    float r;
    if (c < 128)       r = __uint_as_float(pmax[g * 128 + c]);
    else if (c < 256)  r = psum[g * 128 + (c - 128)] / fmaxf((float)pcnt[g], 1.f);
    else               r = psum[g * 128 + (c - 256)];
    out[idx] = r;
}

// ---------------------------------------------------------------------------
extern "C" void kernel_launch(void* const* d_in, const int* in_sizes, int n_in,
                              void* d_out, int out_size, void* d_ws, size_t ws_size,
                              hipStream_t stream) {
    const float* x   = (const float*)d_in[0];
    const int*   ei  = (const int*)d_in[1];
    const int*   gi  = (const int*)d_in[2];
    const float* Wq  = (const float*)d_in[3];
    const float* bq  = (const float*)d_in[4];
    const float* Wk  = (const float*)d_in[5];
    const float* bk  = (const float*)d_in[6];
    const float* Wv  = (const float*)d_in[7];
    const float* bv  = (const float*)d_in[8];
    const float* Wsk = (const float*)d_in[9];
    const float* bsk = (const float*)d_in[10];
    const float* Wt  = (const float*)d_in[11];
    const float* bt  = (const float*)d_in[12];
    float* out = (float*)d_out;

    char* p = (char*)d_ws;
    auto take = [&](size_t bytes) -> char* {
        char* r = p;
        p += (bytes + 255) & ~(size_t)255;
        return r;
    };
    unsigned short* qbuf   = (unsigned short*)take((size_t)N_NODES * 256 * 2);  // q bf16
    unsigned*       k8buf  = (unsigned*)take((size_t)N_NODES * 64 * 4);         // k fp8 (packed)
    unsigned short* vbuf   = (unsigned short*)take((size_t)N_NODES * 256 * 2);  // v bf16
    unsigned short* xb     = (unsigned short*)take((size_t)N_NODES * 128 * 2);  // x0 bf16 / final x
    unsigned short* xb2    = (unsigned short*)take((size_t)N_NODES * 128 * 2);  // x1 bf16
    unsigned short* hb     = (unsigned short*)take((size_t)N_NODES * 256 * 2);  // attn out bf16
    unsigned short* Wqkvp  = (unsigned short*)take((size_t)196608 * 2);         // packed qkv
    unsigned short* Wfp    = (unsigned short*)take((size_t)98304 * 2);          // packed [Wt;Wc]
    float*          Wc     = (float*)take(2 * 128 * 128 * 4);
    float*          bc     = (float*)take(2 * 128 * 4);
    int*            counts = (int*)take((size_t)N_NODES * 4);
    int*            offs   = (int*)take((size_t)(N_NODES + 1) * 4);
    int*            cursor = (int*)take((size_t)N_NODES * 4);
    int*            csr    = (int*)take((size_t)N_EDGES * 4);
    int*            bsum   = (int*)take((size_t)SCAN_BLOCKS * 4);
    int*            boff   = (int*)take((size_t)SCAN_BLOCKS * 4);
    float*          psum   = (float*)take(NGRAPH * 128 * 4);
    unsigned*       pmax   = (unsigned*)take(NGRAPH * 128 * 4);
    int*            pcnt   = (int*)take(NGRAPH * 4);

    const int EB = (N_EDGES + 255) / 256;          // 3125
    const int GB = (N_NODES + 127) / 128;          // 391  (MFMA GEMM / pooling blocks)
    const int AB = (N_NODES + 3) / 4;              // 12500 (attn blocks, 4 dst/block)

    // ---- CSR build ----
    hipMemsetAsync(counts, 0, (size_t)N_NODES * 4, stream);
    degree_kernel<<<EB, 256, 0, stream>>>(ei, counts);
    block_sum_kernel<<<SCAN_BLOCKS, 256, 0, stream>>>(counts, bsum);
    scan_bsum_kernel<<<1, 256, 0, stream>>>(bsum, boff);
    block_scan_kernel<<<SCAN_BLOCKS, 256, 0, stream>>>(counts, boff, offs, cursor);
    scatter_kernel<<<EB, 256, 0, stream>>>(ei, cursor, csr);

    // ---- weight prep ----
    wc_kernel<<<128, 256, 0, stream>>>(Wsk, Wt, Wc);
    bc_kernel<<<1, 256, 0, stream>>>(bsk, Wt, bt, bc);
    pack_qkv_kernel<<<768, 256, 0, stream>>>(Wq, Wk, Wv, Wqkvp);
    pack_fused_kernel<<<384, 256, 0, stream>>>(Wt, Wc, Wfp);

    // ---- layer 0 ----
    fproj_kernel<<<GB, 256, 0, stream>>>(x, xb, Wqkvp, bq, bk, bv, qbuf, k8buf, vbuf);
    attn_kernel<<<AB, 256, 0, stream>>>(qbuf, k8buf, vbuf, offs, csr, hb);
    // out(L0) fused with proj(L1)
    outproj_kernel<<<GB, 256, 0, stream>>>(hb, xb, Wfp, bc, xb2,
                                           Wqkvp + 98304, bq + 256, bk + 256, bv + 256,
                                           qbuf, k8buf, vbuf, 1);
    // ---- layer 1 ----
    attn_kernel<<<AB, 256, 0, stream>>>(qbuf, k8buf, vbuf, offs, csr, hb);
    outproj_kernel<<<GB, 256, 0, stream>>>(hb, xb2, Wfp + 49152, bc + 128, xb,
                                           Wqkvp, bq, bk, bv, qbuf, k8buf, vbuf, 0);

    // ---- pooling ----
    pool_init_kernel<<<1, 256, 0, stream>>>(gi, pcnt, psum, pmax);
    pool_accum_kernel<<<GB, 256, 0, stream>>>(xb, gi, psum, pmax);
    pool_final_kernel<<<(NGRAPH * 384 + 255) / 256, 256, 0, stream>>>(psum, pmax, pcnt, out);
}

// Round 11
// 520.756 us; speedup vs baseline: 1.2363x; 1.0690x over previous
//
#include <hip/hip_runtime.h>
#include <math.h>

#define N_NODES 50000
#define N_EDGES 800000
#define NGRAPH  64
#define SCAN_BLOCKS ((N_NODES + 255) / 256)   // 196
#define LROW 136   // LDS x-tile row stride (shorts): 272B -> bank step 4, 2-way max

typedef __bf16 bf16x8 __attribute__((ext_vector_type(8)));
typedef float  f32x4  __attribute__((ext_vector_type(4)));
typedef float  f32x2  __attribute__((ext_vector_type(2)));

__device__ __forceinline__ unsigned short f2bf(float f) {
    unsigned u = __float_as_uint(f);
    u += 0x7fff + ((u >> 16) & 1);          // round-to-nearest-even
    return (unsigned short)(u >> 16);
}
__device__ __forceinline__ float bf2f(unsigned short u) {
    return __uint_as_float((unsigned)u << 16);
}

// ---------------------------------------------------------------------------
// CSR build
// ---------------------------------------------------------------------------
__global__ void degree_kernel(const int* __restrict__ ei, int* __restrict__ counts) {
    int e = blockIdx.x * 256 + threadIdx.x;
    if (e < N_EDGES) atomicAdd(&counts[ei[N_EDGES + e]], 1);
}

__global__ __launch_bounds__(256) void block_sum_kernel(const int* __restrict__ counts,
                                                        int* __restrict__ bsum) {
    int i = blockIdx.x * 256 + threadIdx.x;
    int v = (i < N_NODES) ? counts[i] : 0;
    #pragma unroll
    for (int o = 32; o >= 1; o >>= 1) v += __shfl_xor(v, o);
    __shared__ int ws[4];
    if ((threadIdx.x & 63) == 0) ws[threadIdx.x >> 6] = v;
    __syncthreads();
    if (threadIdx.x == 0) bsum[blockIdx.x] = ws[0] + ws[1] + ws[2] + ws[3];
}

__global__ __launch_bounds__(256) void scan_bsum_kernel(const int* __restrict__ bsum,
                                                        int* __restrict__ boff) {
    int t = threadIdx.x;
    int v = (t < SCAN_BLOCKS) ? bsum[t] : 0;
    int lane = t & 63, wid = t >> 6;
    int incl = v;
    #pragma unroll
    for (int o = 1; o < 64; o <<= 1) {
        int tv = __shfl_up(incl, o);
        if (lane >= o) incl += tv;
    }
    __shared__ int wsum[4];
    if (lane == 63) wsum[wid] = incl;
    __syncthreads();
    int add = 0;
    for (int w = 0; w < wid; w++) add += wsum[w];
    if (t < SCAN_BLOCKS) boff[t] = add + incl - v;   // exclusive
}

__global__ __launch_bounds__(256) void block_scan_kernel(const int* __restrict__ counts,
                                                         const int* __restrict__ boff,
                                                         int* __restrict__ offs,
                                                         int* __restrict__ cursor) {
    int i = blockIdx.x * 256 + threadIdx.x;
    int v = (i < N_NODES) ? counts[i] : 0;
    int lane = threadIdx.x & 63, wid = threadIdx.x >> 6;
    int incl = v;
    #pragma unroll
    for (int o = 1; o < 64; o <<= 1) {
        int tv = __shfl_up(incl, o);
        if (lane >= o) incl += tv;
    }
    __shared__ int wsum[4];
    if (lane == 63) wsum[wid] = incl;
    __syncthreads();
    int add = boff[blockIdx.x];
    for (int w = 0; w < wid; w++) add += wsum[w];
    if (i < N_NODES) {
        offs[i + 1] = add + incl;
        cursor[i]   = add + incl - v;
    }
    if (i == 0) offs[0] = 0;
}

__global__ void scatter_kernel(const int* __restrict__ ei, int* __restrict__ cursor,
                               int* __restrict__ csr) {
    int e = blockIdx.x * 256 + threadIdx.x;
    if (e < N_EDGES) {
        int d = ei[N_EDGES + e];
        int pos = atomicAdd(&cursor[d], 1);
        csr[pos] = ei[e];  // src
    }
}

// ---------------------------------------------------------------------------
// Skip-path fusion (fp32): Wc[l] = Ws[l] @ Wt[l], bc[l] = bs[l] @ Wt[l] + bt[l]
// ---------------------------------------------------------------------------
__global__ void wc_kernel(const float* __restrict__ Ws, const float* __restrict__ Wt,
                          float* __restrict__ Wc) {
    int idx = blockIdx.x * 256 + threadIdx.x;       // 2*128*128 = 32768
    int l = idx >> 14, ij = idx & 16383, i = ij >> 7, j = ij & 127;
    const float* a = Ws + (size_t)l * 32768;
    const float* b = Wt + (size_t)l * 32768;
    float s = 0.f;
    for (int k = 0; k < 256; k++) s = fmaf(a[i * 256 + k], b[k * 128 + j], s);
    Wc[idx] = s;
}

__global__ void bc_kernel(const float* __restrict__ bs, const float* __restrict__ Wt,
                          const float* __restrict__ bt, float* __restrict__ bc) {
    int idx = threadIdx.x;                           // 2 layers x 128
    int l = idx >> 7, j = idx & 127;
    const float* b = Wt + (size_t)l * 32768;
    float s = bt[l * 128 + j];
    for (int k = 0; k < 256; k++) s = fmaf(bs[l * 256 + k], b[k * 128 + j], s);
    bc[idx] = s;
}

// ---------------------------------------------------------------------------
// Weight packing into MFMA fragment layout (bf16, ks-major). Serves as the
// A operand in the swapped (A=W, B=x) GEMMs.
// ---------------------------------------------------------------------------
__global__ void pack_qkv_kernel(const float* __restrict__ Wq, const float* __restrict__ Wk,
                                const float* __restrict__ Wv, unsigned short* __restrict__ out) {
    int idx = blockIdx.x * 256 + threadIdx.x;        // 2*3*32768 = 196608
    if (idx >= 196608) return;
    int j = idx & 7, lane = (idx >> 3) & 63, ct = (idx >> 9) & 15, ks = (idx >> 13) & 3;
    int m3 = idx >> 15;                              // 0..5
    int l = m3 / 3, m = m3 % 3;
    int k = ks * 32 + ((lane >> 4) * 8) + j;
    int n = ct * 16 + (lane & 15);
    const float* W = (m == 0) ? Wq : (m == 1) ? Wk : Wv;
    out[idx] = f2bf(W[(size_t)l * 32768 + k * 256 + n]);
}

// fused [Wt;Wc] (K=384): KS=12 (ks 0..7 from Wt, 8..11 from Wc), CT=8
__global__ void pack_fused_kernel(const float* __restrict__ Wt, const float* __restrict__ Wc,
                                  unsigned short* __restrict__ out) {
    int idx = blockIdx.x * 256 + threadIdx.x;        // 2*49152 = 98304
    if (idx >= 98304) return;
    int l = idx / 49152, r = idx % 49152;
    int j = r & 7, lane = (r >> 3) & 63;
    int rest = r >> 9;
    int ct = rest & 7, ks = rest >> 3;               // ks 0..11
    int k = ks * 32 + ((lane >> 4) * 8) + j;
    int n = ct * 16 + (lane & 15);
    float v = (k < 256) ? Wt[(size_t)l * 32768 + k * 128 + n]
                        : Wc[(size_t)l * 16384 + (k - 256) * 128 + n];
    out[idx] = f2bf(v);
}

// ---------------------------------------------------------------------------
// Shared proj stage: qkv projection for a 32-node wave tile whose bf16 x rows
// sit in LDS. q -> bf16 [N,256]; k,v -> fp8 e4m3 packed into kv8 rows of
// 128 uints: uint 2c = k channels [4c..4c+3], uint 2c+1 = v channels.
// Attn lane l reads its whole edge slice as ONE uint2 (8B).
// ---------------------------------------------------------------------------
__device__ __forceinline__ void proj_from_lds(
    const unsigned short* T, const unsigned short* __restrict__ Wp,
    const float* __restrict__ b0, const float* __restrict__ b1, const float* __restrict__ b2,
    unsigned short* __restrict__ oq, unsigned* __restrict__ kv8,
    int rbase, int quad, int lr, int lane) {
    int n0 = rbase + lr, n1 = rbase + 16 + lr;
    bf16x8 a0[4], a1[4];
    #pragma unroll
    for (int ks = 0; ks < 4; ks++) {
        a0[ks] = *(const bf16x8*)(T + lr * LROW + ks * 32 + quad * 8);
        a1[ks] = *(const bf16x8*)(T + (16 + lr) * LROW + ks * 32 + quad * 8);
    }
    const float* bias[3] = {b0, b1, b2};
    for (int mm = 0; mm < 3; mm++) {
        const unsigned short* wp = Wp + mm * 32768;
        for (int ct = 0; ct < 16; ct++) {
            f32x4 c0 = {0.f, 0.f, 0.f, 0.f}, c1 = {0.f, 0.f, 0.f, 0.f};
            #pragma unroll
            for (int ks = 0; ks < 4; ks++) {
                bf16x8 wf = *(const bf16x8*)(wp + (size_t)((ks * 16 + ct) * 64 + lane) * 8);
                c0 = __builtin_amdgcn_mfma_f32_16x16x32_bf16(wf, a0[ks], c0, 0, 0, 0);
                c1 = __builtin_amdgcn_mfma_f32_16x16x32_bf16(wf, a1[ks], c1, 0, 0, 0);
            }
            int ob = ct * 16 + quad * 4;
            float4 bb = *(const float4*)&bias[mm][ob];
            float v00 = c0[0] + bb.x, v01 = c0[1] + bb.y, v02 = c0[2] + bb.z, v03 = c0[3] + bb.w;
            float v10 = c1[0] + bb.x, v11 = c1[1] + bb.y, v12 = c1[2] + bb.z, v13 = c1[3] + bb.w;
            if (mm == 0) {
                ushort4 s0, s1;
                s0.x = f2bf(v00); s0.y = f2bf(v01); s0.z = f2bf(v02); s0.w = f2bf(v03);
                s1.x = f2bf(v10); s1.y = f2bf(v11); s1.z = f2bf(v12); s1.w = f2bf(v13);
                if (n0 < N_NODES) *(ushort4*)(oq + (size_t)n0 * 256 + ob) = s0;
                if (n1 < N_NODES) *(ushort4*)(oq + (size_t)n1 * 256 + ob) = s1;
            } else {
                // k (mm=1) or v (mm=2) -> fp8 e4m3 (HW pack, RNE)
                int u0 = __builtin_amdgcn_cvt_pk_fp8_f32(v00, v01, 0, false);
                u0 = __builtin_amdgcn_cvt_pk_fp8_f32(v02, v03, u0, true);
                int u1 = __builtin_amdgcn_cvt_pk_fp8_f32(v10, v11, 0, false);
                u1 = __builtin_amdgcn_cvt_pk_fp8_f32(v12, v13, u1, true);
                int kvo = (ob >> 2) * 2 + (mm - 1);   // 2c for k, 2c+1 for v
                if (n0 < N_NODES) kv8[(size_t)n0 * 128 + kvo] = (unsigned)u0;
                if (n1 < N_NODES) kv8[(size_t)n1 * 128 + kvo] = (unsigned)u1;
            }
        }
    }
}

// ---------------------------------------------------------------------------
// Layer-0 front: fp32 x -> bf16 xb (global) + LDS tile, then qkv projection.
// ---------------------------------------------------------------------------
__global__ __launch_bounds__(256) void fproj_kernel(
    const float* __restrict__ xf, unsigned short* __restrict__ xb,
    const unsigned short* __restrict__ Wp,
    const float* __restrict__ b0, const float* __restrict__ b1, const float* __restrict__ b2,
    unsigned short* __restrict__ oq, unsigned* __restrict__ kv8) {
    __shared__ unsigned short tile[4][32 * LROW];
    int w = threadIdx.x >> 6, lane = threadIdx.x & 63;
    int quad = lane >> 4, lr = lane & 15;
    int rbase = blockIdx.x * 128 + w * 32;
    unsigned short* T = tile[w];

    #pragma unroll
    for (int s = 0; s < 2; s++) {
        int row = rbase + s * 16 + lr;
        if (row < N_NODES) {
            const float4* src = (const float4*)(xf + (size_t)row * 128 + quad * 32);
            ushort4* gdst = (ushort4*)(xb + (size_t)row * 128 + quad * 32);
            ushort4* ldst = (ushort4*)(T + (s * 16 + lr) * LROW + quad * 32);
            #pragma unroll
            for (int i = 0; i < 8; i++) {
                float4 v = src[i];
                ushort4 o;
                o.x = f2bf(v.x); o.y = f2bf(v.y); o.z = f2bf(v.z); o.w = f2bf(v.w);
                gdst[i] = o;
                ldst[i] = o;
            }
        }
    }
    __syncthreads();
    proj_from_lds(T, Wp, b0, b1, b2, oq, kv8, rbase, quad, lr, lane);
}

// ---------------------------------------------------------------------------
// Fused output linear (+ next layer's qkv projection when do_proj):
// x_next = relu([h|x] @ [Wt;Wc] + bc) -> global bf16 + LDS tile -> proj.
// ---------------------------------------------------------------------------
__global__ __launch_bounds__(256) void outproj_kernel(
    const unsigned short* __restrict__ hb, const unsigned short* __restrict__ xbin,
    const unsigned short* __restrict__ Wfp, const float* __restrict__ bc,
    unsigned short* __restrict__ xbout,
    const unsigned short* __restrict__ Wp,
    const float* __restrict__ b0, const float* __restrict__ b1, const float* __restrict__ b2,
    unsigned short* __restrict__ oq, unsigned* __restrict__ kv8, int do_proj) {
    __shared__ unsigned short tile[4][32 * LROW];
    int w = threadIdx.x >> 6, lane = threadIdx.x & 63;
    int quad = lane >> 4, lr = lane & 15;
    int rbase = blockIdx.x * 128 + w * 32;
    int n0 = rbase + lr, n1 = rbase + 16 + lr;
    int n0c = min(n0, N_NODES - 1), n1c = min(n1, N_NODES - 1);
    unsigned short* T = tile[w];

    f32x4 acc[8][2];
    #pragma unroll
    for (int ct = 0; ct < 8; ct++) {
        acc[ct][0] = (f32x4){0.f, 0.f, 0.f, 0.f};
        acc[ct][1] = (f32x4){0.f, 0.f, 0.f, 0.f};
    }

    #pragma unroll 4
    for (int ks = 0; ks < 12; ks++) {
        bf16x8 a0, a1;
        if (ks < 8) {
            a0 = *(const bf16x8*)(hb + (size_t)n0c * 256 + ks * 32 + quad * 8);
            a1 = *(const bf16x8*)(hb + (size_t)n1c * 256 + ks * 32 + quad * 8);
        } else {
            a0 = *(const bf16x8*)(xbin + (size_t)n0c * 128 + (ks - 8) * 32 + quad * 8);
            a1 = *(const bf16x8*)(xbin + (size_t)n1c * 128 + (ks - 8) * 32 + quad * 8);
        }
        #pragma unroll
        for (int ct = 0; ct < 8; ct++) {
            bf16x8 wf = *(const bf16x8*)(Wfp + (size_t)((ks * 8 + ct) * 64 + lane) * 8);
            acc[ct][0] = __builtin_amdgcn_mfma_f32_16x16x32_bf16(wf, a0, acc[ct][0], 0, 0, 0);
            acc[ct][1] = __builtin_amdgcn_mfma_f32_16x16x32_bf16(wf, a1, acc[ct][1], 0, 0, 0);
        }
    }

    #pragma unroll
    for (int ct = 0; ct < 8; ct++) {
        int ob = ct * 16 + quad * 4;
        float4 bb = *(const float4*)&bc[ob];
        ushort4 s0, s1;
        s0.x = f2bf(fmaxf(acc[ct][0][0] + bb.x, 0.f));
        s0.y = f2bf(fmaxf(acc[ct][0][1] + bb.y, 0.f));
        s0.z = f2bf(fmaxf(acc[ct][0][2] + bb.z, 0.f));
        s0.w = f2bf(fmaxf(acc[ct][0][3] + bb.w, 0.f));
        s1.x = f2bf(fmaxf(acc[ct][1][0] + bb.x, 0.f));
        s1.y = f2bf(fmaxf(acc[ct][1][1] + bb.y, 0.f));
        s1.z = f2bf(fmaxf(acc[ct][1][2] + bb.z, 0.f));
        s1.w = f2bf(fmaxf(acc[ct][1][3] + bb.w, 0.f));
        if (n0 < N_NODES) *(ushort4*)(xbout + (size_t)n0 * 128 + ob) = s0;
        if (n1 < N_NODES) *(ushort4*)(xbout + (size_t)n1 * 128 + ob) = s1;
        *(ushort4*)(T + lr * LROW + ob) = s0;
        *(ushort4*)(T + (16 + lr) * LROW + ob) = s1;
    }

    if (do_proj) {
        __syncthreads();
        proj_from_lds(T, Wp, b0, b1, b2, oq, kv8, rbase, quad, lr, lane);
    }
}

// ---------------------------------------------------------------------------
// Attention: 256-thread blocks, one dst/wave, unroll 8. Single pass, no
// max-subtraction (|logit|<~3, exp-safe; softmax shift-invariant).
// k,v both fp8 e4m3: lane reads ONE uint2 (8B) = [k-pack | v-pack] per edge.
// Lanes 0..31 head0, 32..63 head1; intra-32 butterfly.
// ---------------------------------------------------------------------------
__global__ __launch_bounds__(256) void attn_kernel(
    const unsigned short* __restrict__ q, const unsigned* __restrict__ kv8,
    const int* __restrict__ offs, const int* __restrict__ csr,
    unsigned short* __restrict__ hout) {
    const float SCALE = 0.08838834764831845f;  // 1/sqrt(128)
    int w = threadIdx.x >> 6, lane = threadIdx.x & 63;
    int n = blockIdx.x * 4 + w;                // 12500*4 = 50000 exactly
    ushort4 qu = ((const ushort4*)(q + (size_t)n * 256))[lane];
    float4 q4 = make_float4(bf2f(qu.x), bf2f(qu.y), bf2f(qu.z), bf2f(qu.w));
    int beg = offs[n], end = offs[n + 1];

    float4 acc = make_float4(0.f, 0.f, 0.f, 0.f);
    float d = 0.f;

    int j = beg;
    for (; j + 8 <= end; j += 8) {
        uint2 c[8];
        #pragma unroll
        for (int u = 0; u < 8; u++) {
            int s = csr[j + u];
            c[u] = ((const uint2*)(kv8 + (size_t)s * 128))[lane];
        }
        float p[8];
        #pragma unroll
        for (int u = 0; u < 8; u++) {
            f32x2 lo = __builtin_amdgcn_cvt_pk_f32_fp8((int)c[u].x, false);
            f32x2 hi = __builtin_amdgcn_cvt_pk_f32_fp8((int)c[u].x, true);
            p[u] = q4.x * lo.x + q4.y * lo.y + q4.z * hi.x + q4.w * hi.y;
        }
        #pragma unroll
        for (int o = 16; o >= 1; o >>= 1) {
            #pragma unroll
            for (int u = 0; u < 8; u++) p[u] += __shfl_xor(p[u], o);
        }
        #pragma unroll
        for (int u = 0; u < 8; u++) {
            float e = __expf(p[u] * SCALE);
            d += e;
            f32x2 vlo = __builtin_amdgcn_cvt_pk_f32_fp8((int)c[u].y, false);
            f32x2 vhi = __builtin_amdgcn_cvt_pk_f32_fp8((int)c[u].y, true);
            acc.x = fmaf(e, vlo.x, acc.x);
            acc.y = fmaf(e, vlo.y, acc.y);
            acc.z = fmaf(e, vhi.x, acc.z);
            acc.w = fmaf(e, vhi.y, acc.w);
        }
    }
    for (; j < end; j++) {
        int s = csr[j];
        uint2 c = ((const uint2*)(kv8 + (size_t)s * 128))[lane];
        f32x2 lo = __builtin_amdgcn_cvt_pk_f32_fp8((int)c.x, false);
        f32x2 hi = __builtin_amdgcn_cvt_pk_f32_fp8((int)c.x, true);
        float p = q4.x * lo.x + q4.y * lo.y + q4.z * hi.x + q4.w * hi.y;
        #pragma unroll
        for (int o = 16; o >= 1; o >>= 1) p += __shfl_xor(p, o);
        float e = __expf(p * SCALE);
        d += e;
        f32x2 vlo = __builtin_amdgcn_cvt_pk_f32_fp8((int)c.y, false);
        f32x2 vhi = __builtin_amdgcn_cvt_pk_f32_fp8((int)c.y, true);
        acc.x = fmaf(e, vlo.x, acc.x);
        acc.y = fmaf(e, vlo.y, acc.y);
        acc.z = fmaf(e, vhi.x, acc.z);
        acc.w = fmaf(e, vhi.y, acc.w);
    }

    float inv = 1.f / (d + 1e-16f);
    ushort4 hv;
    hv.x = f2bf(acc.x * inv);
    hv.y = f2bf(acc.y * inv);
    hv.z = f2bf(acc.z * inv);
    hv.w = f2bf(acc.w * inv);
    ((ushort4*)(hout + (size_t)n * 256))[lane] = hv;
}

// ---------------------------------------------------------------------------
// Pool init: zero psum/pmax + per-graph counts via binary search (gi sorted).
// ---------------------------------------------------------------------------
__global__ __launch_bounds__(256) void pool_init_kernel(const int* __restrict__ gi,
                                                        int* __restrict__ pcnt,
                                                        float* __restrict__ psum,
                                                        unsigned* __restrict__ pmax) {
    int t = threadIdx.x;
    float4* ps = (float4*)psum;    // 2048 float4
    uint4*  pm = (uint4*)pmax;
    for (int i = t; i < 2048; i += 256) {
        ps[i] = make_float4(0.f, 0.f, 0.f, 0.f);
        uint4 z; z.x = z.y = z.z = z.w = 0u;
        pm[i] = z;
    }
    if (t < NGRAPH) {
        auto lb = [&](int target) {
            int lo = 0, hi = N_NODES;
            while (lo < hi) {
                int mid = (lo + hi) >> 1;
                if (gi[mid] < target) lo = mid + 1;
                else hi = mid;
            }
            return lo;
        };
        int a = lb(t), b = lb(t + 1);
        pcnt[t] = b - a;
    }
}

// ---------------------------------------------------------------------------
// Pooling from bf16 x, ushort4-vectorized, run-compressed (gi sorted).
// relu output >= 0 => uint atomicMax order-correct, 0 is the identity.
// ---------------------------------------------------------------------------
__global__ __launch_bounds__(256) void pool_accum_kernel(
    const unsigned short* __restrict__ xb, const int* __restrict__ gi,
    float* __restrict__ psum, unsigned* __restrict__ pmax) {
    int n0 = blockIdx.x * 128;
    int c4 = (threadIdx.x & 31) * 4;        // 4 consecutive cols
    int phase = threadIdx.x >> 5;           // 0..7
    int first = n0 + phase;
    if (first >= N_NODES) return;
    float s0 = 0.f, s1 = 0.f, s2 = 0.f, s3 = 0.f;
    float m0 = 0.f, m1 = 0.f, m2 = 0.f, m3 = 0.f;
    int cur_g = gi[first];
    for (int r = phase; r < 128; r += 8) {
        int n = n0 + r;
        if (n >= N_NODES) break;
        int g = gi[n];
        if (g != cur_g) {
            float* ps = &psum[cur_g * 128 + c4];
            unsigned* pm = &pmax[cur_g * 128 + c4];
            atomicAdd(ps + 0, s0); atomicAdd(ps + 1, s1);
            atomicAdd(ps + 2, s2); atomicAdd(ps + 3, s3);
            atomicMax(pm + 0, __float_as_uint(m0)); atomicMax(pm + 1, __float_as_uint(m1));
            atomicMax(pm + 2, __float_as_uint(m2)); atomicMax(pm + 3, __float_as_uint(m3));
            s0 = s1 = s2 = s3 = 0.f;
            m0 = m1 = m2 = m3 = 0.f;
            cur_g = g;
        }
        ushort4 u = *(const ushort4*)(xb + (size_t)n * 128 + c4);
        float v0 = bf2f(u.x), v1 = bf2f(u.y), v2 = bf2f(u.z), v3 = bf2f(u.w);
        s0 += v0; s1 += v1; s2 += v2; s3 += v3;
        m0 = fmaxf(m0, v0); m1 = fmaxf(m1, v1);
        m2 = fmaxf(m2, v2); m3 = fmaxf(m3, v3);
    }
    float* ps = &psum[cur_g * 128 + c4];
    unsigned* pm = &pmax[cur_g * 128 + c4];
    atomicAdd(ps + 0, s0); atomicAdd(ps + 1, s1);
    atomicAdd(ps + 2, s2); atomicAdd(ps + 3, s3);
    atomicMax(pm + 0, __float_as_uint(m0)); atomicMax(pm + 1, __float_as_uint(m1));
    atomicMax(pm + 2, __float_as_uint(m2)); atomicMax(pm + 3, __float_as_uint(m3));
}

__global__ void pool_final_kernel(const float* __restrict__ psum, const unsigned* __restrict__ pmax,
                                  const int* __restrict__ pcnt, float* __restrict__ out) {
    int idx = blockIdx.x * 256 + threadIdx.x;
    if (idx >= NGRAPH * 384) return;
    int g = idx / 384, c = idx % 384;
    float r;
    if (c < 128)       r = __uint_as_float(pmax[g * 128 + c]);
    else if (c < 256)  r = psum[g * 128 + (c - 128)] / fmaxf((float)pcnt[g], 1.f);
    else               r = psum[g * 128 + (c - 256)];
    out[idx] = r;
}

// ---------------------------------------------------------------------------
extern "C" void kernel_launch(void* const* d_in, const int* in_sizes, int n_in,
                              void* d_out, int out_size, void* d_ws, size_t ws_size,
                              hipStream_t stream) {
    const float* x   = (const float*)d_in[0];
    const int*   ei  = (const int*)d_in[1];
    const int*   gi  = (const int*)d_in[2];
    const float* Wq  = (const float*)d_in[3];
    const float* bq  = (const float*)d_in[4];
    const float* Wk  = (const float*)d_in[5];
    const float* bk  = (const float*)d_in[6];
    const float* Wv  = (const float*)d_in[7];
    const float* bv  = (const float*)d_in[8];
    const float* Wsk = (const float*)d_in[9];
    const float* bsk = (const float*)d_in[10];
    const float* Wt  = (const float*)d_in[11];
    const float* bt  = (const float*)d_in[12];
    float* out = (float*)d_out;

    char* p = (char*)d_ws;
    auto take = [&](size_t bytes) -> char* {
        char* r = p;
        p += (bytes + 255) & ~(size_t)255;
        return r;
    };
    unsigned short* qbuf   = (unsigned short*)take((size_t)N_NODES * 256 * 2);  // q bf16
    unsigned*       kv8buf = (unsigned*)take((size_t)N_NODES * 128 * 4);        // k|v fp8 packed
    unsigned short* xb     = (unsigned short*)take((size_t)N_NODES * 128 * 2);  // x0 bf16 / final x
    unsigned short* xb2    = (unsigned short*)take((size_t)N_NODES * 128 * 2);  // x1 bf16
    unsigned short* hb     = (unsigned short*)take((size_t)N_NODES * 256 * 2);  // attn out bf16
    unsigned short* Wqkvp  = (unsigned short*)take((size_t)196608 * 2);         // packed qkv
    unsigned short* Wfp    = (unsigned short*)take((size_t)98304 * 2);          // packed [Wt;Wc]
    float*          Wc     = (float*)take(2 * 128 * 128 * 4);
    float*          bc     = (float*)take(2 * 128 * 4);
    int*            counts = (int*)take((size_t)N_NODES * 4);
    int*            offs   = (int*)take((size_t)(N_NODES + 1) * 4);
    int*            cursor = (int*)take((size_t)N_NODES * 4);
    int*            csr    = (int*)take((size_t)N_EDGES * 4);
    int*            bsum   = (int*)take((size_t)SCAN_BLOCKS * 4);
    int*            boff   = (int*)take((size_t)SCAN_BLOCKS * 4);
    float*          psum   = (float*)take(NGRAPH * 128 * 4);
    unsigned*       pmax   = (unsigned*)take(NGRAPH * 128 * 4);
    int*            pcnt   = (int*)take(NGRAPH * 4);

    const int EB = (N_EDGES + 255) / 256;          // 3125
    const int GB = (N_NODES + 127) / 128;          // 391  (MFMA GEMM / pooling blocks)
    const int AB = (N_NODES + 3) / 4;              // 12500 (attn blocks, 4 dst/block)

    // ---- CSR build ----
    hipMemsetAsync(counts, 0, (size_t)N_NODES * 4, stream);
    degree_kernel<<<EB, 256, 0, stream>>>(ei, counts);
    block_sum_kernel<<<SCAN_BLOCKS, 256, 0, stream>>>(counts, bsum);
    scan_bsum_kernel<<<1, 256, 0, stream>>>(bsum, boff);
    block_scan_kernel<<<SCAN_BLOCKS, 256, 0, stream>>>(counts, boff, offs, cursor);
    scatter_kernel<<<EB, 256, 0, stream>>>(ei, cursor, csr);

    // ---- weight prep ----
    wc_kernel<<<128, 256, 0, stream>>>(Wsk, Wt, Wc);
    bc_kernel<<<1, 256, 0, stream>>>(bsk, Wt, bt, bc);
    pack_qkv_kernel<<<768, 256, 0, stream>>>(Wq, Wk, Wv, Wqkvp);
    pack_fused_kernel<<<384, 256, 0, stream>>>(Wt, Wc, Wfp);

    // ---- layer 0 ----
    fproj_kernel<<<GB, 256, 0, stream>>>(x, xb, Wqkvp, bq, bk, bv, qbuf, kv8buf);
    attn_kernel<<<AB, 256, 0, stream>>>(qbuf, kv8buf, offs, csr, hb);
    // out(L0) fused with proj(L1)
    outproj_kernel<<<GB, 256, 0, stream>>>(hb, xb, Wfp, bc, xb2,
                                           Wqkvp + 98304, bq + 256, bk + 256, bv + 256,
                                           qbuf, kv8buf, 1);
    // ---- layer 1 ----
    attn_kernel<<<AB, 256, 0, stream>>>(qbuf, kv8buf, offs, csr, hb);
    outproj_kernel<<<GB, 256, 0, stream>>>(hb, xb2, Wfp + 49152, bc + 128, xb,
                                           Wqkvp, bq, bk, bv, qbuf, kv8buf, 0);

    // ---- pooling ----
    pool_init_kernel<<<1, 256, 0, stream>>>(gi, pcnt, psum, pmax);
    pool_accum_kernel<<<GB, 256, 0, stream>>>(xb, gi, psum, pmax);
    pool_final_kernel<<<(NGRAPH * 384 + 255) / 256, 256, 0, stream>>>(psum, pmax, pcnt, out);
}

// Round 12
// 519.135 us; speedup vs baseline: 1.2402x; 1.0031x over previous
//
#include <hip/hip_runtime.h>
#include <math.h>

#define N_NODES 50000
#define N_EDGES 800000
#define NGRAPH  64
#define SCAN_BLOCKS ((N_NODES + 255) / 256)   // 196
#define LROW 136   // LDS x-tile row stride (shorts): 272B, 16B-aligned rows

typedef __bf16 bf16x8 __attribute__((ext_vector_type(8)));
typedef float  f32x4  __attribute__((ext_vector_type(4)));
typedef float  f32x2  __attribute__((ext_vector_type(2)));

__device__ __forceinline__ unsigned short f2bf(float f) {
    unsigned u = __float_as_uint(f);
    u += 0x7fff + ((u >> 16) & 1);          // round-to-nearest-even
    return (unsigned short)(u >> 16);
}
__device__ __forceinline__ float bf2f(unsigned short u) {
    return __uint_as_float((unsigned)u << 16);
}

// ---------------------------------------------------------------------------
// CSR build
// ---------------------------------------------------------------------------
__global__ void degree_kernel(const int* __restrict__ ei, int* __restrict__ counts) {
    int e = blockIdx.x * 256 + threadIdx.x;
    if (e < N_EDGES) atomicAdd(&counts[ei[N_EDGES + e]], 1);
}

__global__ __launch_bounds__(256) void block_sum_kernel(const int* __restrict__ counts,
                                                        int* __restrict__ bsum) {
    int i = blockIdx.x * 256 + threadIdx.x;
    int v = (i < N_NODES) ? counts[i] : 0;
    #pragma unroll
    for (int o = 32; o >= 1; o >>= 1) v += __shfl_xor(v, o);
    __shared__ int ws[4];
    if ((threadIdx.x & 63) == 0) ws[threadIdx.x >> 6] = v;
    __syncthreads();
    if (threadIdx.x == 0) bsum[blockIdx.x] = ws[0] + ws[1] + ws[2] + ws[3];
}

__global__ __launch_bounds__(256) void scan_bsum_kernel(const int* __restrict__ bsum,
                                                        int* __restrict__ boff) {
    int t = threadIdx.x;
    int v = (t < SCAN_BLOCKS) ? bsum[t] : 0;
    int lane = t & 63, wid = t >> 6;
    int incl = v;
    #pragma unroll
    for (int o = 1; o < 64; o <<= 1) {
        int tv = __shfl_up(incl, o);
        if (lane >= o) incl += tv;
    }
    __shared__ int wsum[4];
    if (lane == 63) wsum[wid] = incl;
    __syncthreads();
    int add = 0;
    for (int w = 0; w < wid; w++) add += wsum[w];
    if (t < SCAN_BLOCKS) boff[t] = add + incl - v;   // exclusive
}

__global__ __launch_bounds__(256) void block_scan_kernel(const int* __restrict__ counts,
                                                         const int* __restrict__ boff,
                                                         int* __restrict__ offs,
                                                         int* __restrict__ cursor) {
    int i = blockIdx.x * 256 + threadIdx.x;
    int v = (i < N_NODES) ? counts[i] : 0;
    int lane = threadIdx.x & 63, wid = threadIdx.x >> 6;
    int incl = v;
    #pragma unroll
    for (int o = 1; o < 64; o <<= 1) {
        int tv = __shfl_up(incl, o);
        if (lane >= o) incl += tv;
    }
    __shared__ int wsum[4];
    if (lane == 63) wsum[wid] = incl;
    __syncthreads();
    int add = boff[blockIdx.x];
    for (int w = 0; w < wid; w++) add += wsum[w];
    if (i < N_NODES) {
        offs[i + 1] = add + incl;
        cursor[i]   = add + incl - v;
    }
    if (i == 0) offs[0] = 0;
}

__global__ void scatter_kernel(const int* __restrict__ ei, int* __restrict__ cursor,
                               int* __restrict__ csr) {
    int e = blockIdx.x * 256 + threadIdx.x;
    if (e < N_EDGES) {
        int d = ei[N_EDGES + e];
        int pos = atomicAdd(&cursor[d], 1);
        csr[pos] = ei[e];  // src
    }
}

// ---------------------------------------------------------------------------
// Skip-path fusion (fp32): Wc[l] = Ws[l] @ Wt[l], bc[l] = bs[l] @ Wt[l] + bt[l]
// ---------------------------------------------------------------------------
__global__ void wc_kernel(const float* __restrict__ Ws, const float* __restrict__ Wt,
                          float* __restrict__ Wc) {
    int idx = blockIdx.x * 256 + threadIdx.x;       // 2*128*128 = 32768
    int l = idx >> 14, ij = idx & 16383, i = ij >> 7, j = ij & 127;
    const float* a = Ws + (size_t)l * 32768;
    const float* b = Wt + (size_t)l * 32768;
    float s = 0.f;
    for (int k = 0; k < 256; k++) s = fmaf(a[i * 256 + k], b[k * 128 + j], s);
    Wc[idx] = s;
}

__global__ void bc_kernel(const float* __restrict__ bs, const float* __restrict__ Wt,
                          const float* __restrict__ bt, float* __restrict__ bc) {
    int idx = threadIdx.x;                           // 2 layers x 128
    int l = idx >> 7, j = idx & 127;
    const float* b = Wt + (size_t)l * 32768;
    float s = bt[l * 128 + j];
    for (int k = 0; k < 256; k++) s = fmaf(bs[l * 256 + k], b[k * 128 + j], s);
    bc[idx] = s;
}

// ---------------------------------------------------------------------------
// Weight packing into MFMA fragment layout (bf16, ks-major). Serves as the
// A operand in the swapped (A=W, B=x) GEMMs.
// ---------------------------------------------------------------------------
__global__ void pack_qkv_kernel(const float* __restrict__ Wq, const float* __restrict__ Wk,
                                const float* __restrict__ Wv, unsigned short* __restrict__ out) {
    int idx = blockIdx.x * 256 + threadIdx.x;        // 2*3*32768 = 196608
    if (idx >= 196608) return;
    int j = idx & 7, lane = (idx >> 3) & 63, ct = (idx >> 9) & 15, ks = (idx >> 13) & 3;
    int m3 = idx >> 15;                              // 0..5
    int l = m3 / 3, m = m3 % 3;
    int k = ks * 32 + ((lane >> 4) * 8) + j;
    int n = ct * 16 + (lane & 15);
    const float* W = (m == 0) ? Wq : (m == 1) ? Wk : Wv;
    out[idx] = f2bf(W[(size_t)l * 32768 + k * 256 + n]);
}

// fused [Wt;Wc] (K=384): KS=12 (ks 0..7 from Wt, 8..11 from Wc), CT=8
__global__ void pack_fused_kernel(const float* __restrict__ Wt, const float* __restrict__ Wc,
                                  unsigned short* __restrict__ out) {
    int idx = blockIdx.x * 256 + threadIdx.x;        // 2*49152 = 98304
    if (idx >= 98304) return;
    int l = idx / 49152, r = idx % 49152;
    int j = r & 7, lane = (r >> 3) & 63;
    int rest = r >> 9;
    int ct = rest & 7, ks = rest >> 3;               // ks 0..11
    int k = ks * 32 + ((lane >> 4) * 8) + j;
    int n = ct * 16 + (lane & 15);
    float v = (k < 256) ? Wt[(size_t)l * 32768 + k * 128 + n]
                        : Wc[(size_t)l * 16384 + (k - 256) * 128 + n];
    out[idx] = f2bf(v);
}

// ---------------------------------------------------------------------------
// Shared proj stage: qkv projection for a 32-node wave tile whose bf16 x rows
// sit in LDS. q -> bf16 [N,256]; k,v -> fp8 e4m3 packed into kv8 rows of
// 128 uints: uint 2c = k channels [4c..4c+3], uint 2c+1 = v channels.
// ---------------------------------------------------------------------------
__device__ __forceinline__ void proj_from_lds(
    const unsigned short* T, const unsigned short* __restrict__ Wp,
    const float* __restrict__ b0, const float* __restrict__ b1, const float* __restrict__ b2,
    unsigned short* __restrict__ oq, unsigned* __restrict__ kv8,
    int rbase, int quad, int lr, int lane) {
    int n0 = rbase + lr, n1 = rbase + 16 + lr;
    bf16x8 a0[4], a1[4];
    #pragma unroll
    for (int ks = 0; ks < 4; ks++) {
        a0[ks] = *(const bf16x8*)(T + lr * LROW + ks * 32 + quad * 8);
        a1[ks] = *(const bf16x8*)(T + (16 + lr) * LROW + ks * 32 + quad * 8);
    }
    const float* bias[3] = {b0, b1, b2};
    for (int mm = 0; mm < 3; mm++) {
        const unsigned short* wp = Wp + mm * 32768;
        for (int ct = 0; ct < 16; ct++) {
            f32x4 c0 = {0.f, 0.f, 0.f, 0.f}, c1 = {0.f, 0.f, 0.f, 0.f};
            #pragma unroll
            for (int ks = 0; ks < 4; ks++) {
                bf16x8 wf = *(const bf16x8*)(wp + (size_t)((ks * 16 + ct) * 64 + lane) * 8);
                c0 = __builtin_amdgcn_mfma_f32_16x16x32_bf16(wf, a0[ks], c0, 0, 0, 0);
                c1 = __builtin_amdgcn_mfma_f32_16x16x32_bf16(wf, a1[ks], c1, 0, 0, 0);
            }
            int ob = ct * 16 + quad * 4;
            float4 bb = *(const float4*)&bias[mm][ob];
            float v00 = c0[0] + bb.x, v01 = c0[1] + bb.y, v02 = c0[2] + bb.z, v03 = c0[3] + bb.w;
            float v10 = c1[0] + bb.x, v11 = c1[1] + bb.y, v12 = c1[2] + bb.z, v13 = c1[3] + bb.w;
            if (mm == 0) {
                ushort4 s0, s1;
                s0.x = f2bf(v00); s0.y = f2bf(v01); s0.z = f2bf(v02); s0.w = f2bf(v03);
                s1.x = f2bf(v10); s1.y = f2bf(v11); s1.z = f2bf(v12); s1.w = f2bf(v13);
                if (n0 < N_NODES) *(ushort4*)(oq + (size_t)n0 * 256 + ob) = s0;
                if (n1 < N_NODES) *(ushort4*)(oq + (size_t)n1 * 256 + ob) = s1;
            } else {
                // k (mm=1) or v (mm=2) -> fp8 e4m3 (HW pack, RNE)
                int u0 = __builtin_amdgcn_cvt_pk_fp8_f32(v00, v01, 0, false);
                u0 = __builtin_amdgcn_cvt_pk_fp8_f32(v02, v03, u0, true);
                int u1 = __builtin_amdgcn_cvt_pk_fp8_f32(v10, v11, 0, false);
                u1 = __builtin_amdgcn_cvt_pk_fp8_f32(v12, v13, u1, true);
                int kvo = (ob >> 2) * 2 + (mm - 1);   // 2c for k, 2c+1 for v
                if (n0 < N_NODES) kv8[(size_t)n0 * 128 + kvo] = (unsigned)u0;
                if (n1 < N_NODES) kv8[(size_t)n1 * 128 + kvo] = (unsigned)u1;
            }
        }
    }
}

// ---------------------------------------------------------------------------
// Layer-0 front (ONE-WAVE blocks, grid 1563): fp32 x -> bf16 xb (global) +
// LDS tile, then qkv projection. Per-wave tile => no cross-wave dependency;
// 64-thread blocks give ~6 blocks/CU instead of 1.5.
// ---------------------------------------------------------------------------
__global__ __launch_bounds__(64) void fproj_kernel(
    const float* __restrict__ xf, unsigned short* __restrict__ xb,
    const unsigned short* __restrict__ Wp,
    const float* __restrict__ b0, const float* __restrict__ b1, const float* __restrict__ b2,
    unsigned short* __restrict__ oq, unsigned* __restrict__ kv8) {
    __shared__ unsigned short T[32 * LROW];
    int lane = threadIdx.x;
    int quad = lane >> 4, lr = lane & 15;
    int rbase = blockIdx.x * 32;

    #pragma unroll
    for (int s = 0; s < 2; s++) {
        int row = rbase + s * 16 + lr;
        if (row < N_NODES) {
            const float4* src = (const float4*)(xf + (size_t)row * 128 + quad * 32);
            ushort4* gdst = (ushort4*)(xb + (size_t)row * 128 + quad * 32);
            ushort4* ldst = (ushort4*)(T + (s * 16 + lr) * LROW + quad * 32);
            #pragma unroll
            for (int i = 0; i < 8; i++) {
                float4 v = src[i];
                ushort4 o;
                o.x = f2bf(v.x); o.y = f2bf(v.y); o.z = f2bf(v.z); o.w = f2bf(v.w);
                gdst[i] = o;
                ldst[i] = o;
            }
        }
    }
    __syncthreads();
    proj_from_lds(T, Wp, b0, b1, b2, oq, kv8, rbase, quad, lr, lane);
}

// ---------------------------------------------------------------------------
// Fused output linear (+ next layer's qkv projection when do_proj), ONE-WAVE
// blocks: x_next = relu([h|x] @ [Wt;Wc] + bc) -> global bf16 + LDS tile -> proj.
// ---------------------------------------------------------------------------
__global__ __launch_bounds__(64) void outproj_kernel(
    const unsigned short* __restrict__ hb, const unsigned short* __restrict__ xbin,
    const unsigned short* __restrict__ Wfp, const float* __restrict__ bc,
    unsigned short* __restrict__ xbout,
    const unsigned short* __restrict__ Wp,
    const float* __restrict__ b0, const float* __restrict__ b1, const float* __restrict__ b2,
    unsigned short* __restrict__ oq, unsigned* __restrict__ kv8, int do_proj) {
    __shared__ unsigned short T[32 * LROW];
    int lane = threadIdx.x;
    int quad = lane >> 4, lr = lane & 15;
    int rbase = blockIdx.x * 32;
    int n0 = rbase + lr, n1 = rbase + 16 + lr;
    int n0c = min(n0, N_NODES - 1), n1c = min(n1, N_NODES - 1);

    f32x4 acc[8][2];
    #pragma unroll
    for (int ct = 0; ct < 8; ct++) {
        acc[ct][0] = (f32x4){0.f, 0.f, 0.f, 0.f};
        acc[ct][1] = (f32x4){0.f, 0.f, 0.f, 0.f};
    }

    #pragma unroll 4
    for (int ks = 0; ks < 12; ks++) {
        bf16x8 a0, a1;
        if (ks < 8) {
            a0 = *(const bf16x8*)(hb + (size_t)n0c * 256 + ks * 32 + quad * 8);
            a1 = *(const bf16x8*)(hb + (size_t)n1c * 256 + ks * 32 + quad * 8);
        } else {
            a0 = *(const bf16x8*)(xbin + (size_t)n0c * 128 + (ks - 8) * 32 + quad * 8);
            a1 = *(const bf16x8*)(xbin + (size_t)n1c * 128 + (ks - 8) * 32 + quad * 8);
        }
        #pragma unroll
        for (int ct = 0; ct < 8; ct++) {
            bf16x8 wf = *(const bf16x8*)(Wfp + (size_t)((ks * 8 + ct) * 64 + lane) * 8);
            acc[ct][0] = __builtin_amdgcn_mfma_f32_16x16x32_bf16(wf, a0, acc[ct][0], 0, 0, 0);
            acc[ct][1] = __builtin_amdgcn_mfma_f32_16x16x32_bf16(wf, a1, acc[ct][1], 0, 0, 0);
        }
    }

    #pragma unroll
    for (int ct = 0; ct < 8; ct++) {
        int ob = ct * 16 + quad * 4;
        float4 bb = *(const float4*)&bc[ob];
        ushort4 s0, s1;
        s0.x = f2bf(fmaxf(acc[ct][0][0] + bb.x, 0.f));
        s0.y = f2bf(fmaxf(acc[ct][0][1] + bb.y, 0.f));
        s0.z = f2bf(fmaxf(acc[ct][0][2] + bb.z, 0.f));
        s0.w = f2bf(fmaxf(acc[ct][0][3] + bb.w, 0.f));
        s1.x = f2bf(fmaxf(acc[ct][1][0] + bb.x, 0.f));
        s1.y = f2bf(fmaxf(acc[ct][1][1] + bb.y, 0.f));
        s1.z = f2bf(fmaxf(acc[ct][1][2] + bb.z, 0.f));
        s1.w = f2bf(fmaxf(acc[ct][1][3] + bb.w, 0.f));
        if (n0 < N_NODES) *(ushort4*)(xbout + (size_t)n0 * 128 + ob) = s0;
        if (n1 < N_NODES) *(ushort4*)(xbout + (size_t)n1 * 128 + ob) = s1;
        *(ushort4*)(T + lr * LROW + ob) = s0;
        *(ushort4*)(T + (16 + lr) * LROW + ob) = s1;
    }

    if (do_proj) {
        __syncthreads();
        proj_from_lds(T, Wp, b0, b1, b2, oq, kv8, rbase, quad, lr, lane);
    }
}

// ---------------------------------------------------------------------------
// Attention: 256-thread blocks, one dst/wave, unroll 8. Single pass, no
// max-subtraction (|logit|<~3, exp-safe; softmax shift-invariant).
// k,v both fp8 e4m3: lane reads ONE uint2 (8B) = [k-pack | v-pack] per edge.
// ---------------------------------------------------------------------------
__global__ __launch_bounds__(256) void attn_kernel(
    const unsigned short* __restrict__ q, const unsigned* __restrict__ kv8,
    const int* __restrict__ offs, const int* __restrict__ csr,
    unsigned short* __restrict__ hout) {
    const float SCALE = 0.08838834764831845f;  // 1/sqrt(128)
    int w = threadIdx.x >> 6, lane = threadIdx.x & 63;
    int n = blockIdx.x * 4 + w;                // 12500*4 = 50000 exactly
    ushort4 qu = ((const ushort4*)(q + (size_t)n * 256))[lane];
    float4 q4 = make_float4(bf2f(qu.x), bf2f(qu.y), bf2f(qu.z), bf2f(qu.w));
    int beg = offs[n], end = offs[n + 1];

    float4 acc = make_float4(0.f, 0.f, 0.f, 0.f);
    float d = 0.f;

    int j = beg;
    for (; j + 8 <= end; j += 8) {
        uint2 c[8];
        #pragma unroll
        for (int u = 0; u < 8; u++) {
            int s = csr[j + u];
            c[u] = ((const uint2*)(kv8 + (size_t)s * 128))[lane];
        }
        float p[8];
        #pragma unroll
        for (int u = 0; u < 8; u++) {
            f32x2 lo = __builtin_amdgcn_cvt_pk_f32_fp8((int)c[u].x, false);
            f32x2 hi = __builtin_amdgcn_cvt_pk_f32_fp8((int)c[u].x, true);
            p[u] = q4.x * lo.x + q4.y * lo.y + q4.z * hi.x + q4.w * hi.y;
        }
        #pragma unroll
        for (int o = 16; o >= 1; o >>= 1) {
            #pragma unroll
            for (int u = 0; u < 8; u++) p[u] += __shfl_xor(p[u], o);
        }
        #pragma unroll
        for (int u = 0; u < 8; u++) {
            float e = __expf(p[u] * SCALE);
            d += e;
            f32x2 vlo = __builtin_amdgcn_cvt_pk_f32_fp8((int)c[u].y, false);
            f32x2 vhi = __builtin_amdgcn_cvt_pk_f32_fp8((int)c[u].y, true);
            acc.x = fmaf(e, vlo.x, acc.x);
            acc.y = fmaf(e, vlo.y, acc.y);
            acc.z = fmaf(e, vhi.x, acc.z);
            acc.w = fmaf(e, vhi.y, acc.w);
        }
    }
    for (; j < end; j++) {
        int s = csr[j];
        uint2 c = ((const uint2*)(kv8 + (size_t)s * 128))[lane];
        f32x2 lo = __builtin_amdgcn_cvt_pk_f32_fp8((int)c.x, false);
        f32x2 hi = __builtin_amdgcn_cvt_pk_f32_fp8((int)c.x, true);
        float p = q4.x * lo.x + q4.y * lo.y + q4.z * hi.x + q4.w * hi.y;
        #pragma unroll
        for (int o = 16; o >= 1; o >>= 1) p += __shfl_xor(p, o);
        float e = __expf(p * SCALE);
        d += e;
        f32x2 vlo = __builtin_amdgcn_cvt_pk_f32_fp8((int)c.y, false);
        f32x2 vhi = __builtin_amdgcn_cvt_pk_f32_fp8((int)c.y, true);
        acc.x = fmaf(e, vlo.x, acc.x);
        acc.y = fmaf(e, vlo.y, acc.y);
        acc.z = fmaf(e, vhi.x, acc.z);
        acc.w = fmaf(e, vhi.y, acc.w);
    }

    float inv = 1.f / (d + 1e-16f);
    ushort4 hv;
    hv.x = f2bf(acc.x * inv);
    hv.y = f2bf(acc.y * inv);
    hv.z = f2bf(acc.z * inv);
    hv.w = f2bf(acc.w * inv);
    ((ushort4*)(hout + (size_t)n * 256))[lane] = hv;
}

// ---------------------------------------------------------------------------
// Pool init: zero psum/pmax + per-graph counts via binary search (gi sorted).
// ---------------------------------------------------------------------------
__global__ __launch_bounds__(256) void pool_init_kernel(const int* __restrict__ gi,
                                                        int* __restrict__ pcnt,
                                                        float* __restrict__ psum,
                                                        unsigned* __restrict__ pmax) {
    int t = threadIdx.x;
    float4* ps = (float4*)psum;    // 2048 float4
    uint4*  pm = (uint4*)pmax;
    for (int i = t; i < 2048; i += 256) {
        ps[i] = make_float4(0.f, 0.f, 0.f, 0.f);
        uint4 z; z.x = z.y = z.z = z.w = 0u;
        pm[i] = z;
    }
    if (t < NGRAPH) {
        auto lb = [&](int target) {
            int lo = 0, hi = N_NODES;
            while (lo < hi) {
                int mid = (lo + hi) >> 1;
                if (gi[mid] < target) lo = mid + 1;
                else hi = mid;
            }
            return lo;
        };
        int a = lb(t), b = lb(t + 1);
        pcnt[t] = b - a;
    }
}

// ---------------------------------------------------------------------------
// Pooling from bf16 x, ushort4-vectorized, run-compressed (gi sorted).
// relu output >= 0 => uint atomicMax order-correct, 0 is the identity.
// ---------------------------------------------------------------------------
__global__ __launch_bounds__(256) void pool_accum_kernel(
    const unsigned short* __restrict__ xb, const int* __restrict__ gi,
    float* __restrict__ psum, unsigned* __restrict__ pmax) {
    int n0 = blockIdx.x * 128;
    int c4 = (threadIdx.x & 31) * 4;        // 4 consecutive cols
    int phase = threadIdx.x >> 5;           // 0..7
    int first = n0 + phase;
    if (first >= N_NODES) return;
    float s0 = 0.f, s1 = 0.f, s2 = 0.f, s3 = 0.f;
    float m0 = 0.f, m1 = 0.f, m2 = 0.f, m3 = 0.f;
    int cur_g = gi[first];
    for (int r = phase; r < 128; r += 8) {
        int n = n0 + r;
        if (n >= N_NODES) break;
        int g = gi[n];
        if (g != cur_g) {
            float* ps = &psum[cur_g * 128 + c4];
            unsigned* pm = &pmax[cur_g * 128 + c4];
            atomicAdd(ps + 0, s0); atomicAdd(ps + 1, s1);
            atomicAdd(ps + 2, s2); atomicAdd(ps + 3, s3);
            atomicMax(pm + 0, __float_as_uint(m0)); atomicMax(pm + 1, __float_as_uint(m1));
            atomicMax(pm + 2, __float_as_uint(m2)); atomicMax(pm + 3, __float_as_uint(m3));
            s0 = s1 = s2 = s3 = 0.f;
            m0 = m1 = m2 = m3 = 0.f;
            cur_g = g;
        }
        ushort4 u = *(const ushort4*)(xb + (size_t)n * 128 + c4);
        float v0 = bf2f(u.x), v1 = bf2f(u.y), v2 = bf2f(u.z), v3 = bf2f(u.w);
        s0 += v0; s1 += v1; s2 += v2; s3 += v3;
        m0 = fmaxf(m0, v0); m1 = fmaxf(m1, v1);
        m2 = fmaxf(m2, v2); m3 = fmaxf(m3, v3);
    }
    float* ps = &psum[cur_g * 128 + c4];
    unsigned* pm = &pmax[cur_g * 128 + c4];
    atomicAdd(ps + 0, s0); atomicAdd(ps + 1, s1);
    atomicAdd(ps + 2, s2); atomicAdd(ps + 3, s3);
    atomicMax(pm + 0, __float_as_uint(m0)); atomicMax(pm + 1, __float_as_uint(m1));
    atomicMax(pm + 2, __float_as_uint(m2)); atomicMax(pm + 3, __float_as_uint(m3));
}

__global__ void pool_final_kernel(const float* __restrict__ psum, const unsigned* __restrict__ pmax,
                                  const int* __restrict__ pcnt, float* __restrict__ out) {
    int idx = blockIdx.x * 256 + threadIdx.x;
    if (idx >= NGRAPH * 384) return;
    int g = idx / 384, c = idx % 384;
    float r;
    if (c < 128)       r = __uint_as_float(pmax[g * 128 + c]);
    else if (c < 256)  r = psum[g * 128 + (c - 128)] / fmaxf((float)pcnt[g], 1.f);
    else               r = psum[g * 128 + (c - 256)];
    out[idx] = r;
}

// ---------------------------------------------------------------------------
extern "C" void kernel_launch(void* const* d_in, const int* in_sizes, int n_in,
                              void* d_out, int out_size, void* d_ws, size_t ws_size,
                              hipStream_t stream) {
    const float* x   = (const float*)d_in[0];
    const int*   ei  = (const int*)d_in[1];
    const int*   gi  = (const int*)d_in[2];
    const float* Wq  = (const float*)d_in[3];
    const float* bq  = (const float*)d_in[4];
    const float* Wk  = (const float*)d_in[5];
    const float* bk  = (const float*)d_in[6];
    const float* Wv  = (const float*)d_in[7];
    const float* bv  = (const float*)d_in[8];
    const float* Wsk = (const float*)d_in[9];
    const float* bsk = (const float*)d_in[10];
    const float* Wt  = (const float*)d_in[11];
    const float* bt  = (const float*)d_in[12];
    float* out = (float*)d_out;

    char* p = (char*)d_ws;
    auto take = [&](size_t bytes) -> char* {
        char* r = p;
        p += (bytes + 255) & ~(size_t)255;
        return r;
    };
    unsigned short* qbuf   = (unsigned short*)take((size_t)N_NODES * 256 * 2);  // q bf16
    unsigned*       kv8buf = (unsigned*)take((size_t)N_NODES * 128 * 4);        // k|v fp8 packed
    unsigned short* xb     = (unsigned short*)take((size_t)N_NODES * 128 * 2);  // x0 bf16 / final x
    unsigned short* xb2    = (unsigned short*)take((size_t)N_NODES * 128 * 2);  // x1 bf16
    unsigned short* hb     = (unsigned short*)take((size_t)N_NODES * 256 * 2);  // attn out bf16
    unsigned short* Wqkvp  = (unsigned short*)take((size_t)196608 * 2);         // packed qkv
    unsigned short* Wfp    = (unsigned short*)take((size_t)98304 * 2);          // packed [Wt;Wc]
    float*          Wc     = (float*)take(2 * 128 * 128 * 4);
    float*          bc     = (float*)take(2 * 128 * 4);
    int*            counts = (int*)take((size_t)N_NODES * 4);
    int*            offs   = (int*)take((size_t)(N_NODES + 1) * 4);
    int*            cursor = (int*)take((size_t)N_NODES * 4);
    int*            csr    = (int*)take((size_t)N_EDGES * 4);
    int*            bsum   = (int*)take((size_t)SCAN_BLOCKS * 4);
    int*            boff   = (int*)take((size_t)SCAN_BLOCKS * 4);
    float*          psum   = (float*)take(NGRAPH * 128 * 4);
    unsigned*       pmax   = (unsigned*)take(NGRAPH * 128 * 4);
    int*            pcnt   = (int*)take(NGRAPH * 4);

    const int EB  = (N_EDGES + 255) / 256;         // 3125
    const int GBW = (N_NODES + 31) / 32;           // 1563 (one-wave GEMM blocks)
    const int PB  = (N_NODES + 127) / 128;         // 391  (pooling blocks)
    const int AB  = (N_NODES + 3) / 4;             // 12500 (attn blocks, 4 dst/block)

    // ---- CSR build ----
    hipMemsetAsync(counts, 0, (size_t)N_NODES * 4, stream);
    degree_kernel<<<EB, 256, 0, stream>>>(ei, counts);
    block_sum_kernel<<<SCAN_BLOCKS, 256, 0, stream>>>(counts, bsum);
    scan_bsum_kernel<<<1, 256, 0, stream>>>(bsum, boff);
    block_scan_kernel<<<SCAN_BLOCKS, 256, 0, stream>>>(counts, boff, offs, cursor);
    scatter_kernel<<<EB, 256, 0, stream>>>(ei, cursor, csr);

    // ---- weight prep ----
    wc_kernel<<<128, 256, 0, stream>>>(Wsk, Wt, Wc);
    bc_kernel<<<1, 256, 0, stream>>>(bsk, Wt, bt, bc);
    pack_qkv_kernel<<<768, 256, 0, stream>>>(Wq, Wk, Wv, Wqkvp);
    pack_fused_kernel<<<384, 256, 0, stream>>>(Wt, Wc, Wfp);

    // ---- layer 0 ----
    fproj_kernel<<<GBW, 64, 0, stream>>>(x, xb, Wqkvp, bq, bk, bv, qbuf, kv8buf);
    attn_kernel<<<AB, 256, 0, stream>>>(qbuf, kv8buf, offs, csr, hb);
    // out(L0) fused with proj(L1)
    outproj_kernel<<<GBW, 64, 0, stream>>>(hb, xb, Wfp, bc, xb2,
                                           Wqkvp + 98304, bq + 256, bk + 256, bv + 256,
                                           qbuf, kv8buf, 1);
    // ---- layer 1 ----
    attn_kernel<<<AB, 256, 0, stream>>>(qbuf, kv8buf, offs, csr, hb);
    outproj_kernel<<<GBW, 64, 0, stream>>>(hb, xb2, Wfp + 49152, bc + 128, xb,
                                           Wqkvp, bq, bk, bv, qbuf, kv8buf, 0);

    // ---- pooling ----
    pool_init_kernel<<<1, 256, 0, stream>>>(gi, pcnt, psum, pmax);
    pool_accum_kernel<<<PB, 256, 0, stream>>>(xb, gi, psum, pmax);
    pool_final_kernel<<<(NGRAPH * 384 + 255) / 256, 256, 0, stream>>>(psum, pmax, pcnt, out);
}

// Round 13
// 471.168 us; speedup vs baseline: 1.3664x; 1.1018x over previous
//
#include <hip/hip_runtime.h>
#include <math.h>

#define N_NODES 50000
#define N_EDGES 800000
#define NGRAPH  64
#define SCAN_BLOCKS ((N_NODES + 255) / 256)   // 196
#define LROW 136   // LDS x-tile row stride (shorts): 272B, 16B-aligned rows

typedef __bf16 bf16x8 __attribute__((ext_vector_type(8)));
typedef float  f32x4  __attribute__((ext_vector_type(4)));
typedef float  f32x2  __attribute__((ext_vector_type(2)));

__device__ __forceinline__ unsigned short f2bf(float f) {
    unsigned u = __float_as_uint(f);
    u += 0x7fff + ((u >> 16) & 1);          // round-to-nearest-even
    return (unsigned short)(u >> 16);
}
__device__ __forceinline__ float bf2f(unsigned short u) {
    return __uint_as_float((unsigned)u << 16);
}

// ---------------------------------------------------------------------------
// CSR build
// ---------------------------------------------------------------------------
__global__ void degree_kernel(const int* __restrict__ ei, int* __restrict__ counts) {
    int e = blockIdx.x * 256 + threadIdx.x;
    if (e < N_EDGES) atomicAdd(&counts[ei[N_EDGES + e]], 1);
}

__global__ __launch_bounds__(256) void block_sum_kernel(const int* __restrict__ counts,
                                                        int* __restrict__ bsum) {
    int i = blockIdx.x * 256 + threadIdx.x;
    int v = (i < N_NODES) ? counts[i] : 0;
    #pragma unroll
    for (int o = 32; o >= 1; o >>= 1) v += __shfl_xor(v, o);
    __shared__ int ws[4];
    if ((threadIdx.x & 63) == 0) ws[threadIdx.x >> 6] = v;
    __syncthreads();
    if (threadIdx.x == 0) bsum[blockIdx.x] = ws[0] + ws[1] + ws[2] + ws[3];
}

__global__ __launch_bounds__(256) void scan_bsum_kernel(const int* __restrict__ bsum,
                                                        int* __restrict__ boff) {
    int t = threadIdx.x;
    int v = (t < SCAN_BLOCKS) ? bsum[t] : 0;
    int lane = t & 63, wid = t >> 6;
    int incl = v;
    #pragma unroll
    for (int o = 1; o < 64; o <<= 1) {
        int tv = __shfl_up(incl, o);
        if (lane >= o) incl += tv;
    }
    __shared__ int wsum[4];
    if (lane == 63) wsum[wid] = incl;
    __syncthreads();
    int add = 0;
    for (int w = 0; w < wid; w++) add += wsum[w];
    if (t < SCAN_BLOCKS) boff[t] = add + incl - v;   // exclusive
}

__global__ __launch_bounds__(256) void block_scan_kernel(const int* __restrict__ counts,
                                                         const int* __restrict__ boff,
                                                         int* __restrict__ offs,
                                                         int* __restrict__ cursor) {
    int i = blockIdx.x * 256 + threadIdx.x;
    int v = (i < N_NODES) ? counts[i] : 0;
    int lane = threadIdx.x & 63, wid = threadIdx.x >> 6;
    int incl = v;
    #pragma unroll
    for (int o = 1; o < 64; o <<= 1) {
        int tv = __shfl_up(incl, o);
        if (lane >= o) incl += tv;
    }
    __shared__ int wsum[4];
    if (lane == 63) wsum[wid] = incl;
    __syncthreads();
    int add = boff[blockIdx.x];
    for (int w = 0; w < wid; w++) add += wsum[w];
    if (i < N_NODES) {
        offs[i + 1] = add + incl;
        cursor[i]   = add + incl - v;
    }
    if (i == 0) offs[0] = 0;
}

__global__ void scatter_kernel(const int* __restrict__ ei, int* __restrict__ cursor,
                               int* __restrict__ csr) {
    int e = blockIdx.x * 256 + threadIdx.x;
    if (e < N_EDGES) {
        int d = ei[N_EDGES + e];
        int pos = atomicAdd(&cursor[d], 1);
        csr[pos] = ei[e];  // src
    }
}

// ---------------------------------------------------------------------------
// Skip-path fusion (fp32): Wc[l] = Ws[l] @ Wt[l], bc[l] = bs[l] @ Wt[l] + bt[l]
// ---------------------------------------------------------------------------
__global__ void wc_kernel(const float* __restrict__ Ws, const float* __restrict__ Wt,
                          float* __restrict__ Wc) {
    int idx = blockIdx.x * 256 + threadIdx.x;       // 2*128*128 = 32768
    int l = idx >> 14, ij = idx & 16383, i = ij >> 7, j = ij & 127;
    const float* a = Ws + (size_t)l * 32768;
    const float* b = Wt + (size_t)l * 32768;
    float s = 0.f;
    for (int k = 0; k < 256; k++) s = fmaf(a[i * 256 + k], b[k * 128 + j], s);
    Wc[idx] = s;
}

__global__ void bc_kernel(const float* __restrict__ bs, const float* __restrict__ Wt,
                          const float* __restrict__ bt, float* __restrict__ bc) {
    int idx = threadIdx.x;                           // 2 layers x 128
    int l = idx >> 7, j = idx & 127;
    const float* b = Wt + (size_t)l * 32768;
    float s = bt[l * 128 + j];
    for (int k = 0; k < 256; k++) s = fmaf(bs[l * 256 + k], b[k * 128 + j], s);
    bc[idx] = s;
}

// ---------------------------------------------------------------------------
// Weight packing into MFMA fragment layout (bf16, ks-major). Serves as the
// A operand in the swapped (A=W, B=x) GEMMs.
// ---------------------------------------------------------------------------
__global__ void pack_qkv_kernel(const float* __restrict__ Wq, const float* __restrict__ Wk,
                                const float* __restrict__ Wv, unsigned short* __restrict__ out) {
    int idx = blockIdx.x * 256 + threadIdx.x;        // 2*3*32768 = 196608
    if (idx >= 196608) return;
    int j = idx & 7, lane = (idx >> 3) & 63, ct = (idx >> 9) & 15, ks = (idx >> 13) & 3;
    int m3 = idx >> 15;                              // 0..5
    int l = m3 / 3, m = m3 % 3;
    int k = ks * 32 + ((lane >> 4) * 8) + j;
    int n = ct * 16 + (lane & 15);
    const float* W = (m == 0) ? Wq : (m == 1) ? Wk : Wv;
    out[idx] = f2bf(W[(size_t)l * 32768 + k * 256 + n]);
}

// fused [Wt;Wc] (K=384): KS=12 (ks 0..7 from Wt, 8..11 from Wc), CT=8
__global__ void pack_fused_kernel(const float* __restrict__ Wt, const float* __restrict__ Wc,
                                  unsigned short* __restrict__ out) {
    int idx = blockIdx.x * 256 + threadIdx.x;        // 2*49152 = 98304
    if (idx >= 98304) return;
    int l = idx / 49152, r = idx % 49152;
    int j = r & 7, lane = (r >> 3) & 63;
    int rest = r >> 9;
    int ct = rest & 7, ks = rest >> 3;               // ks 0..11
    int k = ks * 32 + ((lane >> 4) * 8) + j;
    int n = ct * 16 + (lane & 15);
    float v = (k < 256) ? Wt[(size_t)l * 32768 + k * 128 + n]
                        : Wc[(size_t)l * 16384 + (k - 256) * 128 + n];
    out[idx] = f2bf(v);
}

// ---------------------------------------------------------------------------
// Cooperative proj stage (whole 256-thread block): qkv projection for the
// block's 128 rows. Wave w owns rows [rbase, rbase+32) whose bf16 x sit in
// its LDS tile slice. Weights streamed through a double-buffered 8 KB LDS
// chunk: chunk c = (mm = c/8, ct-pair = c%8, all 4 ks). All waves share the
// stream -> 4x fewer global weight loads, ds_read operands, pipelined.
// q -> bf16 [N,256]; k,v -> fp8 e4m3 into kv8 rows (uint 2c = k, 2c+1 = v).
// ---------------------------------------------------------------------------
__device__ __forceinline__ void proj_stream(
    const unsigned short* Tw, unsigned short* WB,
    const unsigned short* __restrict__ Wp,
    const float* __restrict__ b0, const float* __restrict__ b1, const float* __restrict__ b2,
    unsigned short* __restrict__ oq, unsigned* __restrict__ kv8,
    int rbase, int tid) {
    int lane = tid & 63, quad = lane >> 4, lr = lane & 15;
    int n0 = rbase + lr, n1 = rbase + 16 + lr;
    const float* bias[3] = {b0, b1, b2};

    bf16x8 pa0[4], pa1[4];
    #pragma unroll
    for (int ks = 0; ks < 4; ks++) {
        pa0[ks] = *(const bf16x8*)(Tw + lr * LROW + ks * 32 + quad * 8);
        pa1[ks] = *(const bf16x8*)(Tw + (16 + lr) * LROW + ks * 32 + quad * 8);
    }

    // coop-load mapping: flat 8-short unit f -> (ks = f>>7, c2 = (f>>6)&1, ln = f&63)
    int f0 = tid, f1 = tid + 256;
    int ks0 = f0 >> 7, c20 = (f0 >> 6) & 1, ln0 = f0 & 63;
    int ks1 = f1 >> 7, c21 = (f1 >> 6) & 1, ln1 = f1 & 63;
    auto wload = [&](int c, uint4& r0, uint4& r1) {
        int mm = c >> 3, cp = c & 7;
        const unsigned short* base = Wp + mm * 32768;
        r0 = *(const uint4*)(base + (size_t)((ks0 * 16 + cp * 2 + c20) * 64 + ln0) * 8);
        r1 = *(const uint4*)(base + (size_t)((ks1 * 16 + cp * 2 + c21) * 64 + ln1) * 8);
    };

    auto epi = [&](int mm, int ct, const f32x4& e0, const f32x4& e1) {
        int ob = ct * 16 + quad * 4;
        float4 bb = *(const float4*)&bias[mm][ob];
        float v00 = e0[0] + bb.x, v01 = e0[1] + bb.y, v02 = e0[2] + bb.z, v03 = e0[3] + bb.w;
        float v10 = e1[0] + bb.x, v11 = e1[1] + bb.y, v12 = e1[2] + bb.z, v13 = e1[3] + bb.w;
        if (mm == 0) {
            ushort4 s0, s1;
            s0.x = f2bf(v00); s0.y = f2bf(v01); s0.z = f2bf(v02); s0.w = f2bf(v03);
            s1.x = f2bf(v10); s1.y = f2bf(v11); s1.z = f2bf(v12); s1.w = f2bf(v13);
            if (n0 < N_NODES) *(ushort4*)(oq + (size_t)n0 * 256 + ob) = s0;
            if (n1 < N_NODES) *(ushort4*)(oq + (size_t)n1 * 256 + ob) = s1;
        } else {
            int u0 = __builtin_amdgcn_cvt_pk_fp8_f32(v00, v01, 0, false);
            u0 = __builtin_amdgcn_cvt_pk_fp8_f32(v02, v03, u0, true);
            int u1 = __builtin_amdgcn_cvt_pk_fp8_f32(v10, v11, 0, false);
            u1 = __builtin_amdgcn_cvt_pk_fp8_f32(v12, v13, u1, true);
            int kvo = (ob >> 2) * 2 + (mm - 1);
            if (n0 < N_NODES) kv8[(size_t)n0 * 128 + kvo] = (unsigned)u0;
            if (n1 < N_NODES) kv8[(size_t)n1 * 128 + kvo] = (unsigned)u1;
        }
    };

    uint4 wr0, wr1;
    wload(0, wr0, wr1);
    ((uint4*)WB)[tid] = wr0;
    ((uint4*)WB)[tid + 256] = wr1;
    __syncthreads();

    for (int c = 0; c < 24; c++) {
        if (c < 23) wload(c + 1, wr0, wr1);
        const unsigned short* wb = WB + (c & 1) * 4096;
        f32x4 d00 = {0.f, 0.f, 0.f, 0.f}, d01 = {0.f, 0.f, 0.f, 0.f};
        f32x4 d10 = {0.f, 0.f, 0.f, 0.f}, d11 = {0.f, 0.f, 0.f, 0.f};
        #pragma unroll
        for (int ks = 0; ks < 4; ks++) {
            bf16x8 wf0 = *(const bf16x8*)(wb + ((ks * 2 + 0) * 64 + lane) * 8);
            bf16x8 wf1 = *(const bf16x8*)(wb + ((ks * 2 + 1) * 64 + lane) * 8);
            d00 = __builtin_amdgcn_mfma_f32_16x16x32_bf16(wf0, pa0[ks], d00, 0, 0, 0);
            d01 = __builtin_amdgcn_mfma_f32_16x16x32_bf16(wf0, pa1[ks], d01, 0, 0, 0);
            d10 = __builtin_amdgcn_mfma_f32_16x16x32_bf16(wf1, pa0[ks], d10, 0, 0, 0);
            d11 = __builtin_amdgcn_mfma_f32_16x16x32_bf16(wf1, pa1[ks], d11, 0, 0, 0);
        }
        int mm = c >> 3, ct0 = (c & 7) * 2;
        epi(mm, ct0, d00, d01);
        epi(mm, ct0 + 1, d10, d11);
        if (c < 23) {
            ((uint4*)(WB + ((c + 1) & 1) * 4096))[tid] = wr0;
            ((uint4*)(WB + ((c + 1) & 1) * 4096))[tid + 256] = wr1;
        }
        __syncthreads();
    }
}

// ---------------------------------------------------------------------------
// Layer-0 front (coop 128-row blocks): fp32 x -> bf16 xb (global) + LDS tile,
// then streamed qkv projection.
// ---------------------------------------------------------------------------
__global__ __launch_bounds__(256) void fproj_kernel(
    const float* __restrict__ xf, unsigned short* __restrict__ xb,
    const unsigned short* __restrict__ Wp,
    const float* __restrict__ b0, const float* __restrict__ b1, const float* __restrict__ b2,
    unsigned short* __restrict__ oq, unsigned* __restrict__ kv8) {
    __shared__ unsigned short T[128 * LROW];
    __shared__ unsigned short WB[8192];
    int tid = threadIdx.x;
    int w = tid >> 6, lane = tid & 63;
    int quad = lane >> 4, lr = lane & 15;
    int rbase = blockIdx.x * 128 + w * 32;
    unsigned short* Tw = T + w * 32 * LROW;

    #pragma unroll
    for (int s = 0; s < 2; s++) {
        int row = rbase + s * 16 + lr;
        if (row < N_NODES) {
            const float4* src = (const float4*)(xf + (size_t)row * 128 + quad * 32);
            ushort4* gdst = (ushort4*)(xb + (size_t)row * 128 + quad * 32);
            ushort4* ldst = (ushort4*)(Tw + (s * 16 + lr) * LROW + quad * 32);
            #pragma unroll
            for (int i = 0; i < 8; i++) {
                float4 v = src[i];
                ushort4 o;
                o.x = f2bf(v.x); o.y = f2bf(v.y); o.z = f2bf(v.z); o.w = f2bf(v.w);
                gdst[i] = o;
                ldst[i] = o;
            }
        }
    }
    proj_stream(Tw, WB, Wp, b0, b1, b2, oq, kv8, rbase, tid);
}

// ---------------------------------------------------------------------------
// Fused output linear (+ next layer's qkv projection when do_proj), coop
// 128-row blocks: x_next = relu([h|x] @ [Wt;Wc] + bc), weights streamed by
// ks through the LDS double buffer (12 chunks of 8 KB), A prefetched 1 ahead.
// ---------------------------------------------------------------------------
__global__ __launch_bounds__(256) void outproj_kernel(
    const unsigned short* __restrict__ hb, const unsigned short* __restrict__ xbin,
    const unsigned short* __restrict__ Wfp, const float* __restrict__ bc,
    unsigned short* __restrict__ xbout,
    const unsigned short* __restrict__ Wp,
    const float* __restrict__ b0, const float* __restrict__ b1, const float* __restrict__ b2,
    unsigned short* __restrict__ oq, unsigned* __restrict__ kv8, int do_proj) {
    __shared__ unsigned short T[128 * LROW];
    __shared__ unsigned short WB[8192];
    int tid = threadIdx.x;
    int w = tid >> 6, lane = tid & 63;
    int quad = lane >> 4, lr = lane & 15;
    int rbase = blockIdx.x * 128 + w * 32;
    int n0 = rbase + lr, n1 = rbase + 16 + lr;
    int n0c = min(n0, N_NODES - 1), n1c = min(n1, N_NODES - 1);
    unsigned short* Tw = T + w * 32 * LROW;

    auto load_a = [&](int ks, bf16x8& x0, bf16x8& x1) {
        if (ks < 8) {
            x0 = *(const bf16x8*)(hb + (size_t)n0c * 256 + ks * 32 + quad * 8);
            x1 = *(const bf16x8*)(hb + (size_t)n1c * 256 + ks * 32 + quad * 8);
        } else {
            x0 = *(const bf16x8*)(xbin + (size_t)n0c * 128 + (ks - 8) * 32 + quad * 8);
            x1 = *(const bf16x8*)(xbin + (size_t)n1c * 128 + (ks - 8) * 32 + quad * 8);
        }
    };

    f32x4 acc[8][2];
    #pragma unroll
    for (int ct = 0; ct < 8; ct++) {
        acc[ct][0] = (f32x4){0.f, 0.f, 0.f, 0.f};
        acc[ct][1] = (f32x4){0.f, 0.f, 0.f, 0.f};
    }

    // prologue: W chunk 0 + A frag 0
    uint4 wr0 = ((const uint4*)Wfp)[tid];
    uint4 wr1 = ((const uint4*)Wfp)[tid + 256];
    ((uint4*)WB)[tid] = wr0;
    ((uint4*)WB)[tid + 256] = wr1;
    bf16x8 a0c, a1c, a0n, a1n;
    load_a(0, a0c, a1c);
    __syncthreads();

    for (int ks = 0; ks < 12; ks++) {
        if (ks < 11) {
            wr0 = ((const uint4*)(Wfp + (size_t)(ks + 1) * 4096))[tid];
            wr1 = ((const uint4*)(Wfp + (size_t)(ks + 1) * 4096))[tid + 256];
            load_a(ks + 1, a0n, a1n);
        }
        const unsigned short* wb = WB + (ks & 1) * 4096;
        #pragma unroll
        for (int ct = 0; ct < 8; ct++) {
            bf16x8 wf = *(const bf16x8*)(wb + (ct * 64 + lane) * 8);
            acc[ct][0] = __builtin_amdgcn_mfma_f32_16x16x32_bf16(wf, a0c, acc[ct][0], 0, 0, 0);
            acc[ct][1] = __builtin_amdgcn_mfma_f32_16x16x32_bf16(wf, a1c, acc[ct][1], 0, 0, 0);
        }
        if (ks < 11) {
            ((uint4*)(WB + ((ks + 1) & 1) * 4096))[tid] = wr0;
            ((uint4*)(WB + ((ks + 1) & 1) * 4096))[tid + 256] = wr1;
            a0c = a0n;
            a1c = a1n;
        }
        __syncthreads();
    }

    #pragma unroll
    for (int ct = 0; ct < 8; ct++) {
        int ob = ct * 16 + quad * 4;
        float4 bb = *(const float4*)&bc[ob];
        ushort4 s0, s1;
        s0.x = f2bf(fmaxf(acc[ct][0][0] + bb.x, 0.f));
        s0.y = f2bf(fmaxf(acc[ct][0][1] + bb.y, 0.f));
        s0.z = f2bf(fmaxf(acc[ct][0][2] + bb.z, 0.f));
        s0.w = f2bf(fmaxf(acc[ct][0][3] + bb.w, 0.f));
        s1.x = f2bf(fmaxf(acc[ct][1][0] + bb.x, 0.f));
        s1.y = f2bf(fmaxf(acc[ct][1][1] + bb.y, 0.f));
        s1.z = f2bf(fmaxf(acc[ct][1][2] + bb.z, 0.f));
        s1.w = f2bf(fmaxf(acc[ct][1][3] + bb.w, 0.f));
        if (n0 < N_NODES) *(ushort4*)(xbout + (size_t)n0 * 128 + ob) = s0;
        if (n1 < N_NODES) *(ushort4*)(xbout + (size_t)n1 * 128 + ob) = s1;
        *(ushort4*)(Tw + lr * LROW + ob) = s0;
        *(ushort4*)(Tw + (16 + lr) * LROW + ob) = s1;
    }

    if (do_proj) {
        proj_stream(Tw, WB, Wp, b0, b1, b2, oq, kv8, rbase, tid);
    }
}

// ---------------------------------------------------------------------------
// Attention: 256-thread blocks, one dst/wave, unroll 8. Single pass, no
// max-subtraction (|logit|<~3, exp-safe; softmax shift-invariant).
// k,v both fp8 e4m3: lane reads ONE uint2 (8B) = [k-pack | v-pack] per edge.
// ---------------------------------------------------------------------------
__global__ __launch_bounds__(256) void attn_kernel(
    const unsigned short* __restrict__ q, const unsigned* __restrict__ kv8,
    const int* __restrict__ offs, const int* __restrict__ csr,
    unsigned short* __restrict__ hout) {
    const float SCALE = 0.08838834764831845f;  // 1/sqrt(128)
    int w = threadIdx.x >> 6, lane = threadIdx.x & 63;
    int n = blockIdx.x * 4 + w;                // 12500*4 = 50000 exactly
    ushort4 qu = ((const ushort4*)(q + (size_t)n * 256))[lane];
    float4 q4 = make_float4(bf2f(qu.x), bf2f(qu.y), bf2f(qu.z), bf2f(qu.w));
    int beg = offs[n], end = offs[n + 1];

    float4 acc = make_float4(0.f, 0.f, 0.f, 0.f);
    float d = 0.f;

    int j = beg;
    for (; j + 8 <= end; j += 8) {
        uint2 c[8];
        #pragma unroll
        for (int u = 0; u < 8; u++) {
            int s = csr[j + u];
            c[u] = ((const uint2*)(kv8 + (size_t)s * 128))[lane];
        }
        float p[8];
        #pragma unroll
        for (int u = 0; u < 8; u++) {
            f32x2 lo = __builtin_amdgcn_cvt_pk_f32_fp8((int)c[u].x, false);
            f32x2 hi = __builtin_amdgcn_cvt_pk_f32_fp8((int)c[u].x, true);
            p[u] = q4.x * lo.x + q4.y * lo.y + q4.z * hi.x + q4.w * hi.y;
        }
        #pragma unroll
        for (int o = 16; o >= 1; o >>= 1) {
            #pragma unroll
            for (int u = 0; u < 8; u++) p[u] += __shfl_xor(p[u], o);
        }
        #pragma unroll
        for (int u = 0; u < 8; u++) {
            float e = __expf(p[u] * SCALE);
            d += e;
            f32x2 vlo = __builtin_amdgcn_cvt_pk_f32_fp8((int)c[u].y, false);
            f32x2 vhi = __builtin_amdgcn_cvt_pk_f32_fp8((int)c[u].y, true);
            acc.x = fmaf(e, vlo.x, acc.x);
            acc.y = fmaf(e, vlo.y, acc.y);
            acc.z = fmaf(e, vhi.x, acc.z);
            acc.w = fmaf(e, vhi.y, acc.w);
        }
    }
    for (; j < end; j++) {
        int s = csr[j];
        uint2 c = ((const uint2*)(kv8 + (size_t)s * 128))[lane];
        f32x2 lo = __builtin_amdgcn_cvt_pk_f32_fp8((int)c.x, false);
        f32x2 hi = __builtin_amdgcn_cvt_pk_f32_fp8((int)c.x, true);
        float p = q4.x * lo.x + q4.y * lo.y + q4.z * hi.x + q4.w * hi.y;
        #pragma unroll
        for (int o = 16; o >= 1; o >>= 1) p += __shfl_xor(p, o);
        float e = __expf(p * SCALE);
        d += e;
        f32x2 vlo = __builtin_amdgcn_cvt_pk_f32_fp8((int)c.y, false);
        f32x2 vhi = __builtin_amdgcn_cvt_pk_f32_fp8((int)c.y, true);
        acc.x = fmaf(e, vlo.x, acc.x);
        acc.y = fmaf(e, vlo.y, acc.y);
        acc.z = fmaf(e, vhi.x, acc.z);
        acc.w = fmaf(e, vhi.y, acc.w);
    }

    float inv = 1.f / (d + 1e-16f);
    ushort4 hv;
    hv.x = f2bf(acc.x * inv);
    hv.y = f2bf(acc.y * inv);
    hv.z = f2bf(acc.z * inv);
    hv.w = f2bf(acc.w * inv);
    ((ushort4*)(hout + (size_t)n * 256))[lane] = hv;
}

// ---------------------------------------------------------------------------
// Pool init: zero psum/pmax + per-graph counts via binary search (gi sorted).
// ---------------------------------------------------------------------------
__global__ __launch_bounds__(256) void pool_init_kernel(const int* __restrict__ gi,
                                                        int* __restrict__ pcnt,
                                                        float* __restrict__ psum,
                                                        unsigned* __restrict__ pmax) {
    int t = threadIdx.x;
    float4* ps = (float4*)psum;    // 2048 float4
    uint4*  pm = (uint4*)pmax;
    for (int i = t; i < 2048; i += 256) {
        ps[i] = make_float4(0.f, 0.f, 0.f, 0.f);
        uint4 z; z.x = z.y = z.z = z.w = 0u;
        pm[i] = z;
    }
    if (t < NGRAPH) {
        auto lb = [&](int target) {
            int lo = 0, hi = N_NODES;
            while (lo < hi) {
                int mid = (lo + hi) >> 1;
                if (gi[mid] < target) lo = mid + 1;
                else hi = mid;
            }
            return lo;
        };
        int a = lb(t), b = lb(t + 1);
        pcnt[t] = b - a;
    }
}

// ---------------------------------------------------------------------------
// Pooling from bf16 x, ushort4-vectorized, run-compressed (gi sorted).
// relu output >= 0 => uint atomicMax order-correct, 0 is the identity.
// ---------------------------------------------------------------------------
__global__ __launch_bounds__(256) void pool_accum_kernel(
    const unsigned short* __restrict__ xb, const int* __restrict__ gi,
    float* __restrict__ psum, unsigned* __restrict__ pmax) {
    int n0 = blockIdx.x * 128;
    int c4 = (threadIdx.x & 31) * 4;        // 4 consecutive cols
    int phase = threadIdx.x >> 5;           // 0..7
    int first = n0 + phase;
    if (first >= N_NODES) return;
    float s0 = 0.f, s1 = 0.f, s2 = 0.f, s3 = 0.f;
    float m0 = 0.f, m1 = 0.f, m2 = 0.f, m3 = 0.f;
    int cur_g = gi[first];
    for (int r = phase; r < 128; r += 8) {
        int n = n0 + r;
        if (n >= N_NODES) break;
        int g = gi[n];
        if (g != cur_g) {
            float* ps = &psum[cur_g * 128 + c4];
            unsigned* pm = &pmax[cur_g * 128 + c4];
            atomicAdd(ps + 0, s0); atomicAdd(ps + 1, s1);
            atomicAdd(ps + 2, s2); atomicAdd(ps + 3, s3);
            atomicMax(pm + 0, __float_as_uint(m0)); atomicMax(pm + 1, __float_as_uint(m1));
            atomicMax(pm + 2, __float_as_uint(m2)); atomicMax(pm + 3, __float_as_uint(m3));
            s0 = s1 = s2 = s3 = 0.f;
            m0 = m1 = m2 = m3 = 0.f;
            cur_g = g;
        }
        ushort4 u = *(const ushort4*)(xb + (size_t)n * 128 + c4);
        float v0 = bf2f(u.x), v1 = bf2f(u.y), v2 = bf2f(u.z), v3 = bf2f(u.w);
        s0 += v0; s1 += v1; s2 += v2; s3 += v3;
        m0 = fmaxf(m0, v0); m1 = fmaxf(m1, v1);
        m2 = fmaxf(m2, v2); m3 = fmaxf(m3, v3);
    }
    float* ps = &psum[cur_g * 128 + c4];
    unsigned* pm = &pmax[cur_g * 128 + c4];
    atomicAdd(ps + 0, s0); atomicAdd(ps + 1, s1);
    atomicAdd(ps + 2, s2); atomicAdd(ps + 3, s3);
    atomicMax(pm + 0, __float_as_uint(m0)); atomicMax(pm + 1, __float_as_uint(m1));
    atomicMax(pm + 2, __float_as_uint(m2)); atomicMax(pm + 3, __float_as_uint(m3));
}

__global__ void pool_final_kernel(const float* __restrict__ psum, const unsigned* __restrict__ pmax,
                                  const int* __restrict__ pcnt, float* __restrict__ out) {
    int idx = blockIdx.x * 256 + threadIdx.x;
    if (idx >= NGRAPH * 384) return;
    int g = idx / 384, c = idx % 384;
    float r;
    if (c < 128)       r = __uint_as_float(pmax[g * 128 + c]);
    else if (c < 256)  r = psum[g * 128 + (c - 128)] / fmaxf((float)pcnt[g], 1.f);
    else               r = psum[g * 128 + (c - 256)];
    out[idx] = r;
}

// ---------------------------------------------------------------------------
extern "C" void kernel_launch(void* const* d_in, const int* in_sizes, int n_in,
                              void* d_out, int out_size, void* d_ws, size_t ws_size,
                              hipStream_t stream) {
    const float* x   = (const float*)d_in[0];
    const int*   ei  = (const int*)d_in[1];
    const int*   gi  = (const int*)d_in[2];
    const float* Wq  = (const float*)d_in[3];
    const float* bq  = (const float*)d_in[4];
    const float* Wk  = (const float*)d_in[5];
    const float* bk  = (const float*)d_in[6];
    const float* Wv  = (const float*)d_in[7];
    const float* bv  = (const float*)d_in[8];
    const float* Wsk = (const float*)d_in[9];
    const float* bsk = (const float*)d_in[10];
    const float* Wt  = (const float*)d_in[11];
    const float* bt  = (const float*)d_in[12];
    float* out = (float*)d_out;

    char* p = (char*)d_ws;
    auto take = [&](size_t bytes) -> char* {
        char* r = p;
        p += (bytes + 255) & ~(size_t)255;
        return r;
    };
    unsigned short* qbuf   = (unsigned short*)take((size_t)N_NODES * 256 * 2);  // q bf16
    unsigned*       kv8buf = (unsigned*)take((size_t)N_NODES * 128 * 4);        // k|v fp8 packed
    unsigned short* xb     = (unsigned short*)take((size_t)N_NODES * 128 * 2);  // x0 bf16 / final x
    unsigned short* xb2    = (unsigned short*)take((size_t)N_NODES * 128 * 2);  // x1 bf16
    unsigned short* hb     = (unsigned short*)take((size_t)N_NODES * 256 * 2);  // attn out bf16
    unsigned short* Wqkvp  = (unsigned short*)take((size_t)196608 * 2);         // packed qkv
    unsigned short* Wfp    = (unsigned short*)take((size_t)98304 * 2);          // packed [Wt;Wc]
    float*          Wc     = (float*)take(2 * 128 * 128 * 4);
    float*          bc     = (float*)take(2 * 128 * 4);
    int*            counts = (int*)take((size_t)N_NODES * 4);
    int*            offs   = (int*)take((size_t)(N_NODES + 1) * 4);
    int*            cursor = (int*)take((size_t)N_NODES * 4);
    int*            csr    = (int*)take((size_t)N_EDGES * 4);
    int*            bsum   = (int*)take((size_t)SCAN_BLOCKS * 4);
    int*            boff   = (int*)take((size_t)SCAN_BLOCKS * 4);
    float*          psum   = (float*)take(NGRAPH * 128 * 4);
    unsigned*       pmax   = (unsigned*)take(NGRAPH * 128 * 4);
    int*            pcnt   = (int*)take(NGRAPH * 4);

    const int EB = (N_EDGES + 255) / 256;          // 3125
    const int GB = (N_NODES + 127) / 128;          // 391  (coop GEMM / pooling blocks)
    const int AB = (N_NODES + 3) / 4;              // 12500 (attn blocks, 4 dst/block)

    // ---- CSR build ----
    hipMemsetAsync(counts, 0, (size_t)N_NODES * 4, stream);
    degree_kernel<<<EB, 256, 0, stream>>>(ei, counts);
    block_sum_kernel<<<SCAN_BLOCKS, 256, 0, stream>>>(counts, bsum);
    scan_bsum_kernel<<<1, 256, 0, stream>>>(bsum, boff);
    block_scan_kernel<<<SCAN_BLOCKS, 256, 0, stream>>>(counts, boff, offs, cursor);
    scatter_kernel<<<EB, 256, 0, stream>>>(ei, cursor, csr);

    // ---- weight prep ----
    wc_kernel<<<128, 256, 0, stream>>>(Wsk, Wt, Wc);
    bc_kernel<<<1, 256, 0, stream>>>(bsk, Wt, bt, bc);
    pack_qkv_kernel<<<768, 256, 0, stream>>>(Wq, Wk, Wv, Wqkvp);
    pack_fused_kernel<<<384, 256, 0, stream>>>(Wt, Wc, Wfp);

    // ---- layer 0 ----
    fproj_kernel<<<GB, 256, 0, stream>>>(x, xb, Wqkvp, bq, bk, bv, qbuf, kv8buf);
    attn_kernel<<<AB, 256, 0, stream>>>(qbuf, kv8buf, offs, csr, hb);
    // out(L0) fused with proj(L1)
    outproj_kernel<<<GB, 256, 0, stream>>>(hb, xb, Wfp, bc, xb2,
                                           Wqkvp + 98304, bq + 256, bk + 256, bv + 256,
                                           qbuf, kv8buf, 1);
    // ---- layer 1 ----
    attn_kernel<<<AB, 256, 0, stream>>>(qbuf, kv8buf, offs, csr, hb);
    outproj_kernel<<<GB, 256, 0, stream>>>(hb, xb2, Wfp + 49152, bc + 128, xb,
                                           Wqkvp, bq, bk, bv, qbuf, kv8buf, 0);

    // ---- pooling ----
    pool_init_kernel<<<1, 256, 0, stream>>>(gi, pcnt, psum, pmax);
    pool_accum_kernel<<<GB, 256, 0, stream>>>(xb, gi, psum, pmax);
    pool_final_kernel<<<(NGRAPH * 384 + 255) / 256, 256, 0, stream>>>(psum, pmax, pcnt, out);
}